// Round 2
// baseline (904.900 us; speedup 1.0000x reference)
//
#include <hip/hip_runtime.h>
#include <math.h>

#define NN 100000
#define NE 1250000
#define EPSI 1e-5f

// ---- workspace layout (bytes) ----
#define WS_W        0ull          // bf16 [NE*64]            160,000,000
#define WS_AGG      160000000ull  // f32  [NN*64]             25,600,000
#define WS_WB       185600000ull  // bf16 weights: Wig[4096] Whh[12288] Wih[12288]
#define WS_INVDEG   264000000ull  // f32 [NN]
#define WS_COUNTS   264400000ull  // i32 [NN]
#define WS_ROWSTART 264800000ull  // i32 [NN+1]
#define WS_CURSOR   265200128ull  // i32 [NN]
#define WS_BSUM     265600128ull  // i32 [391]
#define WS_BSUMEX   265601792ull  // i32 [391]
#define WS_REC      265603584ull  // int2 [NE]                10,000,000

typedef unsigned short u16;
typedef unsigned int u32;
typedef short s16x4 __attribute__((ext_vector_type(4)));
typedef short s16x8 __attribute__((ext_vector_type(8)));
typedef float f32x4 __attribute__((ext_vector_type(4)));
typedef u32 u32x4 __attribute__((ext_vector_type(4)));

__device__ __forceinline__ u16 f2bf(float f) {
    u32 u = __float_as_uint(f);
    return (u16)((u + 0x7fffu + ((u >> 16) & 1u)) >> 16);   // RNE
}
__device__ __forceinline__ float bf2f(u16 b) {
    return __uint_as_float(((u32)b) << 16);
}
__device__ __forceinline__ u32 pack2(float lo, float hi) {
    return (u32)f2bf(lo) | ((u32)f2bf(hi) << 16);
}
// packed f32x2 -> bf16x2 (RNE), 1 VALU op
__device__ __forceinline__ u32 cvtpk(float lo, float hi) {
    u32 r;
    asm("v_cvt_pk_bf16_f32 %0, %1, %2" : "=v"(r) : "v"(lo), "v"(hi));
    return r;
}
__device__ __forceinline__ float sigmoidf_(float x) {
    return 1.f / (1.f + __expf(-x));
}
__device__ __forceinline__ s16x8 lds_frag(const u16* p) {
    s16x4 lo = *(const s16x4*)p;
    s16x4 hi = *(const s16x4*)(p + 4);
    return __builtin_shufflevector(lo, hi, 0, 1, 2, 3, 4, 5, 6, 7);
}
__device__ __forceinline__ s16x8 gfrag(const u16* W, int n, int ks, int q) {
    // W row-major [64 cols], 16-byte aligned chunks
    return *(const s16x8*)(W + n * 64 + ks * 32 + q * 8);
}
__device__ __forceinline__ float unpk(const u32* p, int r) {
    u32 v = p[r >> 1];
    return bf2f((u16)((r & 1) ? (v >> 16) : (v & 0xffffu)));
}

// ============ fnet via MFMA: per-edge MLP 13->64->64->64, bf16 out ============
// Swapped-operand scheme: D = mfma(W_frag, X_frag) = (X W^T)^T, so lane (q,t)
// holds H[edge t][feat 16ni+4q+r] in registers. W2/W3 COLUMNS are permuted by
// g(k) at LDS-stage time so the packed acc pairs of layer L are verbatim the
// A-fragment of layer L+1 (zero shuffles / zero LDS between layers). W3 ROWS
// are permuted by rho(n) so the output lands as 2 contiguous 16B chunks/lane
// -> direct global dwordx4 stores (no LDS epilogue).
__global__ __launch_bounds__(256) void k_fnet_mfma(
    const float* __restrict__ ef,
    const float* __restrict__ W1, const float* __restrict__ b1,
    const float* __restrict__ W2, const float* __restrict__ b2,
    const float* __restrict__ W3, const float* __restrict__ b3,
    u16* __restrict__ wout)
{
    __shared__ u16 w1l[64 * 16];
    __shared__ u16 w2l[64 * 68];
    __shared__ u16 w3l[64 * 68];

    int tid = threadIdx.x;
    for (int i = tid; i < 64 * 16; i += 256) w1l[i] = 0;
    for (int i = tid; i < 4096; i += 256) {
        int n = i >> 6, k = i & 63;
        int ks = k >> 5, qq = (k >> 3) & 3, j = k & 7;
        int gk = (ks << 5) + ((j >> 2) << 4) + (qq << 2) + (j & 3);     // column perm
        w2l[n * 68 + k] = f2bf(W2[n * 64 + gk]);
        int ni_ = n >> 4, qr = (n >> 2) & 3, rr = n & 3;
        int rn = (qr << 4) + ((ni_ >> 1) << 3) + ((ni_ & 1) << 2) + rr; // row perm rho
        w3l[n * 68 + k] = f2bf(W3[rn * 64 + gk]);
    }
    __syncthreads();
    for (int i = tid; i < 832; i += 256) {
        int n = i / 13, k = i - n * 13;
        w1l[n * 16 + k] = f2bf(W1[i]);
    }
    __syncthreads();

    int wave = tid >> 6, lane = tid & 63;
    int q = lane >> 4, t = lane & 15;
    int ebase = blockIdx.x * 128 + wave * 32;

    // biases: lane (q,t) needs b[16ni+4q+r] (r=0..3) -> float4 loads
    f32x4 b1v[4], b2v[4], b3v[4];
#pragma unroll
    for (int ni = 0; ni < 4; ++ni) {
        b1v[ni] = *(const f32x4*)(b1 + ni * 16 + q * 4);
        b2v[ni] = *(const f32x4*)(b2 + ni * 16 + q * 4);
        // rho-permuted: slot (ni,q,r) holds feature 16q + 8*(ni>>1) + 4*(ni&1) + r
        b3v[ni] = *(const f32x4*)(b3 + q * 16 + (ni >> 1) * 8 + (ni & 1) * 4);
    }

    const s16x8 zfrag = {0, 0, 0, 0, 0, 0, 0, 0};

    // ---- ef fragments (B operand: lane holds ef[edge t][k=q*8+j]) ----
    s16x8 a1[2];
#pragma unroll
    for (int mi = 0; mi < 2; ++mi) {
        int e = ebase + mi * 16 + t;
        s16x8 a = zfrag;
        if (e < NE) {
#pragma unroll
            for (int j = 0; j < 8; ++j) {
                int k = q * 8 + j;
                float v = (k < 13) ? ef[(size_t)e * 13 + k] : 0.f;
                a[j] = (short)f2bf(v);
            }
        }
        a1[mi] = a;
    }

    // ---- W1 fragments (A operand: lane holds W1[16ni+t][k=q*8+j]) ----
    s16x8 w1f[4];
#pragma unroll
    for (int ni = 0; ni < 4; ++ni) {
        s16x8 b = zfrag;
        if (q < 2) b = lds_frag(&w1l[(ni * 16 + t) * 16 + q * 8]);
        w1f[ni] = b;
    }

    // ---- layer 1: h1[ni][mi] lane-local ----
    f32x4 h1[4][2];
#pragma unroll
    for (int ni = 0; ni < 4; ++ni)
#pragma unroll
        for (int mi = 0; mi < 2; ++mi) {
            f32x4 acc = b1v[ni];
            acc = __builtin_amdgcn_mfma_f32_16x16x32_bf16(w1f[ni], a1[mi], acc, 0, 0, 0);
            h1[ni][mi] = acc;
        }

    // ---- transition 1: relu + pack; xp[mi][4ks..4ks+3] IS the ks-frag ----
    s16x8 x2[2][2];
#pragma unroll
    for (int mi = 0; mi < 2; ++mi) {
        u32 xp[8];
#pragma unroll
        for (int ni = 0; ni < 4; ++ni) {
            f32x4 h = h1[ni][mi];
            xp[ni * 2]     = cvtpk(fmaxf(h[0], 0.f), fmaxf(h[1], 0.f));
            xp[ni * 2 + 1] = cvtpk(fmaxf(h[2], 0.f), fmaxf(h[3], 0.f));
        }
        x2[mi][0] = __builtin_bit_cast(s16x8, *(u32x4*)&xp[0]);
        x2[mi][1] = __builtin_bit_cast(s16x8, *(u32x4*)&xp[4]);
    }

    // ---- layer 2 ----
    f32x4 h2[4][2];
#pragma unroll
    for (int ni = 0; ni < 4; ++ni) {
        s16x8 w0 = lds_frag(&w2l[(ni * 16 + t) * 68 + q * 8]);
        s16x8 w1_ = lds_frag(&w2l[(ni * 16 + t) * 68 + 32 + q * 8]);
#pragma unroll
        for (int mi = 0; mi < 2; ++mi) {
            f32x4 acc = b2v[ni];
            acc = __builtin_amdgcn_mfma_f32_16x16x32_bf16(w0, x2[mi][0], acc, 0, 0, 0);
            acc = __builtin_amdgcn_mfma_f32_16x16x32_bf16(w1_, x2[mi][1], acc, 0, 0, 0);
            h2[ni][mi] = acc;
        }
    }

    // ---- transition 2 ----
    s16x8 x3[2][2];
#pragma unroll
    for (int mi = 0; mi < 2; ++mi) {
        u32 xp[8];
#pragma unroll
        for (int ni = 0; ni < 4; ++ni) {
            f32x4 h = h2[ni][mi];
            xp[ni * 2]     = cvtpk(fmaxf(h[0], 0.f), fmaxf(h[1], 0.f));
            xp[ni * 2 + 1] = cvtpk(fmaxf(h[2], 0.f), fmaxf(h[3], 0.f));
        }
        x3[mi][0] = __builtin_bit_cast(s16x8, *(u32x4*)&xp[0]);
        x3[mi][1] = __builtin_bit_cast(s16x8, *(u32x4*)&xp[4]);
    }

    // ---- layer 3 + direct store ----
#pragma unroll
    for (int mi = 0; mi < 2; ++mi) {
        u32 op[8];
#pragma unroll
        for (int ni = 0; ni < 4; ++ni) {
            s16x8 w0 = lds_frag(&w3l[(ni * 16 + t) * 68 + q * 8]);
            s16x8 w1_ = lds_frag(&w3l[(ni * 16 + t) * 68 + 32 + q * 8]);
            f32x4 acc = b3v[ni];
            acc = __builtin_amdgcn_mfma_f32_16x16x32_bf16(w0, x3[mi][0], acc, 0, 0, 0);
            acc = __builtin_amdgcn_mfma_f32_16x16x32_bf16(w1_, x3[mi][1], acc, 0, 0, 0);
            op[ni * 2]     = cvtpk(acc[0], acc[1]);
            op[ni * 2 + 1] = cvtpk(acc[2], acc[3]);
        }
        int e = ebase + mi * 16 + t;
        if (e < NE) {
            // lane holds output feats [16q..16q+7] (ni 0,1) and [16q+8..16q+15] (ni 2,3)
            *(u32x4*)(wout + (size_t)e * 64 + q * 16)     = *(u32x4*)&op[0];
            *(u32x4*)(wout + (size_t)e * 64 + q * 16 + 8) = *(u32x4*)&op[4];
        }
    }
}

// ---------------- prep: convert GRU weights to bf16 row-major ----------------
__global__ void k_prep_w(const float* __restrict__ Wig, const float* __restrict__ Whh,
                         const float* __restrict__ Wih, u16* __restrict__ wb)
{
    int i = blockIdx.x * 256 + threadIdx.x;   // < 28672
    if (i < 4096) wb[i] = f2bf(Wig[i]);
    else if (i < 16384) wb[i] = f2bf(Whh[i - 4096]);
    else if (i < 28672) wb[i] = f2bf(Wih[i - 16384]);
}

// ---------------- degree counting ----------------
__global__ void k_count(const int* __restrict__ idx, int* __restrict__ counts)
{
    int e = blockIdx.x * 256 + threadIdx.x;
    if (e < NE) atomicAdd(&counts[idx[e]], 1);
}

// ---------------- two-level exclusive scan over counts ----------------
__global__ void k_scan_partial(const int* __restrict__ counts, int* __restrict__ bsum)
{
    __shared__ int s[256];
    int i = blockIdx.x * 256 + threadIdx.x;
    int v = (i < NN) ? counts[i] : 0;
    s[threadIdx.x] = v; __syncthreads();
    for (int off = 128; off > 0; off >>= 1) {
        if (threadIdx.x < off) s[threadIdx.x] += s[threadIdx.x + off];
        __syncthreads();
    }
    if (threadIdx.x == 0) bsum[blockIdx.x] = s[0];
}

__global__ void k_scan_bsum(const int* __restrict__ bsum, int* __restrict__ bsumex)
{
    __shared__ int s[512];
    int t = threadIdx.x;
    int v0 = (t < 391) ? bsum[t] : 0;
    s[t] = v0; __syncthreads();
    for (int off = 1; off < 512; off <<= 1) {
        int add = (t >= off) ? s[t - off] : 0;
        __syncthreads();
        s[t] += add;
        __syncthreads();
    }
    if (t < 391) bsumex[t] = s[t] - v0;
}

__global__ void k_scan_final(const int* __restrict__ counts, const int* __restrict__ bsumex,
                             int* __restrict__ rowstart, int* __restrict__ cursor,
                             float* __restrict__ invdeg)
{
    __shared__ int s[256];
    int t = threadIdx.x;
    int i = blockIdx.x * 256 + t;
    int c = (i < NN) ? counts[i] : 0;
    s[t] = c; __syncthreads();
    for (int off = 1; off < 256; off <<= 1) {
        int add = (t >= off) ? s[t - off] : 0;
        __syncthreads();
        s[t] += add;
        __syncthreads();
    }
    int ex = s[t] - c + bsumex[blockIdx.x];
    if (i < NN) {
        rowstart[i] = ex;
        cursor[i] = ex;
        invdeg[i] = 1.f / (float)(c > 1 ? c : 1);
    }
    if (i == 0) rowstart[NN] = NE;
}

// ---------------- scatter edges into CSR order ----------------
__global__ void k_scatter(const int* __restrict__ idx, int* __restrict__ cursor,
                          int2* __restrict__ rec)
{
    int e = blockIdx.x * 256 + threadIdx.x;
    if (e < NE) {
        int d = idx[e];
        int s = idx[NE + e];
        int p = atomicAdd(&cursor[d], 1);
        rec[p] = make_int2(s, e);
    }
}

// ---------------- copy hx0 into out column 0 ----------------
__global__ void k_init(const float4* __restrict__ hx4, float* __restrict__ outp)
{
    int i = blockIdx.x * 256 + threadIdx.x;
    int n = i >> 4, q = i & 15;
    ((float4*)(outp + (size_t)n * 256))[q] = hx4[i];
}

// ---------------- aggregation: wave per node, 4-wide batched ILP ----------------
__global__ __launch_bounds__(256) void k_agg(
    const float* __restrict__ outp, const u16* __restrict__ w,
    const int2* __restrict__ rec, const int* __restrict__ rowstart,
    const float* __restrict__ invdeg, float* __restrict__ agg, int it)
{
    int lane = threadIdx.x & 63;
    int n = blockIdx.x * 4 + (threadIdx.x >> 6);
    n = __builtin_amdgcn_readfirstlane(n);
    int p0 = rowstart[n], p1 = rowstart[n + 1];
    const float* hxcol = outp + (size_t)it * 64 + lane;
    float a0 = 0.f, a1 = 0.f, a2 = 0.f, a3 = 0.f;
    int p = p0;
    for (; p + 4 <= p1; p += 4) {
        int2 r0 = rec[p];
        int2 r1 = rec[p + 1];
        int2 r2 = rec[p + 2];
        int2 r3 = rec[p + 3];
        float h0 = hxcol[(size_t)r0.x * 256];
        float h1 = hxcol[(size_t)r1.x * 256];
        float h2 = hxcol[(size_t)r2.x * 256];
        float h3 = hxcol[(size_t)r3.x * 256];
        float w0 = bf2f(__builtin_nontemporal_load(&w[(size_t)r0.y * 64 + lane]));
        float w1 = bf2f(__builtin_nontemporal_load(&w[(size_t)r1.y * 64 + lane]));
        float w2 = bf2f(__builtin_nontemporal_load(&w[(size_t)r2.y * 64 + lane]));
        float w3 = bf2f(__builtin_nontemporal_load(&w[(size_t)r3.y * 64 + lane]));
        a0 = fmaf(h0, w0, a0);
        a1 = fmaf(h1, w1, a1);
        a2 = fmaf(h2, w2, a2);
        a3 = fmaf(h3, w3, a3);
    }
    for (; p < p1; ++p) {
        int2 r = rec[p];
        float hv = hxcol[(size_t)r.x * 256];
        float wv = bf2f(__builtin_nontemporal_load(&w[(size_t)r.y * 64 + lane]));
        a0 = fmaf(hv, wv, a0);
    }
    agg[(size_t)n * 64 + lane] = ((a0 + a1) + (a2 + a3)) * invdeg[n];
}

// ======== fused GRU: gate GEMM + gi/gh MFMA + inorm + gates, all in-kernel ========
__global__ __launch_bounds__(256) void k_gru_fused(
    float* __restrict__ outp, const float* __restrict__ agg,
    const u16* __restrict__ wb,
    const float* __restrict__ big, const float* __restrict__ bih,
    const float* __restrict__ bhh, int it)
{
    __shared__ u16 hbuf[4][16 * 68];
    int tid = threadIdx.x;
    int wave = tid >> 6, lane = tid & 63;
    int q = lane >> 4, t = lane & 15;
    int nbase = blockIdx.x * 64 + wave * 16;
    u16* hb = hbuf[wave];
    const u16* wigb = wb;
    const u16* whhb = wb + 4096;
    const u16* wihb = wb + 16384;

    // ---- stage hx -> hb (bf16), coalesced float4 reads ----
    {
        int c = lane & 15;
        int mrow = lane >> 4;
#pragma unroll
        for (int rep = 0; rep < 4; ++rep) {
            int m = rep * 4 + mrow;
            int node = nbase + m;
            float4 v = make_float4(0.f, 0.f, 0.f, 0.f);
            if (node < NN)
                v = *(const float4*)(outp + (size_t)node * 256 + (size_t)it * 64 + c * 4);
            u16* p = &hb[m * 68 + c * 4];
            p[0] = f2bf(v.x); p[1] = f2bf(v.y); p[2] = f2bf(v.z); p[3] = f2bf(v.w);
        }
    }
    // (wave-private buffer; in-order DS pipe makes a barrier unnecessary)

    // ---- hx A-frags + hx in C-layout ----
    s16x8 ahx[2];
    ahx[0] = lds_frag(&hb[t * 68 + q * 8]);
    ahx[1] = lds_frag(&hb[t * 68 + 32 + q * 8]);
    u16 hxc[4][4];
#pragma unroll
    for (int ni = 0; ni < 4; ++ni)
#pragma unroll
        for (int r = 0; r < 4; ++r)
            hxc[ni][r] = hb[(q * 4 + r) * 68 + ni * 16 + t];

    // ---- gate GEMM: sigmoid(hx @ Wig^T + big) * agg -> inp (to hb) ----
#pragma unroll
    for (int ni = 0; ni < 4; ++ni) {
        float bg = big[ni * 16 + t];
        s16x8 b0 = gfrag(wigb, ni * 16 + t, 0, q);
        s16x8 b1 = gfrag(wigb, ni * 16 + t, 1, q);
        f32x4 acc = {bg, bg, bg, bg};
        acc = __builtin_amdgcn_mfma_f32_16x16x32_bf16(ahx[0], b0, acc, 0, 0, 0);
        acc = __builtin_amdgcn_mfma_f32_16x16x32_bf16(ahx[1], b1, acc, 0, 0, 0);
#pragma unroll
        for (int r = 0; r < 4; ++r) {
            int node = nbase + q * 4 + r;
            float av = (node < NN) ? agg[(size_t)node * 64 + ni * 16 + t] : 0.f;
            float iv = sigmoidf_(acc[r]) * av;
            hb[(q * 4 + r) * 68 + ni * 16 + t] = f2bf(iv);
        }
    }

    // ---- gh = hx @ Whh^T  (12 tiles, packed bf16 in regs + stats) ----
    float sgh[4] = {0.f, 0.f, 0.f, 0.f}, qgh[4] = {0.f, 0.f, 0.f, 0.f};
    u32 ghp[12][2];
#pragma unroll
    for (int ni = 0; ni < 12; ++ni) {
        s16x8 b0 = gfrag(whhb, ni * 16 + t, 0, q);
        s16x8 b1 = gfrag(whhb, ni * 16 + t, 1, q);
        f32x4 acc = {0.f, 0.f, 0.f, 0.f};
        acc = __builtin_amdgcn_mfma_f32_16x16x32_bf16(ahx[0], b0, acc, 0, 0, 0);
        acc = __builtin_amdgcn_mfma_f32_16x16x32_bf16(ahx[1], b1, acc, 0, 0, 0);
#pragma unroll
        for (int r = 0; r < 4; ++r) { sgh[r] += acc[r]; qgh[r] += acc[r] * acc[r]; }
        ghp[ni][0] = pack2(acc[0], acc[1]);
        ghp[ni][1] = pack2(acc[2], acc[3]);
    }

    // ---- inp A-frags (after LDS write above; same-wave ordering) ----
    s16x8 ain[2];
    ain[0] = lds_frag(&hb[t * 68 + q * 8]);
    ain[1] = lds_frag(&hb[t * 68 + 32 + q * 8]);

    // ---- gi = inp @ Wih^T ----
    float sgi[4] = {0.f, 0.f, 0.f, 0.f}, qgi[4] = {0.f, 0.f, 0.f, 0.f};
    u32 gip[12][2];
#pragma unroll
    for (int ni = 0; ni < 12; ++ni) {
        s16x8 b0 = gfrag(wihb, ni * 16 + t, 0, q);
        s16x8 b1 = gfrag(wihb, ni * 16 + t, 1, q);
        f32x4 acc = {0.f, 0.f, 0.f, 0.f};
        acc = __builtin_amdgcn_mfma_f32_16x16x32_bf16(ain[0], b0, acc, 0, 0, 0);
        acc = __builtin_amdgcn_mfma_f32_16x16x32_bf16(ain[1], b1, acc, 0, 0, 0);
#pragma unroll
        for (int r = 0; r < 4; ++r) { sgi[r] += acc[r]; qgi[r] += acc[r] * acc[r]; }
        gip[ni][0] = pack2(acc[0], acc[1]);
        gip[ni][1] = pack2(acc[2], acc[3]);
    }

    // ---- reduce stats over t-group ----
#pragma unroll
    for (int m = 1; m < 16; m <<= 1) {
#pragma unroll
        for (int r = 0; r < 4; ++r) {
            sgh[r] += __shfl_xor(sgh[r], m, 64);
            qgh[r] += __shfl_xor(qgh[r], m, 64);
            sgi[r] += __shfl_xor(sgi[r], m, 64);
            qgi[r] += __shfl_xor(qgi[r], m, 64);
        }
    }
    float mi_[4], ri_[4], mh_[4], rh_[4];
#pragma unroll
    for (int r = 0; r < 4; ++r) {
        mi_[r] = sgi[r] * (1.f / 192.f);
        mh_[r] = sgh[r] * (1.f / 192.f);
        ri_[r] = rsqrtf(qgi[r] * (1.f / 192.f) - mi_[r] * mi_[r] + EPSI);
        rh_[r] = rsqrtf(qgh[r] * (1.f / 192.f) - mh_[r] * mh_[r] + EPSI);
    }

    // ---- gates + hx update + store ----
#pragma unroll
    for (int ni = 0; ni < 4; ++ni) {
        int f = ni * 16 + t;
        float bi_r = bih[f], bi_i = bih[64 + f], bi_n = bih[128 + f];
        float bh_r = bhh[f], bh_i = bhh[64 + f], bh_n = bhh[128 + f];
#pragma unroll
        for (int r = 0; r < 4; ++r) {
            int node = nbase + q * 4 + r;
            float iv_r = (unpk(gip[ni], r) - mi_[r]) * ri_[r];
            float iv_i = (unpk(gip[ni + 4], r) - mi_[r]) * ri_[r];
            float iv_n = (unpk(gip[ni + 8], r) - mi_[r]) * ri_[r];
            float hv_r = (unpk(ghp[ni], r) - mh_[r]) * rh_[r];
            float hv_i = (unpk(ghp[ni + 4], r) - mh_[r]) * rh_[r];
            float hv_n = (unpk(ghp[ni + 8], r) - mh_[r]) * rh_[r];
            float rg = sigmoidf_(iv_r + bi_r + hv_r + bh_r);
            float zg = sigmoidf_(iv_i + bi_i + hv_i + bh_i);
            float ng = tanhf(iv_n + bi_n + rg * (hv_n + bh_n));
            float ho = bf2f(hxc[ni][r]);
            float res = ng + zg * (ho - ng);
            if (node < NN)
                outp[(size_t)node * 256 + (size_t)(it + 1) * 64 + f] = res;
        }
    }
}

extern "C" void kernel_launch(void* const* d_in, const int* in_sizes, int n_in,
                              void* d_out, int out_size, void* d_ws, size_t ws_size,
                              hipStream_t stream)
{
    const float* hx  = (const float*)d_in[0];
    const int*   eix = (const int*)d_in[1];
    const float* ef  = (const float*)d_in[2];
    const float* fW1 = (const float*)d_in[3];
    const float* fb1 = (const float*)d_in[4];
    const float* fW2 = (const float*)d_in[5];
    const float* fb2 = (const float*)d_in[6];
    const float* fW3 = (const float*)d_in[7];
    const float* fb3 = (const float*)d_in[8];
    const float* Wih = (const float*)d_in[9];
    const float* Whh = (const float*)d_in[10];
    const float* bih = (const float*)d_in[11];
    const float* bhh = (const float*)d_in[12];
    const float* Wig = (const float*)d_in[13];
    const float* big = (const float*)d_in[14];
    float* outp = (float*)d_out;
    char* ws = (char*)d_ws;

    u16*    w      = (u16*)(ws + WS_W);
    float*  agg    = (float*)(ws + WS_AGG);
    u16*    wb     = (u16*)(ws + WS_WB);
    float*  invdeg = (float*)(ws + WS_INVDEG);
    int*    counts = (int*)(ws + WS_COUNTS);
    int*    rowst  = (int*)(ws + WS_ROWSTART);
    int*    cursor = (int*)(ws + WS_CURSOR);
    int*    bsum   = (int*)(ws + WS_BSUM);
    int*    bsumex = (int*)(ws + WS_BSUMEX);
    int2*   rec    = (int2*)(ws + WS_REC);

    hipMemsetAsync(counts, 0, NN * sizeof(int), stream);
    k_prep_w<<<112, 256, 0, stream>>>(Wig, Whh, Wih, wb);
    k_fnet_mfma<<<9766, 256, 0, stream>>>(ef, fW1, fb1, fW2, fb2, fW3, fb3, w);
    k_count<<<(NE + 255) / 256, 256, 0, stream>>>(eix, counts);
    k_scan_partial<<<391, 256, 0, stream>>>(counts, bsum);
    k_scan_bsum<<<1, 512, 0, stream>>>(bsum, bsumex);
    k_scan_final<<<391, 256, 0, stream>>>(counts, bsumex, rowst, cursor, invdeg);
    k_scatter<<<(NE + 255) / 256, 256, 0, stream>>>(eix, cursor, rec);
    k_init<<<6250, 256, 0, stream>>>((const float4*)hx, outp);

    for (int it = 0; it < 3; ++it) {
        k_agg<<<25000, 256, 0, stream>>>(outp, w, rec, rowst, invdeg, agg, it);
        k_gru_fused<<<1563, 256, 0, stream>>>(outp, agg, wb, big, bih, bhh, it);
    }
}

// Round 3
// 856.867 us; speedup vs baseline: 1.0561x; 1.0561x over previous
//
#include <hip/hip_runtime.h>
#include <math.h>

#define NN 100000
#define NE 1250000
#define EPSI 1e-5f

// ---- workspace layout (bytes) ----
#define WS_W        0ull          // bf16 [NE*64]            160,000,000  (CSR-ordered)
#define WS_AGG      160000000ull  // f32  [NN*64]             25,600,000
#define WS_WB       185600000ull  // bf16 weights: Wig[4096] Whh[12288] Wih[12288]
#define WS_INVDEG   264000000ull  // f32 [NN]
#define WS_COUNTS   264400000ull  // i32 [NN]
#define WS_ROWSTART 264800000ull  // i32 [NN+1]
#define WS_CURSOR   265200128ull  // i32 [NN]
#define WS_BSUM     265600128ull  // i32 [391]
#define WS_BSUMEX   265601792ull  // i32 [391]
#define WS_SRC      265603584ull  // i32 [NE]  src node per CSR slot       5,000,000
#define WS_EPERM    270603584ull  // i32 [NE]  edge id -> CSR slot         5,000,000

typedef unsigned short u16;
typedef unsigned int u32;
typedef short s16x4 __attribute__((ext_vector_type(4)));
typedef short s16x8 __attribute__((ext_vector_type(8)));
typedef float f32x4 __attribute__((ext_vector_type(4)));
typedef u32 u32x4 __attribute__((ext_vector_type(4)));

__device__ __forceinline__ u16 f2bf(float f) {
    u32 u = __float_as_uint(f);
    return (u16)((u + 0x7fffu + ((u >> 16) & 1u)) >> 16);   // RNE
}
__device__ __forceinline__ float bf2f(u16 b) {
    return __uint_as_float(((u32)b) << 16);
}
__device__ __forceinline__ u32 pack2(float lo, float hi) {
    return (u32)f2bf(lo) | ((u32)f2bf(hi) << 16);
}
__device__ __forceinline__ float sigmoidf_(float x) {
    return 1.f / (1.f + __expf(-x));
}
__device__ __forceinline__ s16x8 lds_frag(const u16* p) {
    s16x4 lo = *(const s16x4*)p;
    s16x4 hi = *(const s16x4*)(p + 4);
    return __builtin_shufflevector(lo, hi, 0, 1, 2, 3, 4, 5, 6, 7);
}
__device__ __forceinline__ s16x8 gfrag(const u16* W, int n, int ks, int q) {
    // W row-major [64 cols], 16-byte aligned chunks
    return *(const s16x8*)(W + n * 64 + ks * 32 + q * 8);
}
__device__ __forceinline__ float unpk(const u32* p, int r) {
    u32 v = p[r >> 1];
    return bf2f((u16)((r & 1) ? (v >> 16) : (v & 0xffffu)));
}

// ============ fnet via MFMA: per-edge MLP 13->64->64->64, bf16 out ============
// R0-proven structure (latency-tolerant LDS interleave). Output rows are
// scattered to CSR slot eperm[e] so k_agg streams w sequentially.
__global__ __launch_bounds__(256) void k_fnet_mfma(
    const float* __restrict__ ef,
    const float* __restrict__ W1, const float* __restrict__ b1,
    const float* __restrict__ W2, const float* __restrict__ b2,
    const float* __restrict__ W3, const float* __restrict__ b3,
    const int* __restrict__ eperm,
    u16* __restrict__ wout)
{
    __shared__ u16 w1l[64 * 16];
    __shared__ u16 w2l[64 * 68];
    __shared__ u16 w3l[64 * 68];
    __shared__ u16 hbuf[4][32 * 68];

    int tid = threadIdx.x;
    for (int i = tid; i < 64 * 16; i += 256) w1l[i] = 0;
    for (int i = tid; i < 4096; i += 256) w2l[(i >> 6) * 68 + (i & 63)] = f2bf(W2[i]);
    for (int i = tid; i < 4096; i += 256) w3l[(i >> 6) * 68 + (i & 63)] = f2bf(W3[i]);
    __syncthreads();
    for (int i = tid; i < 832; i += 256) {
        int n = i / 13, k = i - n * 13;
        w1l[n * 16 + k] = f2bf(W1[i]);
    }
    __syncthreads();

    int wave = tid >> 6, lane = tid & 63;
    int q = lane >> 4, t = lane & 15;
    int ebase = blockIdx.x * 128 + wave * 32;
    u16* hb = hbuf[wave];

    float b1v[4], b2v[4], b3v[4];
#pragma unroll
    for (int ni = 0; ni < 4; ++ni) {
        b1v[ni] = b1[ni * 16 + t];
        b2v[ni] = b2[ni * 16 + t];
        b3v[ni] = b3[ni * 16 + t];
    }

    const s16x8 zfrag = {0, 0, 0, 0, 0, 0, 0, 0};

    // layer 1
    s16x8 a1[2];
#pragma unroll
    for (int mi = 0; mi < 2; ++mi) {
        int e = ebase + mi * 16 + t;
        s16x8 a = zfrag;
        if (e < NE) {
#pragma unroll
            for (int j = 0; j < 8; ++j) {
                int k = q * 8 + j;
                float v = (k < 13) ? ef[(size_t)e * 13 + k] : 0.f;
                a[j] = (short)f2bf(v);
            }
        }
        a1[mi] = a;
    }
    s16x8 B1f[4];
#pragma unroll
    for (int ni = 0; ni < 4; ++ni) {
        s16x8 b = zfrag;
        if (q < 2) b = lds_frag(&w1l[(ni * 16 + t) * 16 + q * 8]);
        B1f[ni] = b;
    }
#pragma unroll
    for (int ni = 0; ni < 4; ++ni) {
#pragma unroll
        for (int mi = 0; mi < 2; ++mi) {
            f32x4 acc = {b1v[ni], b1v[ni], b1v[ni], b1v[ni]};
            acc = __builtin_amdgcn_mfma_f32_16x16x32_bf16(a1[mi], B1f[ni], acc, 0, 0, 0);
#pragma unroll
            for (int r = 0; r < 4; ++r)
                hb[(mi * 16 + q * 4 + r) * 68 + ni * 16 + t] = f2bf(fmaxf(acc[r], 0.f));
        }
    }

    // layer 2
    s16x8 a2[2][2];
#pragma unroll
    for (int mi = 0; mi < 2; ++mi)
#pragma unroll
        for (int ks = 0; ks < 2; ++ks)
            a2[mi][ks] = lds_frag(&hb[(mi * 16 + t) * 68 + ks * 32 + q * 8]);
#pragma unroll
    for (int ni = 0; ni < 4; ++ni) {
        s16x8 b0 = lds_frag(&w2l[(ni * 16 + t) * 68 + q * 8]);
        s16x8 b1f = lds_frag(&w2l[(ni * 16 + t) * 68 + 32 + q * 8]);
#pragma unroll
        for (int mi = 0; mi < 2; ++mi) {
            f32x4 acc = {b2v[ni], b2v[ni], b2v[ni], b2v[ni]};
            acc = __builtin_amdgcn_mfma_f32_16x16x32_bf16(a2[mi][0], b0, acc, 0, 0, 0);
            acc = __builtin_amdgcn_mfma_f32_16x16x32_bf16(a2[mi][1], b1f, acc, 0, 0, 0);
#pragma unroll
            for (int r = 0; r < 4; ++r)
                hb[(mi * 16 + q * 4 + r) * 68 + ni * 16 + t] = f2bf(fmaxf(acc[r], 0.f));
        }
    }

    // layer 3
    s16x8 a3[2][2];
#pragma unroll
    for (int mi = 0; mi < 2; ++mi)
#pragma unroll
        for (int ks = 0; ks < 2; ++ks)
            a3[mi][ks] = lds_frag(&hb[(mi * 16 + t) * 68 + ks * 32 + q * 8]);
#pragma unroll
    for (int ni = 0; ni < 4; ++ni) {
        s16x8 b0 = lds_frag(&w3l[(ni * 16 + t) * 68 + q * 8]);
        s16x8 b1f = lds_frag(&w3l[(ni * 16 + t) * 68 + 32 + q * 8]);
#pragma unroll
        for (int mi = 0; mi < 2; ++mi) {
            f32x4 acc = {b3v[ni], b3v[ni], b3v[ni], b3v[ni]};
            acc = __builtin_amdgcn_mfma_f32_16x16x32_bf16(a3[mi][0], b0, acc, 0, 0, 0);
            acc = __builtin_amdgcn_mfma_f32_16x16x32_bf16(a3[mi][1], b1f, acc, 0, 0, 0);
#pragma unroll
            for (int r = 0; r < 4; ++r)
                hb[(mi * 16 + q * 4 + r) * 68 + ni * 16 + t] = f2bf(acc[r]);
        }
    }

    // store, permuted to CSR slot (8 lanes per edge -> 2 lines per row)
#pragma unroll
    for (int p = 0; p < 4; ++p) {
        int g = p * 64 + lane;
        int m = g >> 3, qq = g & 7;
        int e = ebase + m;
        if (e < NE) {
            int pos = eperm[e];
            const u16* sp = &hb[m * 68 + qq * 8];
            s16x4 lo = *(const s16x4*)sp;
            s16x4 hi = *(const s16x4*)(sp + 4);
            struct H128 { s16x4 a, b; } h;
            h.a = lo; h.b = hi;
            u32x4 v = __builtin_bit_cast(u32x4, h);
            *(u32x4*)(wout + (size_t)pos * 64 + qq * 8) = v;
        }
    }
}

// ---------------- prep: convert GRU weights to bf16 row-major ----------------
__global__ void k_prep_w(const float* __restrict__ Wig, const float* __restrict__ Whh,
                         const float* __restrict__ Wih, u16* __restrict__ wb)
{
    int i = blockIdx.x * 256 + threadIdx.x;   // < 28672
    if (i < 4096) wb[i] = f2bf(Wig[i]);
    else if (i < 16384) wb[i] = f2bf(Whh[i - 4096]);
    else if (i < 28672) wb[i] = f2bf(Wih[i - 16384]);
}

// ---------------- degree counting ----------------
__global__ void k_count(const int* __restrict__ idx, int* __restrict__ counts)
{
    int e = blockIdx.x * 256 + threadIdx.x;
    if (e < NE) atomicAdd(&counts[idx[e]], 1);
}

// ---------------- two-level exclusive scan over counts ----------------
__global__ void k_scan_partial(const int* __restrict__ counts, int* __restrict__ bsum)
{
    __shared__ int s[256];
    int i = blockIdx.x * 256 + threadIdx.x;
    int v = (i < NN) ? counts[i] : 0;
    s[threadIdx.x] = v; __syncthreads();
    for (int off = 128; off > 0; off >>= 1) {
        if (threadIdx.x < off) s[threadIdx.x] += s[threadIdx.x + off];
        __syncthreads();
    }
    if (threadIdx.x == 0) bsum[blockIdx.x] = s[0];
}

__global__ void k_scan_bsum(const int* __restrict__ bsum, int* __restrict__ bsumex)
{
    __shared__ int s[512];
    int t = threadIdx.x;
    int v0 = (t < 391) ? bsum[t] : 0;
    s[t] = v0; __syncthreads();
    for (int off = 1; off < 512; off <<= 1) {
        int add = (t >= off) ? s[t - off] : 0;
        __syncthreads();
        s[t] += add;
        __syncthreads();
    }
    if (t < 391) bsumex[t] = s[t] - v0;
}

__global__ void k_scan_final(const int* __restrict__ counts, const int* __restrict__ bsumex,
                             int* __restrict__ rowstart, int* __restrict__ cursor,
                             float* __restrict__ invdeg)
{
    __shared__ int s[256];
    int t = threadIdx.x;
    int i = blockIdx.x * 256 + t;
    int c = (i < NN) ? counts[i] : 0;
    s[t] = c; __syncthreads();
    for (int off = 1; off < 256; off <<= 1) {
        int add = (t >= off) ? s[t - off] : 0;
        __syncthreads();
        s[t] += add;
        __syncthreads();
    }
    int ex = s[t] - c + bsumex[blockIdx.x];
    if (i < NN) {
        rowstart[i] = ex;
        cursor[i] = ex;
        invdeg[i] = 1.f / (float)(c > 1 ? c : 1);
    }
    if (i == 0) rowstart[NN] = NE;
}

// ------- scatter edges into CSR order: srcs[p]=src, eperm[e]=p -------
__global__ void k_scatter(const int* __restrict__ idx, int* __restrict__ cursor,
                          int* __restrict__ srcs, int* __restrict__ eperm)
{
    int e = blockIdx.x * 256 + threadIdx.x;
    if (e < NE) {
        int d = idx[e];
        int s = idx[NE + e];
        int p = atomicAdd(&cursor[d], 1);
        srcs[p] = s;
        eperm[e] = p;
    }
}

// ---------------- copy hx0 into out column 0 ----------------
__global__ void k_init(const float4* __restrict__ hx4, float* __restrict__ outp)
{
    int i = blockIdx.x * 256 + threadIdx.x;
    int n = i >> 4, q = i & 15;
    ((float4*)(outp + (size_t)n * 256))[q] = hx4[i];
}

// ------- aggregation: wave per node; w streams sequentially (CSR order) -------
// srcs reads are wave-uniform (scalar int4); w reads are contiguous 128B rows
// advancing sequentially; only the hx gather is random. 4-wide ILP batching.
__global__ __launch_bounds__(256) void k_agg(
    const float* __restrict__ outp, const u16* __restrict__ w,
    const int* __restrict__ srcs, const int* __restrict__ rowstart,
    const float* __restrict__ invdeg, float* __restrict__ agg, int it)
{
    int lane = threadIdx.x & 63;
    int n = blockIdx.x * 4 + (threadIdx.x >> 6);
    n = __builtin_amdgcn_readfirstlane(n);
    int p0 = rowstart[n], p1 = rowstart[n + 1];
    const float* hxcol = outp + (size_t)it * 64 + lane;
    const u16* wp = w + (size_t)p0 * 64 + lane;
    float a0 = 0.f, a1 = 0.f, a2 = 0.f, a3 = 0.f;
    int p = p0;
    for (; p + 4 <= p1; p += 4) {
        int4 s4 = *(const int4*)(srcs + p);          // wave-uniform -> s_load
        float h0 = hxcol[(size_t)s4.x * 256];
        float h1 = hxcol[(size_t)s4.y * 256];
        float h2 = hxcol[(size_t)s4.z * 256];
        float h3 = hxcol[(size_t)s4.w * 256];
        float w0 = bf2f(__builtin_nontemporal_load(wp));
        float w1 = bf2f(__builtin_nontemporal_load(wp + 64));
        float w2 = bf2f(__builtin_nontemporal_load(wp + 128));
        float w3 = bf2f(__builtin_nontemporal_load(wp + 192));
        wp += 256;
        a0 = fmaf(h0, w0, a0);
        a1 = fmaf(h1, w1, a1);
        a2 = fmaf(h2, w2, a2);
        a3 = fmaf(h3, w3, a3);
    }
    for (; p < p1; ++p) {
        int s = srcs[p];
        float hv = hxcol[(size_t)s * 256];
        float wv = bf2f(__builtin_nontemporal_load(wp));
        wp += 64;
        a0 = fmaf(hv, wv, a0);
    }
    agg[(size_t)n * 64 + lane] = ((a0 + a1) + (a2 + a3)) * invdeg[n];
}

// ======== fused GRU: gate GEMM + gi/gh MFMA + inorm + gates, all in-kernel ========
__global__ __launch_bounds__(256) void k_gru_fused(
    float* __restrict__ outp, const float* __restrict__ agg,
    const u16* __restrict__ wb,
    const float* __restrict__ big, const float* __restrict__ bih,
    const float* __restrict__ bhh, int it)
{
    __shared__ u16 hbuf[4][16 * 68];
    int tid = threadIdx.x;
    int wave = tid >> 6, lane = tid & 63;
    int q = lane >> 4, t = lane & 15;
    int nbase = blockIdx.x * 64 + wave * 16;
    u16* hb = hbuf[wave];
    const u16* wigb = wb;
    const u16* whhb = wb + 4096;
    const u16* wihb = wb + 16384;

    // ---- stage hx -> hb (bf16), coalesced float4 reads ----
    {
        int c = lane & 15;
        int mrow = lane >> 4;
#pragma unroll
        for (int rep = 0; rep < 4; ++rep) {
            int m = rep * 4 + mrow;
            int node = nbase + m;
            float4 v = make_float4(0.f, 0.f, 0.f, 0.f);
            if (node < NN)
                v = *(const float4*)(outp + (size_t)node * 256 + (size_t)it * 64 + c * 4);
            u16* p = &hb[m * 68 + c * 4];
            p[0] = f2bf(v.x); p[1] = f2bf(v.y); p[2] = f2bf(v.z); p[3] = f2bf(v.w);
        }
    }
    // (wave-private buffer; in-order DS pipe makes a barrier unnecessary)

    // ---- hx A-frags + hx in C-layout ----
    s16x8 ahx[2];
    ahx[0] = lds_frag(&hb[t * 68 + q * 8]);
    ahx[1] = lds_frag(&hb[t * 68 + 32 + q * 8]);
    u16 hxc[4][4];
#pragma unroll
    for (int ni = 0; ni < 4; ++ni)
#pragma unroll
        for (int r = 0; r < 4; ++r)
            hxc[ni][r] = hb[(q * 4 + r) * 68 + ni * 16 + t];

    // ---- gate GEMM: sigmoid(hx @ Wig^T + big) * agg -> inp (to hb) ----
#pragma unroll
    for (int ni = 0; ni < 4; ++ni) {
        float bg = big[ni * 16 + t];
        s16x8 b0 = gfrag(wigb, ni * 16 + t, 0, q);
        s16x8 b1 = gfrag(wigb, ni * 16 + t, 1, q);
        f32x4 acc = {bg, bg, bg, bg};
        acc = __builtin_amdgcn_mfma_f32_16x16x32_bf16(ahx[0], b0, acc, 0, 0, 0);
        acc = __builtin_amdgcn_mfma_f32_16x16x32_bf16(ahx[1], b1, acc, 0, 0, 0);
#pragma unroll
        for (int r = 0; r < 4; ++r) {
            int node = nbase + q * 4 + r;
            float av = (node < NN) ? agg[(size_t)node * 64 + ni * 16 + t] : 0.f;
            float iv = sigmoidf_(acc[r]) * av;
            hb[(q * 4 + r) * 68 + ni * 16 + t] = f2bf(iv);
        }
    }

    // ---- gh = hx @ Whh^T  (12 tiles, packed bf16 in regs + stats) ----
    float sgh[4] = {0.f, 0.f, 0.f, 0.f}, qgh[4] = {0.f, 0.f, 0.f, 0.f};
    u32 ghp[12][2];
#pragma unroll
    for (int ni = 0; ni < 12; ++ni) {
        s16x8 b0 = gfrag(whhb, ni * 16 + t, 0, q);
        s16x8 b1 = gfrag(whhb, ni * 16 + t, 1, q);
        f32x4 acc = {0.f, 0.f, 0.f, 0.f};
        acc = __builtin_amdgcn_mfma_f32_16x16x32_bf16(ahx[0], b0, acc, 0, 0, 0);
        acc = __builtin_amdgcn_mfma_f32_16x16x32_bf16(ahx[1], b1, acc, 0, 0, 0);
#pragma unroll
        for (int r = 0; r < 4; ++r) { sgh[r] += acc[r]; qgh[r] += acc[r] * acc[r]; }
        ghp[ni][0] = pack2(acc[0], acc[1]);
        ghp[ni][1] = pack2(acc[2], acc[3]);
    }

    // ---- inp A-frags (after LDS write above; same-wave ordering) ----
    s16x8 ain[2];
    ain[0] = lds_frag(&hb[t * 68 + q * 8]);
    ain[1] = lds_frag(&hb[t * 68 + 32 + q * 8]);

    // ---- gi = inp @ Wih^T ----
    float sgi[4] = {0.f, 0.f, 0.f, 0.f}, qgi[4] = {0.f, 0.f, 0.f, 0.f};
    u32 gip[12][2];
#pragma unroll
    for (int ni = 0; ni < 12; ++ni) {
        s16x8 b0 = gfrag(wihb, ni * 16 + t, 0, q);
        s16x8 b1 = gfrag(wihb, ni * 16 + t, 1, q);
        f32x4 acc = {0.f, 0.f, 0.f, 0.f};
        acc = __builtin_amdgcn_mfma_f32_16x16x32_bf16(ain[0], b0, acc, 0, 0, 0);
        acc = __builtin_amdgcn_mfma_f32_16x16x32_bf16(ain[1], b1, acc, 0, 0, 0);
#pragma unroll
        for (int r = 0; r < 4; ++r) { sgi[r] += acc[r]; qgi[r] += acc[r] * acc[r]; }
        gip[ni][0] = pack2(acc[0], acc[1]);
        gip[ni][1] = pack2(acc[2], acc[3]);
    }

    // ---- reduce stats over t-group ----
#pragma unroll
    for (int m = 1; m < 16; m <<= 1) {
#pragma unroll
        for (int r = 0; r < 4; ++r) {
            sgh[r] += __shfl_xor(sgh[r], m, 64);
            qgh[r] += __shfl_xor(qgh[r], m, 64);
            sgi[r] += __shfl_xor(sgi[r], m, 64);
            qgi[r] += __shfl_xor(qgi[r], m, 64);
        }
    }
    float mi_[4], ri_[4], mh_[4], rh_[4];
#pragma unroll
    for (int r = 0; r < 4; ++r) {
        mi_[r] = sgi[r] * (1.f / 192.f);
        mh_[r] = sgh[r] * (1.f / 192.f);
        ri_[r] = rsqrtf(qgi[r] * (1.f / 192.f) - mi_[r] * mi_[r] + EPSI);
        rh_[r] = rsqrtf(qgh[r] * (1.f / 192.f) - mh_[r] * mh_[r] + EPSI);
    }

    // ---- gates + hx update + store ----
#pragma unroll
    for (int ni = 0; ni < 4; ++ni) {
        int f = ni * 16 + t;
        float bi_r = bih[f], bi_i = bih[64 + f], bi_n = bih[128 + f];
        float bh_r = bhh[f], bh_i = bhh[64 + f], bh_n = bhh[128 + f];
#pragma unroll
        for (int r = 0; r < 4; ++r) {
            int node = nbase + q * 4 + r;
            float iv_r = (unpk(gip[ni], r) - mi_[r]) * ri_[r];
            float iv_i = (unpk(gip[ni + 4], r) - mi_[r]) * ri_[r];
            float iv_n = (unpk(gip[ni + 8], r) - mi_[r]) * ri_[r];
            float hv_r = (unpk(ghp[ni], r) - mh_[r]) * rh_[r];
            float hv_i = (unpk(ghp[ni + 4], r) - mh_[r]) * rh_[r];
            float hv_n = (unpk(ghp[ni + 8], r) - mh_[r]) * rh_[r];
            float rg = sigmoidf_(iv_r + bi_r + hv_r + bh_r);
            float zg = sigmoidf_(iv_i + bi_i + hv_i + bh_i);
            float ng = tanhf(iv_n + bi_n + rg * (hv_n + bh_n));
            float ho = bf2f(hxc[ni][r]);
            float res = ng + zg * (ho - ng);
            if (node < NN)
                outp[(size_t)node * 256 + (size_t)(it + 1) * 64 + f] = res;
        }
    }
}

extern "C" void kernel_launch(void* const* d_in, const int* in_sizes, int n_in,
                              void* d_out, int out_size, void* d_ws, size_t ws_size,
                              hipStream_t stream)
{
    const float* hx  = (const float*)d_in[0];
    const int*   eix = (const int*)d_in[1];
    const float* ef  = (const float*)d_in[2];
    const float* fW1 = (const float*)d_in[3];
    const float* fb1 = (const float*)d_in[4];
    const float* fW2 = (const float*)d_in[5];
    const float* fb2 = (const float*)d_in[6];
    const float* fW3 = (const float*)d_in[7];
    const float* fb3 = (const float*)d_in[8];
    const float* Wih = (const float*)d_in[9];
    const float* Whh = (const float*)d_in[10];
    const float* bih = (const float*)d_in[11];
    const float* bhh = (const float*)d_in[12];
    const float* Wig = (const float*)d_in[13];
    const float* big = (const float*)d_in[14];
    float* outp = (float*)d_out;
    char* ws = (char*)d_ws;

    u16*    w      = (u16*)(ws + WS_W);
    float*  agg    = (float*)(ws + WS_AGG);
    u16*    wb     = (u16*)(ws + WS_WB);
    float*  invdeg = (float*)(ws + WS_INVDEG);
    int*    counts = (int*)(ws + WS_COUNTS);
    int*    rowst  = (int*)(ws + WS_ROWSTART);
    int*    cursor = (int*)(ws + WS_CURSOR);
    int*    bsum   = (int*)(ws + WS_BSUM);
    int*    bsumex = (int*)(ws + WS_BSUMEX);
    int*    srcs   = (int*)(ws + WS_SRC);
    int*    eperm  = (int*)(ws + WS_EPERM);

    hipMemsetAsync(counts, 0, NN * sizeof(int), stream);
    k_prep_w<<<112, 256, 0, stream>>>(Wig, Whh, Wih, wb);
    k_count<<<(NE + 255) / 256, 256, 0, stream>>>(eix, counts);
    k_scan_partial<<<391, 256, 0, stream>>>(counts, bsum);
    k_scan_bsum<<<1, 512, 0, stream>>>(bsum, bsumex);
    k_scan_final<<<391, 256, 0, stream>>>(counts, bsumex, rowst, cursor, invdeg);
    k_scatter<<<(NE + 255) / 256, 256, 0, stream>>>(eix, cursor, srcs, eperm);
    k_fnet_mfma<<<9766, 256, 0, stream>>>(ef, fW1, fb1, fW2, fb2, fW3, fb3, eperm, w);
    k_init<<<6250, 256, 0, stream>>>((const float4*)hx, outp);

    for (int it = 0; it < 3; ++it) {
        k_agg<<<25000, 256, 0, stream>>>(outp, w, srcs, rowst, invdeg, agg, it);
        k_gru_fused<<<1563, 256, 0, stream>>>(outp, agg, wb, big, bih, bhh, it);
    }
}

// Round 4
// 854.886 us; speedup vs baseline: 1.0585x; 1.0023x over previous
//
#include <hip/hip_runtime.h>
#include <math.h>

#define NN 100000
#define NE 1250000
#define EPSI 1e-5f

// ---- workspace layout (bytes) ----
#define WS_W        0ull          // bf16 [NE*64]            160,000,000  (CSR-ordered)
#define WS_AGG      160000000ull  // f32  [NN*64]             25,600,000
#define WS_WB       185600000ull  // bf16 weights: Wig[4096] Whh[12288] Wih[12288]
#define WS_INVDEG   264000000ull  // f32 [NN]
#define WS_COUNTS   264400000ull  // i32 [NN]
#define WS_ROWSTART 264800000ull  // i32 [NN+1]
#define WS_CURSOR   265200128ull  // i32 [NN]
#define WS_BSUM     265600128ull  // i32 [391]
#define WS_BSUMEX   265601792ull  // i32 [391]
#define WS_SRC      265603584ull  // i32 [NE]  src node per CSR slot       5,000,000
#define WS_EPERM    270603584ull  // i32 [NE]  edge id -> CSR slot         5,000,000

typedef unsigned short u16;
typedef unsigned int u32;
typedef short s16x4 __attribute__((ext_vector_type(4)));
typedef short s16x8 __attribute__((ext_vector_type(8)));
typedef float f32x4 __attribute__((ext_vector_type(4)));
typedef u32 u32x4 __attribute__((ext_vector_type(4)));
typedef u32 u32x2 __attribute__((ext_vector_type(2)));
typedef float f32x4u __attribute__((ext_vector_type(4), aligned(4)));

__device__ __forceinline__ u16 f2bf(float f) {
    u32 u = __float_as_uint(f);
    return (u16)((u + 0x7fffu + ((u >> 16) & 1u)) >> 16);   // RNE
}
__device__ __forceinline__ float bf2f(u16 b) {
    return __uint_as_float(((u32)b) << 16);
}
__device__ __forceinline__ u32 pack2(float lo, float hi) {
    return (u32)f2bf(lo) | ((u32)f2bf(hi) << 16);
}
// packed f32x2 -> bf16x2 (RNE), 1 VALU op
__device__ __forceinline__ u32 cvtpk(float lo, float hi) {
    u32 r;
    asm("v_cvt_pk_bf16_f32 %0, %1, %2" : "=v"(r) : "v"(lo), "v"(hi));
    return r;
}
__device__ __forceinline__ float sigmoidf_(float x) {
    return 1.f / (1.f + __expf(-x));
}
__device__ __forceinline__ s16x8 lds_frag(const u16* p) {
    s16x4 lo = *(const s16x4*)p;
    s16x4 hi = *(const s16x4*)(p + 4);
    return __builtin_shufflevector(lo, hi, 0, 1, 2, 3, 4, 5, 6, 7);
}
__device__ __forceinline__ s16x8 gfrag(const u16* W, int n, int ks, int q) {
    // W row-major [64 cols], 16-byte aligned chunks
    return *(const s16x8*)(W + n * 64 + ks * 32 + q * 8);
}
__device__ __forceinline__ float unpk(const u32* p, int r) {
    u32 v = p[r >> 1];
    return bf2f((u16)((r & 1) ? (v >> 16) : (v & 0xffffu)));
}

// ============ fnet via MFMA: per-edge MLP 13->64->64->64, bf16 out ============
// R0 dataflow (LDS transpose between layers) but with all weight matrices
// ROW-PERMUTED by p(n)=4*(n&15)+(n>>4) at staging time. Then lane (q,t)'s
// four ni-values are TRUE feats 4t..4t+3 (contiguous), so transitions pack
// with v_cvt_pk_bf16_f32 + one ds_write_b64 (vs 4 f2bf + 4 ds_write_u16),
// layer 3 stores straight from registers (no LDS epilogue), and every buffer
// stays in true feature order (identity: value of feat 4t+ni lands at col
// 4t+ni). Output rows scattered to CSR slot eperm[e] so k_agg streams w.
__global__ __launch_bounds__(256) void k_fnet_mfma(
    const float* __restrict__ ef,
    const float* __restrict__ W1, const float* __restrict__ b1,
    const float* __restrict__ W2, const float* __restrict__ b2,
    const float* __restrict__ W3, const float* __restrict__ b3,
    const int* __restrict__ eperm,
    u16* __restrict__ wout)
{
    __shared__ u16 w1l[64 * 16];
    __shared__ u16 w2l[64 * 68];
    __shared__ u16 w3l[64 * 68];
    __shared__ u16 hbuf[4][32 * 68];

    int tid = threadIdx.x;
    for (int i = tid; i < 64 * 16; i += 256) w1l[i] = 0;
    for (int i = tid; i < 4096; i += 256) {
        int n = i >> 6, k = i & 63;
        int pn = ((n & 15) << 2) + (n >> 4);          // row perm p(n)
        w2l[n * 68 + k] = f2bf(W2[pn * 64 + k]);
        w3l[n * 68 + k] = f2bf(W3[pn * 64 + k]);
    }
    __syncthreads();
    for (int i = tid; i < 832; i += 256) {
        int n = i / 13, k = i - n * 13;
        int pn = ((n & 15) << 2) + (n >> 4);
        w1l[n * 16 + k] = f2bf(W1[pn * 13 + k]);
    }
    __syncthreads();

    int wave = tid >> 6, lane = tid & 63;
    int q = lane >> 4, t = lane & 15;
    int ebase = blockIdx.x * 128 + wave * 32;
    u16* hb = hbuf[wave];

    // biases in permuted slot order: slot (ni,t) holds true feat 4t+ni
    f32x4 b1v = *(const f32x4*)(b1 + 4 * t);
    f32x4 b2v = *(const f32x4*)(b2 + 4 * t);
    f32x4 b3v = *(const f32x4*)(b3 + 4 * t);

    const s16x8 zfrag = {0, 0, 0, 0, 0, 0, 0, 0};

    // ---- ef fragments: vector loads + packed converts ----
    s16x8 a1[2];
#pragma unroll
    for (int mi = 0; mi < 2; ++mi) {
        int e = ebase + mi * 16 + t;
        u32 xp[4] = {0u, 0u, 0u, 0u};
        if (e < NE) {
            const float* ep = ef + (size_t)e * 13;
            if (q == 0) {
                f32x4u v0 = *(const f32x4u*)(ep);
                f32x4u v1 = *(const f32x4u*)(ep + 4);
                xp[0] = cvtpk(v0[0], v0[1]); xp[1] = cvtpk(v0[2], v0[3]);
                xp[2] = cvtpk(v1[0], v1[1]); xp[3] = cvtpk(v1[2], v1[3]);
            } else if (q == 1) {
                f32x4u v0 = *(const f32x4u*)(ep + 8);
                float v12 = ep[12];
                xp[0] = cvtpk(v0[0], v0[1]); xp[1] = cvtpk(v0[2], v0[3]);
                xp[2] = cvtpk(v12, 0.f);
            }
        }
        a1[mi] = __builtin_bit_cast(s16x8, *(u32x4*)xp);
    }

    // ---- W1 fragments ----
    s16x8 B1f[4];
#pragma unroll
    for (int ni = 0; ni < 4; ++ni) {
        s16x8 b = zfrag;
        if (q < 2) b = lds_frag(&w1l[(ni * 16 + t) * 16 + q * 8]);
        B1f[ni] = b;
    }

    // ---- layer 1 ----
    f32x4 h1[4][2];
#pragma unroll
    for (int ni = 0; ni < 4; ++ni)
#pragma unroll
        for (int mi = 0; mi < 2; ++mi) {
            f32x4 acc = {b1v[ni], b1v[ni], b1v[ni], b1v[ni]};
            acc = __builtin_amdgcn_mfma_f32_16x16x32_bf16(a1[mi], B1f[ni], acc, 0, 0, 0);
            h1[ni][mi] = acc;
        }
    // transition 1: relu + pack + b64 write (cols 4t..4t+3 contiguous)
#pragma unroll
    for (int mi = 0; mi < 2; ++mi)
#pragma unroll
        for (int r = 0; r < 4; ++r) {
            u32 lo = cvtpk(fmaxf(h1[0][mi][r], 0.f), fmaxf(h1[1][mi][r], 0.f));
            u32 hi = cvtpk(fmaxf(h1[2][mi][r], 0.f), fmaxf(h1[3][mi][r], 0.f));
            u32x2 v = {lo, hi};
            *(u32x2*)(&hb[(mi * 16 + q * 4 + r) * 68 + 4 * t]) = v;
        }

    // ---- layer 2 ----
    s16x8 a2[2][2];
#pragma unroll
    for (int mi = 0; mi < 2; ++mi)
#pragma unroll
        for (int ks = 0; ks < 2; ++ks)
            a2[mi][ks] = lds_frag(&hb[(mi * 16 + t) * 68 + ks * 32 + q * 8]);
    f32x4 h2[4][2];
#pragma unroll
    for (int ni = 0; ni < 4; ++ni) {
        s16x8 w0 = lds_frag(&w2l[(ni * 16 + t) * 68 + q * 8]);
        s16x8 w1_ = lds_frag(&w2l[(ni * 16 + t) * 68 + 32 + q * 8]);
#pragma unroll
        for (int mi = 0; mi < 2; ++mi) {
            f32x4 acc = {b2v[ni], b2v[ni], b2v[ni], b2v[ni]};
            acc = __builtin_amdgcn_mfma_f32_16x16x32_bf16(a2[mi][0], w0, acc, 0, 0, 0);
            acc = __builtin_amdgcn_mfma_f32_16x16x32_bf16(a2[mi][1], w1_, acc, 0, 0, 0);
            h2[ni][mi] = acc;
        }
    }
    // transition 2
#pragma unroll
    for (int mi = 0; mi < 2; ++mi)
#pragma unroll
        for (int r = 0; r < 4; ++r) {
            u32 lo = cvtpk(fmaxf(h2[0][mi][r], 0.f), fmaxf(h2[1][mi][r], 0.f));
            u32 hi = cvtpk(fmaxf(h2[2][mi][r], 0.f), fmaxf(h2[3][mi][r], 0.f));
            u32x2 v = {lo, hi};
            *(u32x2*)(&hb[(mi * 16 + q * 4 + r) * 68 + 4 * t]) = v;
        }

    // ---- layer 3: registers -> global, no LDS epilogue ----
    s16x8 a3[2][2];
#pragma unroll
    for (int mi = 0; mi < 2; ++mi)
#pragma unroll
        for (int ks = 0; ks < 2; ++ks)
            a3[mi][ks] = lds_frag(&hb[(mi * 16 + t) * 68 + ks * 32 + q * 8]);
    f32x4 h3[4][2];
#pragma unroll
    for (int ni = 0; ni < 4; ++ni) {
        s16x8 w0 = lds_frag(&w3l[(ni * 16 + t) * 68 + q * 8]);
        s16x8 w1_ = lds_frag(&w3l[(ni * 16 + t) * 68 + 32 + q * 8]);
#pragma unroll
        for (int mi = 0; mi < 2; ++mi) {
            f32x4 acc = {b3v[ni], b3v[ni], b3v[ni], b3v[ni]};
            acc = __builtin_amdgcn_mfma_f32_16x16x32_bf16(a3[mi][0], w0, acc, 0, 0, 0);
            acc = __builtin_amdgcn_mfma_f32_16x16x32_bf16(a3[mi][1], w1_, acc, 0, 0, 0);
            h3[ni][mi] = acc;
        }
    }
    // CSR positions for this lane's 8 edges (safe-clamped int4 loads)
    int base0 = ebase + q * 4;
    int base1 = ebase + 16 + q * 4;
    int4 pos0 = *(const int4*)(eperm + ((base0 + 3 < NE) ? base0 : 0));
    int4 pos1 = *(const int4*)(eperm + ((base1 + 3 < NE) ? base1 : 0));
#pragma unroll
    for (int mi = 0; mi < 2; ++mi)
#pragma unroll
        for (int r = 0; r < 4; ++r) {
            int e = ebase + mi * 16 + q * 4 + r;
            if (e < NE) {
                int pos = mi ? ((const int*)&pos1)[r] : ((const int*)&pos0)[r];
                u32x2 v = {cvtpk(h3[0][mi][r], h3[1][mi][r]),
                           cvtpk(h3[2][mi][r], h3[3][mi][r])};
                *(u32x2*)(wout + (size_t)pos * 64 + 4 * t) = v;
            }
        }
}

// ---------------- prep: convert GRU weights to bf16 row-major ----------------
__global__ void k_prep_w(const float* __restrict__ Wig, const float* __restrict__ Whh,
                         const float* __restrict__ Wih, u16* __restrict__ wb)
{
    int i = blockIdx.x * 256 + threadIdx.x;   // < 28672
    if (i < 4096) wb[i] = f2bf(Wig[i]);
    else if (i < 16384) wb[i] = f2bf(Whh[i - 4096]);
    else if (i < 28672) wb[i] = f2bf(Wih[i - 16384]);
}

// ---------------- degree counting ----------------
__global__ void k_count(const int* __restrict__ idx, int* __restrict__ counts)
{
    int e = blockIdx.x * 256 + threadIdx.x;
    if (e < NE) atomicAdd(&counts[idx[e]], 1);
}

// ---------------- two-level exclusive scan over counts ----------------
__global__ void k_scan_partial(const int* __restrict__ counts, int* __restrict__ bsum)
{
    __shared__ int s[256];
    int i = blockIdx.x * 256 + threadIdx.x;
    int v = (i < NN) ? counts[i] : 0;
    s[threadIdx.x] = v; __syncthreads();
    for (int off = 128; off > 0; off >>= 1) {
        if (threadIdx.x < off) s[threadIdx.x] += s[threadIdx.x + off];
        __syncthreads();
    }
    if (threadIdx.x == 0) bsum[blockIdx.x] = s[0];
}

__global__ void k_scan_bsum(const int* __restrict__ bsum, int* __restrict__ bsumex)
{
    __shared__ int s[512];
    int t = threadIdx.x;
    int v0 = (t < 391) ? bsum[t] : 0;
    s[t] = v0; __syncthreads();
    for (int off = 1; off < 512; off <<= 1) {
        int add = (t >= off) ? s[t - off] : 0;
        __syncthreads();
        s[t] += add;
        __syncthreads();
    }
    if (t < 391) bsumex[t] = s[t] - v0;
}

__global__ void k_scan_final(const int* __restrict__ counts, const int* __restrict__ bsumex,
                             int* __restrict__ rowstart, int* __restrict__ cursor,
                             float* __restrict__ invdeg)
{
    __shared__ int s[256];
    int t = threadIdx.x;
    int i = blockIdx.x * 256 + t;
    int c = (i < NN) ? counts[i] : 0;
    s[t] = c; __syncthreads();
    for (int off = 1; off < 256; off <<= 1) {
        int add = (t >= off) ? s[t - off] : 0;
        __syncthreads();
        s[t] += add;
        __syncthreads();
    }
    int ex = s[t] - c + bsumex[blockIdx.x];
    if (i < NN) {
        rowstart[i] = ex;
        cursor[i] = ex;
        invdeg[i] = 1.f / (float)(c > 1 ? c : 1);
    }
    if (i == 0) rowstart[NN] = NE;
}

// ------- scatter edges into CSR order: srcs[p]=src, eperm[e]=p -------
__global__ void k_scatter(const int* __restrict__ idx, int* __restrict__ cursor,
                          int* __restrict__ srcs, int* __restrict__ eperm)
{
    int e = blockIdx.x * 256 + threadIdx.x;
    if (e < NE) {
        int d = idx[e];
        int s = idx[NE + e];
        int p = atomicAdd(&cursor[d], 1);
        srcs[p] = s;
        eperm[e] = p;
    }
}

// ---------------- copy hx0 into out column 0 ----------------
__global__ void k_init(const float4* __restrict__ hx4, float* __restrict__ outp)
{
    int i = blockIdx.x * 256 + threadIdx.x;
    int n = i >> 4, q = i & 15;
    ((float4*)(outp + (size_t)n * 256))[q] = hx4[i];
}

// ------- aggregation: wave per node; w streams sequentially (CSR order) -------
__global__ __launch_bounds__(256) void k_agg(
    const float* __restrict__ outp, const u16* __restrict__ w,
    const int* __restrict__ srcs, const int* __restrict__ rowstart,
    const float* __restrict__ invdeg, float* __restrict__ agg, int it)
{
    int lane = threadIdx.x & 63;
    int n = blockIdx.x * 4 + (threadIdx.x >> 6);
    n = __builtin_amdgcn_readfirstlane(n);
    int p0 = rowstart[n], p1 = rowstart[n + 1];
    const float* hxcol = outp + (size_t)it * 64 + lane;
    const u16* wp = w + (size_t)p0 * 64 + lane;
    float a0 = 0.f, a1 = 0.f, a2 = 0.f, a3 = 0.f;
    int p = p0;
    for (; p + 4 <= p1; p += 4) {
        int4 s4 = *(const int4*)(srcs + p);          // wave-uniform -> s_load
        float h0 = hxcol[(size_t)s4.x * 256];
        float h1 = hxcol[(size_t)s4.y * 256];
        float h2 = hxcol[(size_t)s4.z * 256];
        float h3 = hxcol[(size_t)s4.w * 256];
        float w0 = bf2f(__builtin_nontemporal_load(wp));
        float w1 = bf2f(__builtin_nontemporal_load(wp + 64));
        float w2 = bf2f(__builtin_nontemporal_load(wp + 128));
        float w3 = bf2f(__builtin_nontemporal_load(wp + 192));
        wp += 256;
        a0 = fmaf(h0, w0, a0);
        a1 = fmaf(h1, w1, a1);
        a2 = fmaf(h2, w2, a2);
        a3 = fmaf(h3, w3, a3);
    }
    for (; p < p1; ++p) {
        int s = srcs[p];
        float hv = hxcol[(size_t)s * 256];
        float wv = bf2f(__builtin_nontemporal_load(wp));
        wp += 64;
        a0 = fmaf(hv, wv, a0);
    }
    agg[(size_t)n * 64 + lane] = ((a0 + a1) + (a2 + a3)) * invdeg[n];
}

// ======== fused GRU: gate GEMM + gi/gh MFMA + inorm + gates, all in-kernel ========
__global__ __launch_bounds__(256) void k_gru_fused(
    float* __restrict__ outp, const float* __restrict__ agg,
    const u16* __restrict__ wb,
    const float* __restrict__ big, const float* __restrict__ bih,
    const float* __restrict__ bhh, int it)
{
    __shared__ u16 hbuf[4][16 * 68];
    int tid = threadIdx.x;
    int wave = tid >> 6, lane = tid & 63;
    int q = lane >> 4, t = lane & 15;
    int nbase = blockIdx.x * 64 + wave * 16;
    u16* hb = hbuf[wave];
    const u16* wigb = wb;
    const u16* whhb = wb + 4096;
    const u16* wihb = wb + 16384;

    // ---- stage hx -> hb (bf16), coalesced float4 reads ----
    {
        int c = lane & 15;
        int mrow = lane >> 4;
#pragma unroll
        for (int rep = 0; rep < 4; ++rep) {
            int m = rep * 4 + mrow;
            int node = nbase + m;
            float4 v = make_float4(0.f, 0.f, 0.f, 0.f);
            if (node < NN)
                v = *(const float4*)(outp + (size_t)node * 256 + (size_t)it * 64 + c * 4);
            u16* p = &hb[m * 68 + c * 4];
            p[0] = f2bf(v.x); p[1] = f2bf(v.y); p[2] = f2bf(v.z); p[3] = f2bf(v.w);
        }
    }
    // (wave-private buffer; in-order DS pipe makes a barrier unnecessary)

    // ---- hx A-frags + hx in C-layout ----
    s16x8 ahx[2];
    ahx[0] = lds_frag(&hb[t * 68 + q * 8]);
    ahx[1] = lds_frag(&hb[t * 68 + 32 + q * 8]);
    u16 hxc[4][4];
#pragma unroll
    for (int ni = 0; ni < 4; ++ni)
#pragma unroll
        for (int r = 0; r < 4; ++r)
            hxc[ni][r] = hb[(q * 4 + r) * 68 + ni * 16 + t];

    // ---- gate GEMM: sigmoid(hx @ Wig^T + big) * agg -> inp (to hb) ----
#pragma unroll
    for (int ni = 0; ni < 4; ++ni) {
        float bg = big[ni * 16 + t];
        s16x8 b0 = gfrag(wigb, ni * 16 + t, 0, q);
        s16x8 b1 = gfrag(wigb, ni * 16 + t, 1, q);
        f32x4 acc = {bg, bg, bg, bg};
        acc = __builtin_amdgcn_mfma_f32_16x16x32_bf16(ahx[0], b0, acc, 0, 0, 0);
        acc = __builtin_amdgcn_mfma_f32_16x16x32_bf16(ahx[1], b1, acc, 0, 0, 0);
#pragma unroll
        for (int r = 0; r < 4; ++r) {
            int node = nbase + q * 4 + r;
            float av = (node < NN) ? agg[(size_t)node * 64 + ni * 16 + t] : 0.f;
            float iv = sigmoidf_(acc[r]) * av;
            hb[(q * 4 + r) * 68 + ni * 16 + t] = f2bf(iv);
        }
    }

    // ---- gh = hx @ Whh^T  (12 tiles, packed bf16 in regs + stats) ----
    float sgh[4] = {0.f, 0.f, 0.f, 0.f}, qgh[4] = {0.f, 0.f, 0.f, 0.f};
    u32 ghp[12][2];
#pragma unroll
    for (int ni = 0; ni < 12; ++ni) {
        s16x8 b0 = gfrag(whhb, ni * 16 + t, 0, q);
        s16x8 b1 = gfrag(whhb, ni * 16 + t, 1, q);
        f32x4 acc = {0.f, 0.f, 0.f, 0.f};
        acc = __builtin_amdgcn_mfma_f32_16x16x32_bf16(ahx[0], b0, acc, 0, 0, 0);
        acc = __builtin_amdgcn_mfma_f32_16x16x32_bf16(ahx[1], b1, acc, 0, 0, 0);
#pragma unroll
        for (int r = 0; r < 4; ++r) { sgh[r] += acc[r]; qgh[r] += acc[r] * acc[r]; }
        ghp[ni][0] = pack2(acc[0], acc[1]);
        ghp[ni][1] = pack2(acc[2], acc[3]);
    }

    // ---- inp A-frags (after LDS write above; same-wave ordering) ----
    s16x8 ain[2];
    ain[0] = lds_frag(&hb[t * 68 + q * 8]);
    ain[1] = lds_frag(&hb[t * 68 + 32 + q * 8]);

    // ---- gi = inp @ Wih^T ----
    float sgi[4] = {0.f, 0.f, 0.f, 0.f}, qgi[4] = {0.f, 0.f, 0.f, 0.f};
    u32 gip[12][2];
#pragma unroll
    for (int ni = 0; ni < 12; ++ni) {
        s16x8 b0 = gfrag(wihb, ni * 16 + t, 0, q);
        s16x8 b1 = gfrag(wihb, ni * 16 + t, 1, q);
        f32x4 acc = {0.f, 0.f, 0.f, 0.f};
        acc = __builtin_amdgcn_mfma_f32_16x16x32_bf16(ain[0], b0, acc, 0, 0, 0);
        acc = __builtin_amdgcn_mfma_f32_16x16x32_bf16(ain[1], b1, acc, 0, 0, 0);
#pragma unroll
        for (int r = 0; r < 4; ++r) { sgi[r] += acc[r]; qgi[r] += acc[r] * acc[r]; }
        gip[ni][0] = pack2(acc[0], acc[1]);
        gip[ni][1] = pack2(acc[2], acc[3]);
    }

    // ---- reduce stats over t-group ----
#pragma unroll
    for (int m = 1; m < 16; m <<= 1) {
#pragma unroll
        for (int r = 0; r < 4; ++r) {
            sgh[r] += __shfl_xor(sgh[r], m, 64);
            qgh[r] += __shfl_xor(qgh[r], m, 64);
            sgi[r] += __shfl_xor(sgi[r], m, 64);
            qgi[r] += __shfl_xor(qgi[r], m, 64);
        }
    }
    float mi_[4], ri_[4], mh_[4], rh_[4];
#pragma unroll
    for (int r = 0; r < 4; ++r) {
        mi_[r] = sgi[r] * (1.f / 192.f);
        mh_[r] = sgh[r] * (1.f / 192.f);
        ri_[r] = rsqrtf(qgi[r] * (1.f / 192.f) - mi_[r] * mi_[r] + EPSI);
        rh_[r] = rsqrtf(qgh[r] * (1.f / 192.f) - mh_[r] * mh_[r] + EPSI);
    }

    // ---- gates + hx update + store ----
#pragma unroll
    for (int ni = 0; ni < 4; ++ni) {
        int f = ni * 16 + t;
        float bi_r = bih[f], bi_i = bih[64 + f], bi_n = bih[128 + f];
        float bh_r = bhh[f], bh_i = bhh[64 + f], bh_n = bhh[128 + f];
#pragma unroll
        for (int r = 0; r < 4; ++r) {
            int node = nbase + q * 4 + r;
            float iv_r = (unpk(gip[ni], r) - mi_[r]) * ri_[r];
            float iv_i = (unpk(gip[ni + 4], r) - mi_[r]) * ri_[r];
            float iv_n = (unpk(gip[ni + 8], r) - mi_[r]) * ri_[r];
            float hv_r = (unpk(ghp[ni], r) - mh_[r]) * rh_[r];
            float hv_i = (unpk(ghp[ni + 4], r) - mh_[r]) * rh_[r];
            float hv_n = (unpk(ghp[ni + 8], r) - mh_[r]) * rh_[r];
            float rg = sigmoidf_(iv_r + bi_r + hv_r + bh_r);
            float zg = sigmoidf_(iv_i + bi_i + hv_i + bh_i);
            float ng = tanhf(iv_n + bi_n + rg * (hv_n + bh_n));
            float ho = bf2f(hxc[ni][r]);
            float res = ng + zg * (ho - ng);
            if (node < NN)
                outp[(size_t)node * 256 + (size_t)(it + 1) * 64 + f] = res;
        }
    }
}

extern "C" void kernel_launch(void* const* d_in, const int* in_sizes, int n_in,
                              void* d_out, int out_size, void* d_ws, size_t ws_size,
                              hipStream_t stream)
{
    const float* hx  = (const float*)d_in[0];
    const int*   eix = (const int*)d_in[1];
    const float* ef  = (const float*)d_in[2];
    const float* fW1 = (const float*)d_in[3];
    const float* fb1 = (const float*)d_in[4];
    const float* fW2 = (const float*)d_in[5];
    const float* fb2 = (const float*)d_in[6];
    const float* fW3 = (const float*)d_in[7];
    const float* fb3 = (const float*)d_in[8];
    const float* Wih = (const float*)d_in[9];
    const float* Whh = (const float*)d_in[10];
    const float* bih = (const float*)d_in[11];
    const float* bhh = (const float*)d_in[12];
    const float* Wig = (const float*)d_in[13];
    const float* big = (const float*)d_in[14];
    float* outp = (float*)d_out;
    char* ws = (char*)d_ws;

    u16*    w      = (u16*)(ws + WS_W);
    float*  agg    = (float*)(ws + WS_AGG);
    u16*    wb     = (u16*)(ws + WS_WB);
    float*  invdeg = (float*)(ws + WS_INVDEG);
    int*    counts = (int*)(ws + WS_COUNTS);
    int*    rowst  = (int*)(ws + WS_ROWSTART);
    int*    cursor = (int*)(ws + WS_CURSOR);
    int*    bsum   = (int*)(ws + WS_BSUM);
    int*    bsumex = (int*)(ws + WS_BSUMEX);
    int*    srcs   = (int*)(ws + WS_SRC);
    int*    eperm  = (int*)(ws + WS_EPERM);

    hipMemsetAsync(counts, 0, NN * sizeof(int), stream);
    k_prep_w<<<112, 256, 0, stream>>>(Wig, Whh, Wih, wb);
    k_count<<<(NE + 255) / 256, 256, 0, stream>>>(eix, counts);
    k_scan_partial<<<391, 256, 0, stream>>>(counts, bsum);
    k_scan_bsum<<<1, 512, 0, stream>>>(bsum, bsumex);
    k_scan_final<<<391, 256, 0, stream>>>(counts, bsumex, rowst, cursor, invdeg);
    k_scatter<<<(NE + 255) / 256, 256, 0, stream>>>(eix, cursor, srcs, eperm);
    k_fnet_mfma<<<9766, 256, 0, stream>>>(ef, fW1, fb1, fW2, fb2, fW3, fb3, eperm, w);
    k_init<<<6250, 256, 0, stream>>>((const float4*)hx, outp);

    for (int it = 0; it < 3; ++it) {
        k_agg<<<25000, 256, 0, stream>>>(outp, w, srcs, rowst, invdeg, agg, it);
        k_gru_fused<<<1563, 256, 0, stream>>>(outp, agg, wb, big, bih, bhh, it);
    }
}

// Round 5
// 843.232 us; speedup vs baseline: 1.0731x; 1.0138x over previous
//
#include <hip/hip_runtime.h>
#include <math.h>

#define NN 100000
#define NE 1250000
#define EPSI 1e-5f

// ---- workspace layout (bytes) ----
#define WS_W        0ull          // bf16 [NE*64]            160,000,000  (CSR-ordered)
#define WS_AGG      160000000ull  // f32  [NN*64]             25,600,000
#define WS_WB       185600000ull  // bf16 weights (see k_prep_w)
#define WS_INVDEG   264000000ull  // f32 [NN]
#define WS_COUNTS   264400000ull  // i32 [NN]
#define WS_ROWSTART 264800000ull  // i32 [NN+1]
#define WS_CURSOR   265200128ull  // i32 [NN]
#define WS_BSUM     265600128ull  // i32 [391]
#define WS_BSUMEX   265601792ull  // i32 [391]
#define WS_SRC      265603584ull  // i32 [NE]  src node per CSR slot       5,000,000
#define WS_EPERM    270603584ull  // i32 [NE]  edge id -> CSR slot         5,000,000

// wb (bf16) sub-layout, all row-permuted by p(n)=4*(n&15)+(n>>4) within
// each 64-row block:
//   [0)      Wig   64x64
//   [4096)   Whh  192x64   (perm within each gate's 64 rows)
//   [16384)  Wih  192x64   (perm within each gate's 64 rows)
//   [28672)  W1    64x16   (13 cols + 3 zero pad)
//   [29696)  W2    64x64
//   [33792)  W3    64x64   -> total 37888 elements
#define WB_TOTAL 37888

typedef unsigned short u16;
typedef unsigned int u32;
typedef short s16x4 __attribute__((ext_vector_type(4)));
typedef short s16x8 __attribute__((ext_vector_type(8)));
typedef float f32x4 __attribute__((ext_vector_type(4)));
typedef u32 u32x4 __attribute__((ext_vector_type(4)));
typedef u32 u32x2 __attribute__((ext_vector_type(2)));
typedef float f32x4u __attribute__((ext_vector_type(4), aligned(4)));

__device__ __forceinline__ u16 f2bf(float f) {
    u32 u = __float_as_uint(f);
    return (u16)((u + 0x7fffu + ((u >> 16) & 1u)) >> 16);   // RNE
}
__device__ __forceinline__ float bf2f(u16 b) {
    return __uint_as_float(((u32)b) << 16);
}
// packed f32x2 -> bf16x2 (RNE), 1 VALU op
__device__ __forceinline__ u32 cvtpk(float lo, float hi) {
    u32 r;
    asm("v_cvt_pk_bf16_f32 %0, %1, %2" : "=v"(r) : "v"(lo), "v"(hi));
    return r;
}
__device__ __forceinline__ float sigmoidf_(float x) {
    return 1.f / (1.f + __expf(-x));
}
// tanh via exp, saturating at +-1; ~4 VALU ops vs libm tanhf's ~20
__device__ __forceinline__ float tanhf_(float x) {
    float e = __expf(2.f * x);
    return 1.f - 2.f / (e + 1.f);
}
__device__ __forceinline__ s16x8 lds_frag(const u16* p) {
    s16x4 lo = *(const s16x4*)p;
    s16x4 hi = *(const s16x4*)(p + 4);
    return __builtin_shufflevector(lo, hi, 0, 1, 2, 3, 4, 5, 6, 7);
}
__device__ __forceinline__ s16x8 gfrag(const u16* W, int n, int ks, int q) {
    // W row-major [64 cols], 16-byte aligned chunks
    return *(const s16x8*)(W + n * 64 + ks * 32 + q * 8);
}
__device__ __forceinline__ float unpk(const u32* p, int r) {
    u32 v = p[r >> 1];
    return bf2f((u16)((r & 1) ? (v >> 16) : (v & 0xffffu)));
}

// ============ fnet via MFMA: per-edge MLP 13->64->64->64, bf16 out ============
// Weights read directly from prepped global bf16 (18KB -> L1-resident,
// k_gru_fused-proven pattern). No block-shared LDS, no __syncthreads ->
// LDS/block 36.9->17.4 KB, 8 blocks/CU. Row perm p(n) makes each lane's
// 4 tile-values true feats 4t..4t+3 (contiguous): transitions are
// 2 cvtpk + 1 ds_write_b64; layer-3 stores straight to global (CSR slot).
__global__ __launch_bounds__(256) void k_fnet_mfma(
    const float* __restrict__ ef,
    const float* __restrict__ b1, const float* __restrict__ b2,
    const float* __restrict__ b3,
    const int* __restrict__ eperm,
    const u16* __restrict__ wbf,
    u16* __restrict__ wout)
{
    __shared__ u16 hbuf[4][32 * 68];

    int tid = threadIdx.x;
    int wave = tid >> 6, lane = tid & 63;
    int q = lane >> 4, t = lane & 15;
    int ebase = blockIdx.x * 128 + wave * 32;
    u16* hb = hbuf[wave];
    const u16* wf1 = wbf + 28672;
    const u16* wf2 = wbf + 29696;
    const u16* wf3 = wbf + 33792;

    // biases in permuted slot order: slot (ni,t) holds true feat 4t+ni
    f32x4 b1v = *(const f32x4*)(b1 + 4 * t);
    f32x4 b2v = *(const f32x4*)(b2 + 4 * t);
    f32x4 b3v = *(const f32x4*)(b3 + 4 * t);

    const s16x8 zfrag = {0, 0, 0, 0, 0, 0, 0, 0};

    // ---- ef fragments: vector loads + packed converts ----
    s16x8 a1[2];
#pragma unroll
    for (int mi = 0; mi < 2; ++mi) {
        int e = ebase + mi * 16 + t;
        u32 xp[4] = {0u, 0u, 0u, 0u};
        if (e < NE) {
            const float* ep = ef + (size_t)e * 13;
            if (q == 0) {
                f32x4u v0 = *(const f32x4u*)(ep);
                f32x4u v1 = *(const f32x4u*)(ep + 4);
                xp[0] = cvtpk(v0[0], v0[1]); xp[1] = cvtpk(v0[2], v0[3]);
                xp[2] = cvtpk(v1[0], v1[1]); xp[3] = cvtpk(v1[2], v1[3]);
            } else if (q == 1) {
                f32x4u v0 = *(const f32x4u*)(ep + 8);
                float v12 = ep[12];
                xp[0] = cvtpk(v0[0], v0[1]); xp[1] = cvtpk(v0[2], v0[3]);
                xp[2] = cvtpk(v12, 0.f);
            }
        }
        a1[mi] = __builtin_bit_cast(s16x8, *(u32x4*)xp);
    }

    // ---- W1 fragments (global, zero-padded 16-col rows) ----
    s16x8 B1f[4];
#pragma unroll
    for (int ni = 0; ni < 4; ++ni) {
        s16x8 b = zfrag;
        if (q < 2) b = *(const s16x8*)(wf1 + (ni * 16 + t) * 16 + q * 8);
        B1f[ni] = b;
    }

    // ---- layer 1 ----
    f32x4 h1[4][2];
#pragma unroll
    for (int ni = 0; ni < 4; ++ni)
#pragma unroll
        for (int mi = 0; mi < 2; ++mi) {
            f32x4 acc = {b1v[ni], b1v[ni], b1v[ni], b1v[ni]};
            acc = __builtin_amdgcn_mfma_f32_16x16x32_bf16(a1[mi], B1f[ni], acc, 0, 0, 0);
            h1[ni][mi] = acc;
        }
    // transition 1: relu + pack + b64 write (cols 4t..4t+3 contiguous)
#pragma unroll
    for (int mi = 0; mi < 2; ++mi)
#pragma unroll
        for (int r = 0; r < 4; ++r) {
            u32 lo = cvtpk(fmaxf(h1[0][mi][r], 0.f), fmaxf(h1[1][mi][r], 0.f));
            u32 hi = cvtpk(fmaxf(h1[2][mi][r], 0.f), fmaxf(h1[3][mi][r], 0.f));
            u32x2 v = {lo, hi};
            *(u32x2*)(&hb[(mi * 16 + q * 4 + r) * 68 + 4 * t]) = v;
        }

    // ---- layer 2 (weight frags from global) ----
    s16x8 a2[2][2];
#pragma unroll
    for (int mi = 0; mi < 2; ++mi)
#pragma unroll
        for (int ks = 0; ks < 2; ++ks)
            a2[mi][ks] = lds_frag(&hb[(mi * 16 + t) * 68 + ks * 32 + q * 8]);
    f32x4 h2[4][2];
#pragma unroll
    for (int ni = 0; ni < 4; ++ni) {
        s16x8 w0 = gfrag(wf2, ni * 16 + t, 0, q);
        s16x8 w1_ = gfrag(wf2, ni * 16 + t, 1, q);
#pragma unroll
        for (int mi = 0; mi < 2; ++mi) {
            f32x4 acc = {b2v[ni], b2v[ni], b2v[ni], b2v[ni]};
            acc = __builtin_amdgcn_mfma_f32_16x16x32_bf16(a2[mi][0], w0, acc, 0, 0, 0);
            acc = __builtin_amdgcn_mfma_f32_16x16x32_bf16(a2[mi][1], w1_, acc, 0, 0, 0);
            h2[ni][mi] = acc;
        }
    }
    // transition 2
#pragma unroll
    for (int mi = 0; mi < 2; ++mi)
#pragma unroll
        for (int r = 0; r < 4; ++r) {
            u32 lo = cvtpk(fmaxf(h2[0][mi][r], 0.f), fmaxf(h2[1][mi][r], 0.f));
            u32 hi = cvtpk(fmaxf(h2[2][mi][r], 0.f), fmaxf(h2[3][mi][r], 0.f));
            u32x2 v = {lo, hi};
            *(u32x2*)(&hb[(mi * 16 + q * 4 + r) * 68 + 4 * t]) = v;
        }

    // ---- layer 3: registers -> global, no LDS epilogue ----
    s16x8 a3[2][2];
#pragma unroll
    for (int mi = 0; mi < 2; ++mi)
#pragma unroll
        for (int ks = 0; ks < 2; ++ks)
            a3[mi][ks] = lds_frag(&hb[(mi * 16 + t) * 68 + ks * 32 + q * 8]);
    f32x4 h3[4][2];
#pragma unroll
    for (int ni = 0; ni < 4; ++ni) {
        s16x8 w0 = gfrag(wf3, ni * 16 + t, 0, q);
        s16x8 w1_ = gfrag(wf3, ni * 16 + t, 1, q);
#pragma unroll
        for (int mi = 0; mi < 2; ++mi) {
            f32x4 acc = {b3v[ni], b3v[ni], b3v[ni], b3v[ni]};
            acc = __builtin_amdgcn_mfma_f32_16x16x32_bf16(a3[mi][0], w0, acc, 0, 0, 0);
            acc = __builtin_amdgcn_mfma_f32_16x16x32_bf16(a3[mi][1], w1_, acc, 0, 0, 0);
            h3[ni][mi] = acc;
        }
    }
    // CSR positions for this lane's 8 edges (safe-clamped int4 loads)
    int base0 = ebase + q * 4;
    int base1 = ebase + 16 + q * 4;
    int4 pos0 = *(const int4*)(eperm + ((base0 + 3 < NE) ? base0 : 0));
    int4 pos1 = *(const int4*)(eperm + ((base1 + 3 < NE) ? base1 : 0));
#pragma unroll
    for (int mi = 0; mi < 2; ++mi)
#pragma unroll
        for (int r = 0; r < 4; ++r) {
            int e = ebase + mi * 16 + q * 4 + r;
            if (e < NE) {
                int pos = mi ? ((const int*)&pos1)[r] : ((const int*)&pos0)[r];
                u32x2 v = {cvtpk(h3[0][mi][r], h3[1][mi][r]),
                           cvtpk(h3[2][mi][r], h3[3][mi][r])};
                *(u32x2*)(wout + (size_t)pos * 64 + 4 * t) = v;
            }
        }
}

// ------- prep: bf16 weights, row-permuted by p(n) within 64-row blocks -------
__global__ void k_prep_w(const float* __restrict__ Wig, const float* __restrict__ Whh,
                         const float* __restrict__ Wih,
                         const float* __restrict__ W1, const float* __restrict__ W2,
                         const float* __restrict__ W3, u16* __restrict__ wb)
{
    int i = blockIdx.x * 256 + threadIdx.x;   // < WB_TOTAL
    if (i >= WB_TOTAL) return;
    float v;
    if (i < 4096) {
        int n = i >> 6, k = i & 63;
        int pn = ((n & 15) << 2) + (n >> 4);
        v = Wig[pn * 64 + k];
    } else if (i < 16384) {
        int j = i - 4096;
        int n = j >> 6, k = j & 63;
        int g = n >> 6, m = n & 63;
        int pm = ((m & 15) << 2) + (m >> 4);
        v = Whh[(g * 64 + pm) * 64 + k];
    } else if (i < 28672) {
        int j = i - 16384;
        int n = j >> 6, k = j & 63;
        int g = n >> 6, m = n & 63;
        int pm = ((m & 15) << 2) + (m >> 4);
        v = Wih[(g * 64 + pm) * 64 + k];
    } else if (i < 29696) {
        int j = i - 28672;
        int n = j >> 4, k = j & 15;
        int pn = ((n & 15) << 2) + (n >> 4);
        v = (k < 13) ? W1[pn * 13 + k] : 0.f;
    } else if (i < 33792) {
        int j = i - 29696;
        int n = j >> 6, k = j & 63;
        int pn = ((n & 15) << 2) + (n >> 4);
        v = W2[pn * 64 + k];
    } else {
        int j = i - 33792;
        int n = j >> 6, k = j & 63;
        int pn = ((n & 15) << 2) + (n >> 4);
        v = W3[pn * 64 + k];
    }
    wb[i] = f2bf(v);
}

// ---------------- degree counting ----------------
__global__ void k_count(const int* __restrict__ idx, int* __restrict__ counts)
{
    int e = blockIdx.x * 256 + threadIdx.x;
    if (e < NE) atomicAdd(&counts[idx[e]], 1);
}

// ---------------- two-level exclusive scan over counts ----------------
__global__ void k_scan_partial(const int* __restrict__ counts, int* __restrict__ bsum)
{
    __shared__ int s[256];
    int i = blockIdx.x * 256 + threadIdx.x;
    int v = (i < NN) ? counts[i] : 0;
    s[threadIdx.x] = v; __syncthreads();
    for (int off = 128; off > 0; off >>= 1) {
        if (threadIdx.x < off) s[threadIdx.x] += s[threadIdx.x + off];
        __syncthreads();
    }
    if (threadIdx.x == 0) bsum[blockIdx.x] = s[0];
}

__global__ void k_scan_bsum(const int* __restrict__ bsum, int* __restrict__ bsumex)
{
    __shared__ int s[512];
    int t = threadIdx.x;
    int v0 = (t < 391) ? bsum[t] : 0;
    s[t] = v0; __syncthreads();
    for (int off = 1; off < 512; off <<= 1) {
        int add = (t >= off) ? s[t - off] : 0;
        __syncthreads();
        s[t] += add;
        __syncthreads();
    }
    if (t < 391) bsumex[t] = s[t] - v0;
}

__global__ void k_scan_final(const int* __restrict__ counts, const int* __restrict__ bsumex,
                             int* __restrict__ rowstart, int* __restrict__ cursor,
                             float* __restrict__ invdeg)
{
    __shared__ int s[256];
    int t = threadIdx.x;
    int i = blockIdx.x * 256 + t;
    int c = (i < NN) ? counts[i] : 0;
    s[t] = c; __syncthreads();
    for (int off = 1; off < 256; off <<= 1) {
        int add = (t >= off) ? s[t - off] : 0;
        __syncthreads();
        s[t] += add;
        __syncthreads();
    }
    int ex = s[t] - c + bsumex[blockIdx.x];
    if (i < NN) {
        rowstart[i] = ex;
        cursor[i] = ex;
        invdeg[i] = 1.f / (float)(c > 1 ? c : 1);
    }
    if (i == 0) rowstart[NN] = NE;
}

// ------- scatter edges into CSR order: srcs[p]=src, eperm[e]=p -------
__global__ void k_scatter(const int* __restrict__ idx, int* __restrict__ cursor,
                          int* __restrict__ srcs, int* __restrict__ eperm)
{
    int e = blockIdx.x * 256 + threadIdx.x;
    if (e < NE) {
        int d = idx[e];
        int s = idx[NE + e];
        int p = atomicAdd(&cursor[d], 1);
        srcs[p] = s;
        eperm[e] = p;
    }
}

// ---------------- copy hx0 into out column 0 ----------------
__global__ void k_init(const float4* __restrict__ hx4, float* __restrict__ outp)
{
    int i = blockIdx.x * 256 + threadIdx.x;
    int n = i >> 4, q = i & 15;
    ((float4*)(outp + (size_t)n * 256))[q] = hx4[i];
}

// ------- aggregation: wave per node; w streams sequentially (CSR order) -------
__global__ __launch_bounds__(256) void k_agg(
    const float* __restrict__ outp, const u16* __restrict__ w,
    const int* __restrict__ srcs, const int* __restrict__ rowstart,
    const float* __restrict__ invdeg, float* __restrict__ agg, int it)
{
    int lane = threadIdx.x & 63;
    int n = blockIdx.x * 4 + (threadIdx.x >> 6);
    n = __builtin_amdgcn_readfirstlane(n);
    int p0 = rowstart[n], p1 = rowstart[n + 1];
    const float* hxcol = outp + (size_t)it * 64 + lane;
    const u16* wp = w + (size_t)p0 * 64 + lane;
    float a0 = 0.f, a1 = 0.f, a2 = 0.f, a3 = 0.f;
    int p = p0;
    for (; p + 4 <= p1; p += 4) {
        int4 s4 = *(const int4*)(srcs + p);          // wave-uniform -> s_load
        float h0 = hxcol[(size_t)s4.x * 256];
        float h1 = hxcol[(size_t)s4.y * 256];
        float h2 = hxcol[(size_t)s4.z * 256];
        float h3 = hxcol[(size_t)s4.w * 256];
        float w0 = bf2f(__builtin_nontemporal_load(wp));
        float w1 = bf2f(__builtin_nontemporal_load(wp + 64));
        float w2 = bf2f(__builtin_nontemporal_load(wp + 128));
        float w3 = bf2f(__builtin_nontemporal_load(wp + 192));
        wp += 256;
        a0 = fmaf(h0, w0, a0);
        a1 = fmaf(h1, w1, a1);
        a2 = fmaf(h2, w2, a2);
        a3 = fmaf(h3, w3, a3);
    }
    for (; p < p1; ++p) {
        int s = srcs[p];
        float hv = hxcol[(size_t)s * 256];
        float wv = bf2f(__builtin_nontemporal_load(wp));
        wp += 64;
        a0 = fmaf(hv, wv, a0);
    }
    agg[(size_t)n * 64 + lane] = ((a0 + a1) + (a2 + a3)) * invdeg[n];
}

// ======== fused GRU: gate GEMM + gi/gh MFMA + inorm + gates, all in-kernel ========
// Weights row-permuted by p(n) (per gate block) so tile ni of lane (q,t) is
// TRUE feat 4t+ni -> agg reads float4, out stores float4, inp/hx LDS b64,
// biases float4. InstanceNorm sums are permutation-invariant (fp reorder only).
__global__ __launch_bounds__(256) void k_gru_fused(
    float* __restrict__ outp, const float* __restrict__ agg,
    const u16* __restrict__ wb,
    const float* __restrict__ big, const float* __restrict__ bih,
    const float* __restrict__ bhh, int it)
{
    __shared__ u16 hbuf[4][16 * 68];
    int tid = threadIdx.x;
    int wave = tid >> 6, lane = tid & 63;
    int q = lane >> 4, t = lane & 15;
    int nbase = blockIdx.x * 64 + wave * 16;
    u16* hb = hbuf[wave];
    const u16* wigb = wb;
    const u16* whhb = wb + 4096;
    const u16* wihb = wb + 16384;

    // ---- stage hx -> hb (bf16), float4 reads, packed b64 writes ----
    {
        int c = lane & 15;
        int mrow = lane >> 4;
#pragma unroll
        for (int rep = 0; rep < 4; ++rep) {
            int m = rep * 4 + mrow;
            int node = nbase + m;
            float4 v = make_float4(0.f, 0.f, 0.f, 0.f);
            if (node < NN)
                v = *(const float4*)(outp + (size_t)node * 256 + (size_t)it * 64 + c * 4);
            u32x2 pk = {cvtpk(v.x, v.y), cvtpk(v.z, v.w)};
            *(u32x2*)(&hb[m * 68 + c * 4]) = pk;
        }
    }
    // (wave-private buffer; in-order DS pipe makes a barrier unnecessary)

    // ---- hx A-frags + hx rows 4t..4t+3 (C-layout) ----
    s16x8 ahx[2];
    ahx[0] = lds_frag(&hb[t * 68 + q * 8]);
    ahx[1] = lds_frag(&hb[t * 68 + 32 + q * 8]);
    u32 hxpk[4][2];
#pragma unroll
    for (int r = 0; r < 4; ++r)
        *(u32x2*)hxpk[r] = *(const u32x2*)(&hb[(q * 4 + r) * 68 + 4 * t]);

    // ---- gate GEMM: sigmoid(hx @ Wig^T + big) * agg -> inp (to hb) ----
    f32x4 bgv = *(const f32x4*)(big + 4 * t);
    f32x4 gacc[4];
#pragma unroll
    for (int ni = 0; ni < 4; ++ni) {
        s16x8 b0 = gfrag(wigb, ni * 16 + t, 0, q);
        s16x8 b1 = gfrag(wigb, ni * 16 + t, 1, q);
        f32x4 acc = {bgv[ni], bgv[ni], bgv[ni], bgv[ni]};
        acc = __builtin_amdgcn_mfma_f32_16x16x32_bf16(ahx[0], b0, acc, 0, 0, 0);
        acc = __builtin_amdgcn_mfma_f32_16x16x32_bf16(ahx[1], b1, acc, 0, 0, 0);
        gacc[ni] = acc;
    }
#pragma unroll
    for (int r = 0; r < 4; ++r) {
        int node = nbase + q * 4 + r;
        f32x4 av = {0.f, 0.f, 0.f, 0.f};
        if (node < NN) av = *(const f32x4*)(agg + (size_t)node * 64 + 4 * t);
        float i0 = sigmoidf_(gacc[0][r]) * av[0];
        float i1 = sigmoidf_(gacc[1][r]) * av[1];
        float i2 = sigmoidf_(gacc[2][r]) * av[2];
        float i3 = sigmoidf_(gacc[3][r]) * av[3];
        u32x2 pk = {cvtpk(i0, i1), cvtpk(i2, i3)};
        *(u32x2*)(&hb[(q * 4 + r) * 68 + 4 * t]) = pk;
    }

    // ---- gh = hx @ Whh^T  (12 tiles, packed bf16 in regs + stats) ----
    float sgh[4] = {0.f, 0.f, 0.f, 0.f}, qgh[4] = {0.f, 0.f, 0.f, 0.f};
    u32 ghp[12][2];
#pragma unroll
    for (int ni = 0; ni < 12; ++ni) {
        s16x8 b0 = gfrag(whhb, ni * 16 + t, 0, q);
        s16x8 b1 = gfrag(whhb, ni * 16 + t, 1, q);
        f32x4 acc = {0.f, 0.f, 0.f, 0.f};
        acc = __builtin_amdgcn_mfma_f32_16x16x32_bf16(ahx[0], b0, acc, 0, 0, 0);
        acc = __builtin_amdgcn_mfma_f32_16x16x32_bf16(ahx[1], b1, acc, 0, 0, 0);
#pragma unroll
        for (int r = 0; r < 4; ++r) { sgh[r] += acc[r]; qgh[r] += acc[r] * acc[r]; }
        ghp[ni][0] = cvtpk(acc[0], acc[1]);
        ghp[ni][1] = cvtpk(acc[2], acc[3]);
    }

    // ---- inp A-frags (after LDS write above; same-wave ordering) ----
    s16x8 ain[2];
    ain[0] = lds_frag(&hb[t * 68 + q * 8]);
    ain[1] = lds_frag(&hb[t * 68 + 32 + q * 8]);

    // ---- gi = inp @ Wih^T ----
    float sgi[4] = {0.f, 0.f, 0.f, 0.f}, qgi[4] = {0.f, 0.f, 0.f, 0.f};
    u32 gip[12][2];
#pragma unroll
    for (int ni = 0; ni < 12; ++ni) {
        s16x8 b0 = gfrag(wihb, ni * 16 + t, 0, q);
        s16x8 b1 = gfrag(wihb, ni * 16 + t, 1, q);
        f32x4 acc = {0.f, 0.f, 0.f, 0.f};
        acc = __builtin_amdgcn_mfma_f32_16x16x32_bf16(ain[0], b0, acc, 0, 0, 0);
        acc = __builtin_amdgcn_mfma_f32_16x16x32_bf16(ain[1], b1, acc, 0, 0, 0);
#pragma unroll
        for (int r = 0; r < 4; ++r) { sgi[r] += acc[r]; qgi[r] += acc[r] * acc[r]; }
        gip[ni][0] = cvtpk(acc[0], acc[1]);
        gip[ni][1] = cvtpk(acc[2], acc[3]);
    }

    // ---- reduce stats over t-group ----
#pragma unroll
    for (int m = 1; m < 16; m <<= 1) {
#pragma unroll
        for (int r = 0; r < 4; ++r) {
            sgh[r] += __shfl_xor(sgh[r], m, 64);
            qgh[r] += __shfl_xor(qgh[r], m, 64);
            sgi[r] += __shfl_xor(sgi[r], m, 64);
            qgi[r] += __shfl_xor(qgi[r], m, 64);
        }
    }
    float mi_[4], ri_[4], mh_[4], rh_[4];
#pragma unroll
    for (int r = 0; r < 4; ++r) {
        mi_[r] = sgi[r] * (1.f / 192.f);
        mh_[r] = sgh[r] * (1.f / 192.f);
        ri_[r] = rsqrtf(qgi[r] * (1.f / 192.f) - mi_[r] * mi_[r] + EPSI);
        rh_[r] = rsqrtf(qgh[r] * (1.f / 192.f) - mh_[r] * mh_[r] + EPSI);
    }

    // ---- gates + hx update + float4 stores ----
    f32x4 bihr = *(const f32x4*)(bih + 4 * t);
    f32x4 bihi = *(const f32x4*)(bih + 64 + 4 * t);
    f32x4 bihn = *(const f32x4*)(bih + 128 + 4 * t);
    f32x4 bhhr = *(const f32x4*)(bhh + 4 * t);
    f32x4 bhhi = *(const f32x4*)(bhh + 64 + 4 * t);
    f32x4 bhhn = *(const f32x4*)(bhh + 128 + 4 * t);
#pragma unroll
    for (int r = 0; r < 4; ++r) {
        int node = nbase + q * 4 + r;
        f32x4 res;
#pragma unroll
        for (int ni = 0; ni < 4; ++ni) {
            float iv_r = (unpk(gip[ni], r) - mi_[r]) * ri_[r];
            float iv_i = (unpk(gip[ni + 4], r) - mi_[r]) * ri_[r];
            float iv_n = (unpk(gip[ni + 8], r) - mi_[r]) * ri_[r];
            float hv_r = (unpk(ghp[ni], r) - mh_[r]) * rh_[r];
            float hv_i = (unpk(ghp[ni + 4], r) - mh_[r]) * rh_[r];
            float hv_n = (unpk(ghp[ni + 8], r) - mh_[r]) * rh_[r];
            float rg = sigmoidf_(iv_r + bihr[ni] + hv_r + bhhr[ni]);
            float zg = sigmoidf_(iv_i + bihi[ni] + hv_i + bhhi[ni]);
            float ng = tanhf_(iv_n + bihn[ni] + rg * (hv_n + bhhn[ni]));
            float ho = bf2f((u16)((ni & 1) ? (hxpk[r][ni >> 1] >> 16)
                                           : (hxpk[r][ni >> 1] & 0xffffu)));
            res[ni] = ng + zg * (ho - ng);
        }
        if (node < NN)
            *(f32x4*)(outp + (size_t)node * 256 + (size_t)(it + 1) * 64 + 4 * t) = res;
    }
}

extern "C" void kernel_launch(void* const* d_in, const int* in_sizes, int n_in,
                              void* d_out, int out_size, void* d_ws, size_t ws_size,
                              hipStream_t stream)
{
    const float* hx  = (const float*)d_in[0];
    const int*   eix = (const int*)d_in[1];
    const float* ef  = (const float*)d_in[2];
    const float* fW1 = (const float*)d_in[3];
    const float* fb1 = (const float*)d_in[4];
    const float* fW2 = (const float*)d_in[5];
    const float* fb2 = (const float*)d_in[6];
    const float* fW3 = (const float*)d_in[7];
    const float* fb3 = (const float*)d_in[8];
    const float* Wih = (const float*)d_in[9];
    const float* Whh = (const float*)d_in[10];
    const float* bih = (const float*)d_in[11];
    const float* bhh = (const float*)d_in[12];
    const float* Wig = (const float*)d_in[13];
    const float* big = (const float*)d_in[14];
    float* outp = (float*)d_out;
    char* ws = (char*)d_ws;

    u16*    w      = (u16*)(ws + WS_W);
    float*  agg    = (float*)(ws + WS_AGG);
    u16*    wb     = (u16*)(ws + WS_WB);
    float*  invdeg = (float*)(ws + WS_INVDEG);
    int*    counts = (int*)(ws + WS_COUNTS);
    int*    rowst  = (int*)(ws + WS_ROWSTART);
    int*    cursor = (int*)(ws + WS_CURSOR);
    int*    bsum   = (int*)(ws + WS_BSUM);
    int*    bsumex = (int*)(ws + WS_BSUMEX);
    int*    srcs   = (int*)(ws + WS_SRC);
    int*    eperm  = (int*)(ws + WS_EPERM);

    hipMemsetAsync(counts, 0, NN * sizeof(int), stream);
    k_prep_w<<<(WB_TOTAL + 255) / 256, 256, 0, stream>>>(Wig, Whh, Wih, fW1, fW2, fW3, wb);
    k_count<<<(NE + 255) / 256, 256, 0, stream>>>(eix, counts);
    k_scan_partial<<<391, 256, 0, stream>>>(counts, bsum);
    k_scan_bsum<<<1, 512, 0, stream>>>(bsum, bsumex);
    k_scan_final<<<391, 256, 0, stream>>>(counts, bsumex, rowst, cursor, invdeg);
    k_scatter<<<(NE + 255) / 256, 256, 0, stream>>>(eix, cursor, srcs, eperm);
    k_fnet_mfma<<<9766, 256, 0, stream>>>(ef, fb1, fb2, fb3, eperm, wb, w);
    k_init<<<6250, 256, 0, stream>>>((const float4*)hx, outp);

    for (int it = 0; it < 3; ++it) {
        k_agg<<<25000, 256, 0, stream>>>(outp, w, srcs, rowst, invdeg, agg, it);
        k_gru_fused<<<1563, 256, 0, stream>>>(outp, agg, wb, big, bih, bhh, it);
    }
}

// Round 6
// 819.320 us; speedup vs baseline: 1.1045x; 1.0292x over previous
//
#include <hip/hip_runtime.h>
#include <math.h>

#define NN 100000
#define NE 1250000
#define EPSI 1e-5f

// ---- workspace layout (bytes) ----
#define WS_W        0ull          // bf16 [NE*64]            160,000,000  (CSR-ordered)
#define WS_AGG      160000000ull  // f32  [NN*64]             25,600,000
#define WS_WB       185600000ull  // bf16 weights (see k_prep_w)
#define WS_INVDEG   264000000ull  // f32 [NN]
#define WS_COUNTS   264400000ull  // i32 [NN]
#define WS_ROWSTART 264800000ull  // i32 [NN+1]
#define WS_CURSOR   265200128ull  // i32 [NN]
#define WS_BSUM     265600128ull  // i32 [391]
#define WS_BSUMEX   265601792ull  // i32 [391]
#define WS_SRC      265603584ull  // i32 [NE]  src node per CSR slot       5,000,000
#define WS_EPERM    270603584ull  // i32 [NE]  edge id -> CSR slot         5,000,000

// wb (bf16) sub-layout, all row-permuted by p(n)=4*(n&15)+(n>>4) within
// each 64-row block:
//   [0)      Wig   64x64
//   [4096)   Whh  192x64   (perm within each gate's 64 rows)
//   [16384)  Wih  192x64   (perm within each gate's 64 rows)
//   [28672)  W1    64x16   (13 cols + 3 zero pad)
//   [29696)  W2    64x64
//   [33792)  W3    64x64   -> total 37888 elements
#define WB_TOTAL 37888

typedef unsigned short u16;
typedef unsigned int u32;
typedef short s16x4 __attribute__((ext_vector_type(4)));
typedef short s16x8 __attribute__((ext_vector_type(8)));
typedef float f32x4 __attribute__((ext_vector_type(4)));
typedef u32 u32x4 __attribute__((ext_vector_type(4)));
typedef u32 u32x2 __attribute__((ext_vector_type(2)));
typedef float f32x4u __attribute__((ext_vector_type(4), aligned(4)));

__device__ __forceinline__ u16 f2bf(float f) {
    u32 u = __float_as_uint(f);
    return (u16)((u + 0x7fffu + ((u >> 16) & 1u)) >> 16);   // RNE
}
__device__ __forceinline__ float bf2f(u16 b) {
    return __uint_as_float(((u32)b) << 16);
}
// packed f32x2 -> bf16x2 (RNE), 1 VALU op
__device__ __forceinline__ u32 cvtpk(float lo, float hi) {
    u32 r;
    asm("v_cvt_pk_bf16_f32 %0, %1, %2" : "=v"(r) : "v"(lo), "v"(hi));
    return r;
}
__device__ __forceinline__ float sigmoidf_(float x) {
    return 1.f / (1.f + __expf(-x));
}
// tanh via exp, saturating at +-1; ~4 VALU ops vs libm tanhf's ~20
__device__ __forceinline__ float tanhf_(float x) {
    float e = __expf(2.f * x);
    return 1.f - 2.f / (e + 1.f);
}
__device__ __forceinline__ s16x8 lds_frag(const u16* p) {
    s16x4 lo = *(const s16x4*)p;
    s16x4 hi = *(const s16x4*)(p + 4);
    return __builtin_shufflevector(lo, hi, 0, 1, 2, 3, 4, 5, 6, 7);
}
__device__ __forceinline__ s16x8 gfrag(const u16* W, int n, int ks, int q) {
    // W row-major [64 cols], 16-byte aligned chunks
    return *(const s16x8*)(W + n * 64 + ks * 32 + q * 8);
}
__device__ __forceinline__ float unpk(const u32* p, int r) {
    u32 v = p[r >> 1];
    return bf2f((u16)((r & 1) ? (v >> 16) : (v & 0xffffu)));
}

// ============ fnet via MFMA: per-edge MLP 13->64->64->64, bf16 out ============
// R4-proven dataflow: weights staged into LDS (ds_read on the layer chain,
// ~60cy vs ~200cy global — R5 measured the global variant 17us slower), hbuf
// transitions with cvtpk+b64 writes (row perm p(n) makes lane cols 4t..4t+3
// contiguous). Staging copies prepped bf16 directly (no f2bf). Output rows
// scattered to CSR slot eperm[e] so k_agg streams w sequentially.
__global__ __launch_bounds__(256) void k_fnet_mfma(
    const float* __restrict__ ef,
    const float* __restrict__ b1, const float* __restrict__ b2,
    const float* __restrict__ b3,
    const int* __restrict__ eperm,
    const u16* __restrict__ wbf,
    u16* __restrict__ wout)
{
    __shared__ u16 w1l[64 * 16];
    __shared__ u16 w2l[64 * 68];
    __shared__ u16 w3l[64 * 68];
    __shared__ u16 hbuf[4][32 * 68];

    int tid = threadIdx.x;
    const u16* wf1 = wbf + 28672;
    const u16* wf2 = wbf + 29696;
    const u16* wf3 = wbf + 33792;
    for (int i = tid; i < 1024; i += 256) w1l[i] = wf1[i];
    for (int i = tid; i < 4096; i += 256) {
        int n = i >> 6, k = i & 63;
        w2l[n * 68 + k] = wf2[i];
        w3l[n * 68 + k] = wf3[i];
    }
    __syncthreads();

    int wave = tid >> 6, lane = tid & 63;
    int q = lane >> 4, t = lane & 15;
    int ebase = blockIdx.x * 128 + wave * 32;
    u16* hb = hbuf[wave];

    // biases in permuted slot order: slot (ni,t) holds true feat 4t+ni
    f32x4 b1v = *(const f32x4*)(b1 + 4 * t);
    f32x4 b2v = *(const f32x4*)(b2 + 4 * t);
    f32x4 b3v = *(const f32x4*)(b3 + 4 * t);

    const s16x8 zfrag = {0, 0, 0, 0, 0, 0, 0, 0};

    // ---- ef fragments: vector loads + packed converts ----
    s16x8 a1[2];
#pragma unroll
    for (int mi = 0; mi < 2; ++mi) {
        int e = ebase + mi * 16 + t;
        u32 xp[4] = {0u, 0u, 0u, 0u};
        if (e < NE) {
            const float* ep = ef + (size_t)e * 13;
            if (q == 0) {
                f32x4u v0 = *(const f32x4u*)(ep);
                f32x4u v1 = *(const f32x4u*)(ep + 4);
                xp[0] = cvtpk(v0[0], v0[1]); xp[1] = cvtpk(v0[2], v0[3]);
                xp[2] = cvtpk(v1[0], v1[1]); xp[3] = cvtpk(v1[2], v1[3]);
            } else if (q == 1) {
                f32x4u v0 = *(const f32x4u*)(ep + 8);
                float v12 = ep[12];
                xp[0] = cvtpk(v0[0], v0[1]); xp[1] = cvtpk(v0[2], v0[3]);
                xp[2] = cvtpk(v12, 0.f);
            }
        }
        a1[mi] = __builtin_bit_cast(s16x8, *(u32x4*)xp);
    }

    // ---- W1 fragments ----
    s16x8 B1f[4];
#pragma unroll
    for (int ni = 0; ni < 4; ++ni) {
        s16x8 b = zfrag;
        if (q < 2) b = lds_frag(&w1l[(ni * 16 + t) * 16 + q * 8]);
        B1f[ni] = b;
    }

    // ---- layer 1 ----
    f32x4 h1[4][2];
#pragma unroll
    for (int ni = 0; ni < 4; ++ni)
#pragma unroll
        for (int mi = 0; mi < 2; ++mi) {
            f32x4 acc = {b1v[ni], b1v[ni], b1v[ni], b1v[ni]};
            acc = __builtin_amdgcn_mfma_f32_16x16x32_bf16(a1[mi], B1f[ni], acc, 0, 0, 0);
            h1[ni][mi] = acc;
        }
    // transition 1: relu + pack + b64 write (cols 4t..4t+3 contiguous)
#pragma unroll
    for (int mi = 0; mi < 2; ++mi)
#pragma unroll
        for (int r = 0; r < 4; ++r) {
            u32 lo = cvtpk(fmaxf(h1[0][mi][r], 0.f), fmaxf(h1[1][mi][r], 0.f));
            u32 hi = cvtpk(fmaxf(h1[2][mi][r], 0.f), fmaxf(h1[3][mi][r], 0.f));
            u32x2 v = {lo, hi};
            *(u32x2*)(&hb[(mi * 16 + q * 4 + r) * 68 + 4 * t]) = v;
        }

    // ---- layer 2 ----
    s16x8 a2[2][2];
#pragma unroll
    for (int mi = 0; mi < 2; ++mi)
#pragma unroll
        for (int ks = 0; ks < 2; ++ks)
            a2[mi][ks] = lds_frag(&hb[(mi * 16 + t) * 68 + ks * 32 + q * 8]);
    f32x4 h2[4][2];
#pragma unroll
    for (int ni = 0; ni < 4; ++ni) {
        s16x8 w0 = lds_frag(&w2l[(ni * 16 + t) * 68 + q * 8]);
        s16x8 w1_ = lds_frag(&w2l[(ni * 16 + t) * 68 + 32 + q * 8]);
#pragma unroll
        for (int mi = 0; mi < 2; ++mi) {
            f32x4 acc = {b2v[ni], b2v[ni], b2v[ni], b2v[ni]};
            acc = __builtin_amdgcn_mfma_f32_16x16x32_bf16(a2[mi][0], w0, acc, 0, 0, 0);
            acc = __builtin_amdgcn_mfma_f32_16x16x32_bf16(a2[mi][1], w1_, acc, 0, 0, 0);
            h2[ni][mi] = acc;
        }
    }
    // transition 2
#pragma unroll
    for (int mi = 0; mi < 2; ++mi)
#pragma unroll
        for (int r = 0; r < 4; ++r) {
            u32 lo = cvtpk(fmaxf(h2[0][mi][r], 0.f), fmaxf(h2[1][mi][r], 0.f));
            u32 hi = cvtpk(fmaxf(h2[2][mi][r], 0.f), fmaxf(h2[3][mi][r], 0.f));
            u32x2 v = {lo, hi};
            *(u32x2*)(&hb[(mi * 16 + q * 4 + r) * 68 + 4 * t]) = v;
        }

    // ---- layer 3: registers -> global, no LDS epilogue ----
    s16x8 a3[2][2];
#pragma unroll
    for (int mi = 0; mi < 2; ++mi)
#pragma unroll
        for (int ks = 0; ks < 2; ++ks)
            a3[mi][ks] = lds_frag(&hb[(mi * 16 + t) * 68 + ks * 32 + q * 8]);
    f32x4 h3[4][2];
#pragma unroll
    for (int ni = 0; ni < 4; ++ni) {
        s16x8 w0 = lds_frag(&w3l[(ni * 16 + t) * 68 + q * 8]);
        s16x8 w1_ = lds_frag(&w3l[(ni * 16 + t) * 68 + 32 + q * 8]);
#pragma unroll
        for (int mi = 0; mi < 2; ++mi) {
            f32x4 acc = {b3v[ni], b3v[ni], b3v[ni], b3v[ni]};
            acc = __builtin_amdgcn_mfma_f32_16x16x32_bf16(a3[mi][0], w0, acc, 0, 0, 0);
            acc = __builtin_amdgcn_mfma_f32_16x16x32_bf16(a3[mi][1], w1_, acc, 0, 0, 0);
            h3[ni][mi] = acc;
        }
    }
    // CSR positions for this lane's 8 edges (safe-clamped int4 loads)
    int base0 = ebase + q * 4;
    int base1 = ebase + 16 + q * 4;
    int4 pos0 = *(const int4*)(eperm + ((base0 + 3 < NE) ? base0 : 0));
    int4 pos1 = *(const int4*)(eperm + ((base1 + 3 < NE) ? base1 : 0));
#pragma unroll
    for (int mi = 0; mi < 2; ++mi)
#pragma unroll
        for (int r = 0; r < 4; ++r) {
            int e = ebase + mi * 16 + q * 4 + r;
            if (e < NE) {
                int pos = mi ? ((const int*)&pos1)[r] : ((const int*)&pos0)[r];
                u32x2 v = {cvtpk(h3[0][mi][r], h3[1][mi][r]),
                           cvtpk(h3[2][mi][r], h3[3][mi][r])};
                *(u32x2*)(wout + (size_t)pos * 64 + 4 * t) = v;
            }
        }
}

// ------- prep: bf16 weights, row-permuted by p(n) within 64-row blocks -------
__global__ void k_prep_w(const float* __restrict__ Wig, const float* __restrict__ Whh,
                         const float* __restrict__ Wih,
                         const float* __restrict__ W1, const float* __restrict__ W2,
                         const float* __restrict__ W3, u16* __restrict__ wb)
{
    int i = blockIdx.x * 256 + threadIdx.x;   // < WB_TOTAL
    if (i >= WB_TOTAL) return;
    float v;
    if (i < 4096) {
        int n = i >> 6, k = i & 63;
        int pn = ((n & 15) << 2) + (n >> 4);
        v = Wig[pn * 64 + k];
    } else if (i < 16384) {
        int j = i - 4096;
        int n = j >> 6, k = j & 63;
        int g = n >> 6, m = n & 63;
        int pm = ((m & 15) << 2) + (m >> 4);
        v = Whh[(g * 64 + pm) * 64 + k];
    } else if (i < 28672) {
        int j = i - 16384;
        int n = j >> 6, k = j & 63;
        int g = n >> 6, m = n & 63;
        int pm = ((m & 15) << 2) + (m >> 4);
        v = Wih[(g * 64 + pm) * 64 + k];
    } else if (i < 29696) {
        int j = i - 28672;
        int n = j >> 4, k = j & 15;
        int pn = ((n & 15) << 2) + (n >> 4);
        v = (k < 13) ? W1[pn * 13 + k] : 0.f;
    } else if (i < 33792) {
        int j = i - 29696;
        int n = j >> 6, k = j & 63;
        int pn = ((n & 15) << 2) + (n >> 4);
        v = W2[pn * 64 + k];
    } else {
        int j = i - 33792;
        int n = j >> 6, k = j & 63;
        int pn = ((n & 15) << 2) + (n >> 4);
        v = W3[pn * 64 + k];
    }
    wb[i] = f2bf(v);
}

// ---------------- degree counting ----------------
__global__ void k_count(const int* __restrict__ idx, int* __restrict__ counts)
{
    int e = blockIdx.x * 256 + threadIdx.x;
    if (e < NE) atomicAdd(&counts[idx[e]], 1);
}

// ---------------- two-level exclusive scan over counts ----------------
__global__ void k_scan_partial(const int* __restrict__ counts, int* __restrict__ bsum)
{
    __shared__ int s[256];
    int i = blockIdx.x * 256 + threadIdx.x;
    int v = (i < NN) ? counts[i] : 0;
    s[threadIdx.x] = v; __syncthreads();
    for (int off = 128; off > 0; off >>= 1) {
        if (threadIdx.x < off) s[threadIdx.x] += s[threadIdx.x + off];
        __syncthreads();
    }
    if (threadIdx.x == 0) bsum[blockIdx.x] = s[0];
}

__global__ void k_scan_bsum(const int* __restrict__ bsum, int* __restrict__ bsumex)
{
    __shared__ int s[512];
    int t = threadIdx.x;
    int v0 = (t < 391) ? bsum[t] : 0;
    s[t] = v0; __syncthreads();
    for (int off = 1; off < 512; off <<= 1) {
        int add = (t >= off) ? s[t - off] : 0;
        __syncthreads();
        s[t] += add;
        __syncthreads();
    }
    if (t < 391) bsumex[t] = s[t] - v0;
}

__global__ void k_scan_final(const int* __restrict__ counts, const int* __restrict__ bsumex,
                             int* __restrict__ rowstart, int* __restrict__ cursor,
                             float* __restrict__ invdeg)
{
    __shared__ int s[256];
    int t = threadIdx.x;
    int i = blockIdx.x * 256 + t;
    int c = (i < NN) ? counts[i] : 0;
    s[t] = c; __syncthreads();
    for (int off = 1; off < 256; off <<= 1) {
        int add = (t >= off) ? s[t - off] : 0;
        __syncthreads();
        s[t] += add;
        __syncthreads();
    }
    int ex = s[t] - c + bsumex[blockIdx.x];
    if (i < NN) {
        rowstart[i] = ex;
        cursor[i] = ex;
        invdeg[i] = 1.f / (float)(c > 1 ? c : 1);
    }
    if (i == 0) rowstart[NN] = NE;
}

// ------- scatter edges into CSR order: srcs[p]=src, eperm[e]=p -------
__global__ void k_scatter(const int* __restrict__ idx, int* __restrict__ cursor,
                          int* __restrict__ srcs, int* __restrict__ eperm)
{
    int e = blockIdx.x * 256 + threadIdx.x;
    if (e < NE) {
        int d = idx[e];
        int s = idx[NE + e];
        int p = atomicAdd(&cursor[d], 1);
        srcs[p] = s;
        eperm[e] = p;
    }
}

// ---------------- copy hx0 into out column 0 ----------------
__global__ void k_init(const float4* __restrict__ hx4, float* __restrict__ outp)
{
    int i = blockIdx.x * 256 + threadIdx.x;
    int n = i >> 4, q = i & 15;
    ((float4*)(outp + (size_t)n * 256))[q] = hx4[i];
}

// ------- aggregation: wave per node; w streams sequentially (CSR order) -------
// 8-deep load batch: 8 scalar srcs + 8 hx gathers + 8 nt w loads issued before
// the FMA group -> ~2 dependent latency rounds per wave at mean degree 12.5
// (vs ~3.5 with the 4-wide batch). VGPR cost ~8 (kernel was at 8).
__global__ __launch_bounds__(256) void k_agg(
    const float* __restrict__ outp, const u16* __restrict__ w,
    const int* __restrict__ srcs, const int* __restrict__ rowstart,
    const float* __restrict__ invdeg, float* __restrict__ agg, int it)
{
    int lane = threadIdx.x & 63;
    int n = blockIdx.x * 4 + (threadIdx.x >> 6);
    n = __builtin_amdgcn_readfirstlane(n);
    int p0 = rowstart[n], p1 = rowstart[n + 1];
    const float* hxcol = outp + (size_t)it * 64 + lane;
    const u16* wp = w + (size_t)p0 * 64 + lane;
    float a0 = 0.f, a1 = 0.f, a2 = 0.f, a3 = 0.f;
    int p = p0;
    for (; p + 8 <= p1; p += 8) {
        int4 sa = *(const int4*)(srcs + p);          // wave-uniform -> s_load
        int4 sb = *(const int4*)(srcs + p + 4);
        float h0 = hxcol[(size_t)sa.x * 256];
        float h1 = hxcol[(size_t)sa.y * 256];
        float h2 = hxcol[(size_t)sa.z * 256];
        float h3 = hxcol[(size_t)sa.w * 256];
        float h4 = hxcol[(size_t)sb.x * 256];
        float h5 = hxcol[(size_t)sb.y * 256];
        float h6 = hxcol[(size_t)sb.z * 256];
        float h7 = hxcol[(size_t)sb.w * 256];
        float w0 = bf2f(__builtin_nontemporal_load(wp));
        float w1 = bf2f(__builtin_nontemporal_load(wp + 64));
        float w2 = bf2f(__builtin_nontemporal_load(wp + 128));
        float w3 = bf2f(__builtin_nontemporal_load(wp + 192));
        float w4 = bf2f(__builtin_nontemporal_load(wp + 256));
        float w5 = bf2f(__builtin_nontemporal_load(wp + 320));
        float w6 = bf2f(__builtin_nontemporal_load(wp + 384));
        float w7 = bf2f(__builtin_nontemporal_load(wp + 448));
        wp += 512;
        a0 = fmaf(h0, w0, a0);
        a1 = fmaf(h1, w1, a1);
        a2 = fmaf(h2, w2, a2);
        a3 = fmaf(h3, w3, a3);
        a0 = fmaf(h4, w4, a0);
        a1 = fmaf(h5, w5, a1);
        a2 = fmaf(h6, w6, a2);
        a3 = fmaf(h7, w7, a3);
    }
    if (p + 4 <= p1) {
        int4 s4 = *(const int4*)(srcs + p);
        float h0 = hxcol[(size_t)s4.x * 256];
        float h1 = hxcol[(size_t)s4.y * 256];
        float h2 = hxcol[(size_t)s4.z * 256];
        float h3 = hxcol[(size_t)s4.w * 256];
        float w0 = bf2f(__builtin_nontemporal_load(wp));
        float w1 = bf2f(__builtin_nontemporal_load(wp + 64));
        float w2 = bf2f(__builtin_nontemporal_load(wp + 128));
        float w3 = bf2f(__builtin_nontemporal_load(wp + 192));
        wp += 256;
        a0 = fmaf(h0, w0, a0);
        a1 = fmaf(h1, w1, a1);
        a2 = fmaf(h2, w2, a2);
        a3 = fmaf(h3, w3, a3);
        p += 4;
    }
    for (; p < p1; ++p) {
        int s = srcs[p];
        float hv = hxcol[(size_t)s * 256];
        float wv = bf2f(__builtin_nontemporal_load(wp));
        wp += 64;
        a0 = fmaf(hv, wv, a0);
    }
    agg[(size_t)n * 64 + lane] = ((a0 + a1) + (a2 + a3)) * invdeg[n];
}

// ======== fused GRU: gate GEMM + gi/gh MFMA + inorm + gates, all in-kernel ========
// Weights row-permuted by p(n) (per gate block) so tile ni of lane (q,t) is
// TRUE feat 4t+ni -> agg reads float4, out stores float4, inp/hx LDS b64,
// biases float4. InstanceNorm sums are permutation-invariant (fp reorder only).
__global__ __launch_bounds__(256) void k_gru_fused(
    float* __restrict__ outp, const float* __restrict__ agg,
    const u16* __restrict__ wb,
    const float* __restrict__ big, const float* __restrict__ bih,
    const float* __restrict__ bhh, int it)
{
    __shared__ u16 hbuf[4][16 * 68];
    int tid = threadIdx.x;
    int wave = tid >> 6, lane = tid & 63;
    int q = lane >> 4, t = lane & 15;
    int nbase = blockIdx.x * 64 + wave * 16;
    u16* hb = hbuf[wave];
    const u16* wigb = wb;
    const u16* whhb = wb + 4096;
    const u16* wihb = wb + 16384;

    // ---- stage hx -> hb (bf16), float4 reads, packed b64 writes ----
    {
        int c = lane & 15;
        int mrow = lane >> 4;
#pragma unroll
        for (int rep = 0; rep < 4; ++rep) {
            int m = rep * 4 + mrow;
            int node = nbase + m;
            float4 v = make_float4(0.f, 0.f, 0.f, 0.f);
            if (node < NN)
                v = *(const float4*)(outp + (size_t)node * 256 + (size_t)it * 64 + c * 4);
            u32x2 pk = {cvtpk(v.x, v.y), cvtpk(v.z, v.w)};
            *(u32x2*)(&hb[m * 68 + c * 4]) = pk;
        }
    }
    // (wave-private buffer; in-order DS pipe makes a barrier unnecessary)

    // ---- hx A-frags + hx rows 4t..4t+3 (C-layout) ----
    s16x8 ahx[2];
    ahx[0] = lds_frag(&hb[t * 68 + q * 8]);
    ahx[1] = lds_frag(&hb[t * 68 + 32 + q * 8]);
    u32 hxpk[4][2];
#pragma unroll
    for (int r = 0; r < 4; ++r)
        *(u32x2*)hxpk[r] = *(const u32x2*)(&hb[(q * 4 + r) * 68 + 4 * t]);

    // ---- gate GEMM: sigmoid(hx @ Wig^T + big) * agg -> inp (to hb) ----
    f32x4 bgv = *(const f32x4*)(big + 4 * t);
    f32x4 gacc[4];
#pragma unroll
    for (int ni = 0; ni < 4; ++ni) {
        s16x8 b0 = gfrag(wigb, ni * 16 + t, 0, q);
        s16x8 b1 = gfrag(wigb, ni * 16 + t, 1, q);
        f32x4 acc = {bgv[ni], bgv[ni], bgv[ni], bgv[ni]};
        acc = __builtin_amdgcn_mfma_f32_16x16x32_bf16(ahx[0], b0, acc, 0, 0, 0);
        acc = __builtin_amdgcn_mfma_f32_16x16x32_bf16(ahx[1], b1, acc, 0, 0, 0);
        gacc[ni] = acc;
    }
#pragma unroll
    for (int r = 0; r < 4; ++r) {
        int node = nbase + q * 4 + r;
        f32x4 av = {0.f, 0.f, 0.f, 0.f};
        if (node < NN) av = *(const f32x4*)(agg + (size_t)node * 64 + 4 * t);
        float i0 = sigmoidf_(gacc[0][r]) * av[0];
        float i1 = sigmoidf_(gacc[1][r]) * av[1];
        float i2 = sigmoidf_(gacc[2][r]) * av[2];
        float i3 = sigmoidf_(gacc[3][r]) * av[3];
        u32x2 pk = {cvtpk(i0, i1), cvtpk(i2, i3)};
        *(u32x2*)(&hb[(q * 4 + r) * 68 + 4 * t]) = pk;
    }

    // ---- gh = hx @ Whh^T  (12 tiles, packed bf16 in regs + stats) ----
    float sgh[4] = {0.f, 0.f, 0.f, 0.f}, qgh[4] = {0.f, 0.f, 0.f, 0.f};
    u32 ghp[12][2];
#pragma unroll
    for (int ni = 0; ni < 12; ++ni) {
        s16x8 b0 = gfrag(whhb, ni * 16 + t, 0, q);
        s16x8 b1 = gfrag(whhb, ni * 16 + t, 1, q);
        f32x4 acc = {0.f, 0.f, 0.f, 0.f};
        acc = __builtin_amdgcn_mfma_f32_16x16x32_bf16(ahx[0], b0, acc, 0, 0, 0);
        acc = __builtin_amdgcn_mfma_f32_16x16x32_bf16(ahx[1], b1, acc, 0, 0, 0);
#pragma unroll
        for (int r = 0; r < 4; ++r) { sgh[r] += acc[r]; qgh[r] += acc[r] * acc[r]; }
        ghp[ni][0] = cvtpk(acc[0], acc[1]);
        ghp[ni][1] = cvtpk(acc[2], acc[3]);
    }

    // ---- inp A-frags (after LDS write above; same-wave ordering) ----
    s16x8 ain[2];
    ain[0] = lds_frag(&hb[t * 68 + q * 8]);
    ain[1] = lds_frag(&hb[t * 68 + 32 + q * 8]);

    // ---- gi = inp @ Wih^T ----
    float sgi[4] = {0.f, 0.f, 0.f, 0.f}, qgi[4] = {0.f, 0.f, 0.f, 0.f};
    u32 gip[12][2];
#pragma unroll
    for (int ni = 0; ni < 12; ++ni) {
        s16x8 b0 = gfrag(wihb, ni * 16 + t, 0, q);
        s16x8 b1 = gfrag(wihb, ni * 16 + t, 1, q);
        f32x4 acc = {0.f, 0.f, 0.f, 0.f};
        acc = __builtin_amdgcn_mfma_f32_16x16x32_bf16(ain[0], b0, acc, 0, 0, 0);
        acc = __builtin_amdgcn_mfma_f32_16x16x32_bf16(ain[1], b1, acc, 0, 0, 0);
#pragma unroll
        for (int r = 0; r < 4; ++r) { sgi[r] += acc[r]; qgi[r] += acc[r] * acc[r]; }
        gip[ni][0] = cvtpk(acc[0], acc[1]);
        gip[ni][1] = cvtpk(acc[2], acc[3]);
    }

    // ---- reduce stats over t-group ----
#pragma unroll
    for (int m = 1; m < 16; m <<= 1) {
#pragma unroll
        for (int r = 0; r < 4; ++r) {
            sgh[r] += __shfl_xor(sgh[r], m, 64);
            qgh[r] += __shfl_xor(qgh[r], m, 64);
            sgi[r] += __shfl_xor(sgi[r], m, 64);
            qgi[r] += __shfl_xor(qgi[r], m, 64);
        }
    }
    float mi_[4], ri_[4], mh_[4], rh_[4];
#pragma unroll
    for (int r = 0; r < 4; ++r) {
        mi_[r] = sgi[r] * (1.f / 192.f);
        mh_[r] = sgh[r] * (1.f / 192.f);
        ri_[r] = rsqrtf(qgi[r] * (1.f / 192.f) - mi_[r] * mi_[r] + EPSI);
        rh_[r] = rsqrtf(qgh[r] * (1.f / 192.f) - mh_[r] * mh_[r] + EPSI);
    }

    // ---- gates + hx update + float4 stores ----
    f32x4 bihr = *(const f32x4*)(bih + 4 * t);
    f32x4 bihi = *(const f32x4*)(bih + 64 + 4 * t);
    f32x4 bihn = *(const f32x4*)(bih + 128 + 4 * t);
    f32x4 bhhr = *(const f32x4*)(bhh + 4 * t);
    f32x4 bhhi = *(const f32x4*)(bhh + 64 + 4 * t);
    f32x4 bhhn = *(const f32x4*)(bhh + 128 + 4 * t);
#pragma unroll
    for (int r = 0; r < 4; ++r) {
        int node = nbase + q * 4 + r;
        f32x4 res;
#pragma unroll
        for (int ni = 0; ni < 4; ++ni) {
            float iv_r = (unpk(gip[ni], r) - mi_[r]) * ri_[r];
            float iv_i = (unpk(gip[ni + 4], r) - mi_[r]) * ri_[r];
            float iv_n = (unpk(gip[ni + 8], r) - mi_[r]) * ri_[r];
            float hv_r = (unpk(ghp[ni], r) - mh_[r]) * rh_[r];
            float hv_i = (unpk(ghp[ni + 4], r) - mh_[r]) * rh_[r];
            float hv_n = (unpk(ghp[ni + 8], r) - mh_[r]) * rh_[r];
            float rg = sigmoidf_(iv_r + bihr[ni] + hv_r + bhhr[ni]);
            float zg = sigmoidf_(iv_i + bihi[ni] + hv_i + bhhi[ni]);
            float ng = tanhf_(iv_n + bihn[ni] + rg * (hv_n + bhhn[ni]));
            float ho = bf2f((u16)((ni & 1) ? (hxpk[r][ni >> 1] >> 16)
                                           : (hxpk[r][ni >> 1] & 0xffffu)));
            res[ni] = ng + zg * (ho - ng);
        }
        if (node < NN)
            *(f32x4*)(outp + (size_t)node * 256 + (size_t)(it + 1) * 64 + 4 * t) = res;
    }
}

extern "C" void kernel_launch(void* const* d_in, const int* in_sizes, int n_in,
                              void* d_out, int out_size, void* d_ws, size_t ws_size,
                              hipStream_t stream)
{
    const float* hx  = (const float*)d_in[0];
    const int*   eix = (const int*)d_in[1];
    const float* ef  = (const float*)d_in[2];
    const float* fW1 = (const float*)d_in[3];
    const float* fb1 = (const float*)d_in[4];
    const float* fW2 = (const float*)d_in[5];
    const float* fb2 = (const float*)d_in[6];
    const float* fW3 = (const float*)d_in[7];
    const float* fb3 = (const float*)d_in[8];
    const float* Wih = (const float*)d_in[9];
    const float* Whh = (const float*)d_in[10];
    const float* bih = (const float*)d_in[11];
    const float* bhh = (const float*)d_in[12];
    const float* Wig = (const float*)d_in[13];
    const float* big = (const float*)d_in[14];
    float* outp = (float*)d_out;
    char* ws = (char*)d_ws;

    u16*    w      = (u16*)(ws + WS_W);
    float*  agg    = (float*)(ws + WS_AGG);
    u16*    wb     = (u16*)(ws + WS_WB);
    float*  invdeg = (float*)(ws + WS_INVDEG);
    int*    counts = (int*)(ws + WS_COUNTS);
    int*    rowst  = (int*)(ws + WS_ROWSTART);
    int*    cursor = (int*)(ws + WS_CURSOR);
    int*    bsum   = (int*)(ws + WS_BSUM);
    int*    bsumex = (int*)(ws + WS_BSUMEX);
    int*    srcs   = (int*)(ws + WS_SRC);
    int*    eperm  = (int*)(ws + WS_EPERM);

    hipMemsetAsync(counts, 0, NN * sizeof(int), stream);
    k_prep_w<<<(WB_TOTAL + 255) / 256, 256, 0, stream>>>(Wig, Whh, Wih, fW1, fW2, fW3, wb);
    k_count<<<(NE + 255) / 256, 256, 0, stream>>>(eix, counts);
    k_scan_partial<<<391, 256, 0, stream>>>(counts, bsum);
    k_scan_bsum<<<1, 512, 0, stream>>>(bsum, bsumex);
    k_scan_final<<<391, 256, 0, stream>>>(counts, bsumex, rowst, cursor, invdeg);
    k_scatter<<<(NE + 255) / 256, 256, 0, stream>>>(eix, cursor, srcs, eperm);
    k_fnet_mfma<<<9766, 256, 0, stream>>>(ef, fb1, fb2, fb3, eperm, wb, w);
    k_init<<<6250, 256, 0, stream>>>((const float4*)hx, outp);

    for (int it = 0; it < 3; ++it) {
        k_agg<<<25000, 256, 0, stream>>>(outp, w, srcs, rowst, invdeg, agg, it);
        k_gru_fused<<<1563, 256, 0, stream>>>(outp, agg, wb, big, bih, bhh, it);
    }
}

// Round 7
// 807.156 us; speedup vs baseline: 1.1211x; 1.0151x over previous
//
#include <hip/hip_runtime.h>
#include <math.h>

#define NN 100000
#define NE 1250000
#define EPSI 1e-5f

// ---- workspace layout (bytes) ----
#define WS_W        0ull          // bf16 [NE*64]            160,000,000  (CSR-ordered)
#define WS_AGG      160000000ull  // f32  [NN*64]             25,600,000
#define WS_WB       185600000ull  // bf16 weights (see k_prep_w)
#define WS_INVDEG   264000000ull  // f32 [NN]
#define WS_COUNTS   264400000ull  // i32 [NN]
#define WS_ROWSTART 264800000ull  // i32 [NN+1]
#define WS_CURSOR   265200128ull  // i32 [NN]
#define WS_BSUM     265600128ull  // i32 [391]
#define WS_BSUMEX   265601792ull  // i32 [391]
#define WS_SRC      265603584ull  // i32 [NE]  src node per CSR slot       5,000,000
#define WS_EPERM    270603584ull  // i32 [NE]  edge id -> CSR slot         5,000,000

// wb (bf16) sub-layout, all row-permuted by p(n)=4*(n&15)+(n>>4) within
// each 64-row block:
//   [0)      Wig   64x64
//   [4096)   Whh  192x64   (perm within each gate's 64 rows)
//   [16384)  Wih  192x64   (perm within each gate's 64 rows)
//   [28672)  W1    64x16   (13 cols + 3 zero pad)
//   [29696)  W2    64x64
//   [33792)  W3    64x64   -> total 37888 elements
#define WB_TOTAL 37888

typedef unsigned short u16;
typedef unsigned int u32;
typedef short s16x4 __attribute__((ext_vector_type(4)));
typedef short s16x8 __attribute__((ext_vector_type(8)));
typedef float f32x4 __attribute__((ext_vector_type(4)));
typedef u32 u32x4 __attribute__((ext_vector_type(4)));
typedef u32 u32x2 __attribute__((ext_vector_type(2)));
typedef float f32x4u __attribute__((ext_vector_type(4), aligned(4)));

__device__ __forceinline__ u16 f2bf(float f) {
    u32 u = __float_as_uint(f);
    return (u16)((u + 0x7fffu + ((u >> 16) & 1u)) >> 16);   // RNE
}
__device__ __forceinline__ float bf2f(u16 b) {
    return __uint_as_float(((u32)b) << 16);
}
// packed f32x2 -> bf16x2 (RNE), 1 VALU op
__device__ __forceinline__ u32 cvtpk(float lo, float hi) {
    u32 r;
    asm("v_cvt_pk_bf16_f32 %0, %1, %2" : "=v"(r) : "v"(lo), "v"(hi));
    return r;
}
__device__ __forceinline__ float sigmoidf_(float x) {
    return 1.f / (1.f + __expf(-x));
}
// tanh via exp, saturating at +-1; ~4 VALU ops vs libm tanhf's ~20
__device__ __forceinline__ float tanhf_(float x) {
    float e = __expf(2.f * x);
    return 1.f - 2.f / (e + 1.f);
}
__device__ __forceinline__ s16x8 lds_frag(const u16* p) {
    s16x4 lo = *(const s16x4*)p;
    s16x4 hi = *(const s16x4*)(p + 4);
    return __builtin_shufflevector(lo, hi, 0, 1, 2, 3, 4, 5, 6, 7);
}
__device__ __forceinline__ s16x8 gfrag(const u16* W, int n, int ks, int q) {
    // W row-major [64 cols], 16-byte aligned chunks
    return *(const s16x8*)(W + n * 64 + ks * 32 + q * 8);
}
__device__ __forceinline__ float unpk(const u32* p, int r) {
    u32 v = p[r >> 1];
    return bf2f((u16)((r & 1) ? (v >> 16) : (v & 0xffffu)));
}

// ============ fnet via MFMA: per-edge MLP 13->64->64->64, bf16 out ============
// R6 dataflow (LDS weights, hbuf transitions, CSR-scattered stores) with the
// staging prologue VECTORIZED: dwordx4 global loads + b64 LDS writes
// (~30 ops/thread vs ~350 scalar ops in R6 — staging was ~1000 of the ~1400
// measured VALU instructions per wave).
__global__ __launch_bounds__(256) void k_fnet_mfma(
    const float* __restrict__ ef,
    const float* __restrict__ b1, const float* __restrict__ b2,
    const float* __restrict__ b3,
    const int* __restrict__ eperm,
    const u16* __restrict__ wbf,
    u16* __restrict__ wout)
{
    __shared__ u16 w1l[64 * 16];
    __shared__ u16 w2l[64 * 68];
    __shared__ u16 w3l[64 * 68];
    __shared__ u16 hbuf[4][32 * 68];

    int tid = threadIdx.x;
    const u16* wf1 = wbf + 28672;
    const u16* wf2 = wbf + 29696;
    const u16* wf3 = wbf + 33792;
    // w1l: 1024 u16 = 128 x 16B chunks, rows contiguous (16B aligned both sides)
    if (tid < 128)
        *(u32x4*)(&w1l[tid * 8]) = *(const u32x4*)(wf1 + tid * 8);
    // w2l/w3l: 512 x 16B chunks each; row stride 136B in LDS -> split to 2x b64
    for (int c = tid; c < 512; c += 256) {
        int n = c >> 3, cc = c & 7;
        u32x4 v2 = *(const u32x4*)(wf2 + c * 8);
        u32x4 v3 = *(const u32x4*)(wf3 + c * 8);
        u16* p2 = &w2l[n * 68 + cc * 8];
        u16* p3 = &w3l[n * 68 + cc * 8];
        *(u32x2*)p2       = __builtin_shufflevector(v2, v2, 0, 1);
        *(u32x2*)(p2 + 4) = __builtin_shufflevector(v2, v2, 2, 3);
        *(u32x2*)p3       = __builtin_shufflevector(v3, v3, 0, 1);
        *(u32x2*)(p3 + 4) = __builtin_shufflevector(v3, v3, 2, 3);
    }
    __syncthreads();

    int wave = tid >> 6, lane = tid & 63;
    int q = lane >> 4, t = lane & 15;
    int ebase = blockIdx.x * 128 + wave * 32;
    u16* hb = hbuf[wave];

    // biases in permuted slot order: slot (ni,t) holds true feat 4t+ni
    f32x4 b1v = *(const f32x4*)(b1 + 4 * t);
    f32x4 b2v = *(const f32x4*)(b2 + 4 * t);
    f32x4 b3v = *(const f32x4*)(b3 + 4 * t);

    const s16x8 zfrag = {0, 0, 0, 0, 0, 0, 0, 0};

    // ---- ef fragments: vector loads + packed converts ----
    s16x8 a1[2];
#pragma unroll
    for (int mi = 0; mi < 2; ++mi) {
        int e = ebase + mi * 16 + t;
        u32 xp[4] = {0u, 0u, 0u, 0u};
        if (e < NE) {
            const float* ep = ef + (size_t)e * 13;
            if (q == 0) {
                f32x4u v0 = *(const f32x4u*)(ep);
                f32x4u v1 = *(const f32x4u*)(ep + 4);
                xp[0] = cvtpk(v0[0], v0[1]); xp[1] = cvtpk(v0[2], v0[3]);
                xp[2] = cvtpk(v1[0], v1[1]); xp[3] = cvtpk(v1[2], v1[3]);
            } else if (q == 1) {
                f32x4u v0 = *(const f32x4u*)(ep + 8);
                float v12 = ep[12];
                xp[0] = cvtpk(v0[0], v0[1]); xp[1] = cvtpk(v0[2], v0[3]);
                xp[2] = cvtpk(v12, 0.f);
            }
        }
        a1[mi] = __builtin_bit_cast(s16x8, *(u32x4*)xp);
    }

    // ---- W1 fragments ----
    s16x8 B1f[4];
#pragma unroll
    for (int ni = 0; ni < 4; ++ni) {
        s16x8 b = zfrag;
        if (q < 2) b = lds_frag(&w1l[(ni * 16 + t) * 16 + q * 8]);
        B1f[ni] = b;
    }

    // ---- layer 1 ----
    f32x4 h1[4][2];
#pragma unroll
    for (int ni = 0; ni < 4; ++ni)
#pragma unroll
        for (int mi = 0; mi < 2; ++mi) {
            f32x4 acc = {b1v[ni], b1v[ni], b1v[ni], b1v[ni]};
            acc = __builtin_amdgcn_mfma_f32_16x16x32_bf16(a1[mi], B1f[ni], acc, 0, 0, 0);
            h1[ni][mi] = acc;
        }
    // transition 1: relu + pack + b64 write (cols 4t..4t+3 contiguous)
#pragma unroll
    for (int mi = 0; mi < 2; ++mi)
#pragma unroll
        for (int r = 0; r < 4; ++r) {
            u32 lo = cvtpk(fmaxf(h1[0][mi][r], 0.f), fmaxf(h1[1][mi][r], 0.f));
            u32 hi = cvtpk(fmaxf(h1[2][mi][r], 0.f), fmaxf(h1[3][mi][r], 0.f));
            u32x2 v = {lo, hi};
            *(u32x2*)(&hb[(mi * 16 + q * 4 + r) * 68 + 4 * t]) = v;
        }

    // ---- layer 2 ----
    s16x8 a2[2][2];
#pragma unroll
    for (int mi = 0; mi < 2; ++mi)
#pragma unroll
        for (int ks = 0; ks < 2; ++ks)
            a2[mi][ks] = lds_frag(&hb[(mi * 16 + t) * 68 + ks * 32 + q * 8]);
    f32x4 h2[4][2];
#pragma unroll
    for (int ni = 0; ni < 4; ++ni) {
        s16x8 w0 = lds_frag(&w2l[(ni * 16 + t) * 68 + q * 8]);
        s16x8 w1_ = lds_frag(&w2l[(ni * 16 + t) * 68 + 32 + q * 8]);
#pragma unroll
        for (int mi = 0; mi < 2; ++mi) {
            f32x4 acc = {b2v[ni], b2v[ni], b2v[ni], b2v[ni]};
            acc = __builtin_amdgcn_mfma_f32_16x16x32_bf16(a2[mi][0], w0, acc, 0, 0, 0);
            acc = __builtin_amdgcn_mfma_f32_16x16x32_bf16(a2[mi][1], w1_, acc, 0, 0, 0);
            h2[ni][mi] = acc;
        }
    }
    // transition 2
#pragma unroll
    for (int mi = 0; mi < 2; ++mi)
#pragma unroll
        for (int r = 0; r < 4; ++r) {
            u32 lo = cvtpk(fmaxf(h2[0][mi][r], 0.f), fmaxf(h2[1][mi][r], 0.f));
            u32 hi = cvtpk(fmaxf(h2[2][mi][r], 0.f), fmaxf(h2[3][mi][r], 0.f));
            u32x2 v = {lo, hi};
            *(u32x2*)(&hb[(mi * 16 + q * 4 + r) * 68 + 4 * t]) = v;
        }

    // ---- layer 3: registers -> global, no LDS epilogue ----
    s16x8 a3[2][2];
#pragma unroll
    for (int mi = 0; mi < 2; ++mi)
#pragma unroll
        for (int ks = 0; ks < 2; ++ks)
            a3[mi][ks] = lds_frag(&hb[(mi * 16 + t) * 68 + ks * 32 + q * 8]);
    f32x4 h3[4][2];
#pragma unroll
    for (int ni = 0; ni < 4; ++ni) {
        s16x8 w0 = lds_frag(&w3l[(ni * 16 + t) * 68 + q * 8]);
        s16x8 w1_ = lds_frag(&w3l[(ni * 16 + t) * 68 + 32 + q * 8]);
#pragma unroll
        for (int mi = 0; mi < 2; ++mi) {
            f32x4 acc = {b3v[ni], b3v[ni], b3v[ni], b3v[ni]};
            acc = __builtin_amdgcn_mfma_f32_16x16x32_bf16(a3[mi][0], w0, acc, 0, 0, 0);
            acc = __builtin_amdgcn_mfma_f32_16x16x32_bf16(a3[mi][1], w1_, acc, 0, 0, 0);
            h3[ni][mi] = acc;
        }
    }
    // CSR positions for this lane's 8 edges (safe-clamped int4 loads)
    int base0 = ebase + q * 4;
    int base1 = ebase + 16 + q * 4;
    int4 pos0 = *(const int4*)(eperm + ((base0 + 3 < NE) ? base0 : 0));
    int4 pos1 = *(const int4*)(eperm + ((base1 + 3 < NE) ? base1 : 0));
#pragma unroll
    for (int mi = 0; mi < 2; ++mi)
#pragma unroll
        for (int r = 0; r < 4; ++r) {
            int e = ebase + mi * 16 + q * 4 + r;
            if (e < NE) {
                int pos = mi ? ((const int*)&pos1)[r] : ((const int*)&pos0)[r];
                u32x2 v = {cvtpk(h3[0][mi][r], h3[1][mi][r]),
                           cvtpk(h3[2][mi][r], h3[3][mi][r])};
                *(u32x2*)(wout + (size_t)pos * 64 + 4 * t) = v;
            }
        }
}

// ------- prep: bf16 weights, row-permuted by p(n) within 64-row blocks -------
__global__ void k_prep_w(const float* __restrict__ Wig, const float* __restrict__ Whh,
                         const float* __restrict__ Wih,
                         const float* __restrict__ W1, const float* __restrict__ W2,
                         const float* __restrict__ W3, u16* __restrict__ wb)
{
    int i = blockIdx.x * 256 + threadIdx.x;   // < WB_TOTAL
    if (i >= WB_TOTAL) return;
    float v;
    if (i < 4096) {
        int n = i >> 6, k = i & 63;
        int pn = ((n & 15) << 2) + (n >> 4);
        v = Wig[pn * 64 + k];
    } else if (i < 16384) {
        int j = i - 4096;
        int n = j >> 6, k = j & 63;
        int g = n >> 6, m = n & 63;
        int pm = ((m & 15) << 2) + (m >> 4);
        v = Whh[(g * 64 + pm) * 64 + k];
    } else if (i < 28672) {
        int j = i - 16384;
        int n = j >> 6, k = j & 63;
        int g = n >> 6, m = n & 63;
        int pm = ((m & 15) << 2) + (m >> 4);
        v = Wih[(g * 64 + pm) * 64 + k];
    } else if (i < 29696) {
        int j = i - 28672;
        int n = j >> 4, k = j & 15;
        int pn = ((n & 15) << 2) + (n >> 4);
        v = (k < 13) ? W1[pn * 13 + k] : 0.f;
    } else if (i < 33792) {
        int j = i - 29696;
        int n = j >> 6, k = j & 63;
        int pn = ((n & 15) << 2) + (n >> 4);
        v = W2[pn * 64 + k];
    } else {
        int j = i - 33792;
        int n = j >> 6, k = j & 63;
        int pn = ((n & 15) << 2) + (n >> 4);
        v = W3[pn * 64 + k];
    }
    wb[i] = f2bf(v);
}

// ---------------- degree counting ----------------
__global__ void k_count(const int* __restrict__ idx, int* __restrict__ counts)
{
    int e = blockIdx.x * 256 + threadIdx.x;
    if (e < NE) atomicAdd(&counts[idx[e]], 1);
}

// ---------------- two-level exclusive scan over counts ----------------
__global__ void k_scan_partial(const int* __restrict__ counts, int* __restrict__ bsum)
{
    __shared__ int s[256];
    int i = blockIdx.x * 256 + threadIdx.x;
    int v = (i < NN) ? counts[i] : 0;
    s[threadIdx.x] = v; __syncthreads();
    for (int off = 128; off > 0; off >>= 1) {
        if (threadIdx.x < off) s[threadIdx.x] += s[threadIdx.x + off];
        __syncthreads();
    }
    if (threadIdx.x == 0) bsum[blockIdx.x] = s[0];
}

__global__ void k_scan_bsum(const int* __restrict__ bsum, int* __restrict__ bsumex)
{
    __shared__ int s[512];
    int t = threadIdx.x;
    int v0 = (t < 391) ? bsum[t] : 0;
    s[t] = v0; __syncthreads();
    for (int off = 1; off < 512; off <<= 1) {
        int add = (t >= off) ? s[t - off] : 0;
        __syncthreads();
        s[t] += add;
        __syncthreads();
    }
    if (t < 391) bsumex[t] = s[t] - v0;
}

__global__ void k_scan_final(const int* __restrict__ counts, const int* __restrict__ bsumex,
                             int* __restrict__ rowstart, int* __restrict__ cursor,
                             float* __restrict__ invdeg)
{
    __shared__ int s[256];
    int t = threadIdx.x;
    int i = blockIdx.x * 256 + t;
    int c = (i < NN) ? counts[i] : 0;
    s[t] = c; __syncthreads();
    for (int off = 1; off < 256; off <<= 1) {
        int add = (t >= off) ? s[t - off] : 0;
        __syncthreads();
        s[t] += add;
        __syncthreads();
    }
    int ex = s[t] - c + bsumex[blockIdx.x];
    if (i < NN) {
        rowstart[i] = ex;
        cursor[i] = ex;
        invdeg[i] = 1.f / (float)(c > 1 ? c : 1);
    }
    if (i == 0) rowstart[NN] = NE;
}

// ------- scatter edges into CSR order: srcs[p]=src, eperm[e]=p -------
__global__ void k_scatter(const int* __restrict__ idx, int* __restrict__ cursor,
                          int* __restrict__ srcs, int* __restrict__ eperm)
{
    int e = blockIdx.x * 256 + threadIdx.x;
    if (e < NE) {
        int d = idx[e];
        int s = idx[NE + e];
        int p = atomicAdd(&cursor[d], 1);
        srcs[p] = s;
        eperm[e] = p;
    }
}

// ---------------- copy hx0 into out column 0 ----------------
__global__ void k_init(const float4* __restrict__ hx4, float* __restrict__ outp)
{
    int i = blockIdx.x * 256 + threadIdx.x;
    int n = i >> 4, q = i & 15;
    ((float4*)(outp + (size_t)n * 256))[q] = hx4[i];
}

// ------- aggregation: wave per node; w streams sequentially (CSR order) -------
__global__ __launch_bounds__(256) void k_agg(
    const float* __restrict__ outp, const u16* __restrict__ w,
    const int* __restrict__ srcs, const int* __restrict__ rowstart,
    const float* __restrict__ invdeg, float* __restrict__ agg, int it)
{
    int lane = threadIdx.x & 63;
    int n = blockIdx.x * 4 + (threadIdx.x >> 6);
    n = __builtin_amdgcn_readfirstlane(n);
    int p0 = rowstart[n], p1 = rowstart[n + 1];
    const float* hxcol = outp + (size_t)it * 64 + lane;
    const u16* wp = w + (size_t)p0 * 64 + lane;
    float a0 = 0.f, a1 = 0.f, a2 = 0.f, a3 = 0.f;
    int p = p0;
    for (; p + 8 <= p1; p += 8) {
        int4 sa = *(const int4*)(srcs + p);          // wave-uniform -> s_load
        int4 sb = *(const int4*)(srcs + p + 4);
        float h0 = hxcol[(size_t)sa.x * 256];
        float h1 = hxcol[(size_t)sa.y * 256];
        float h2 = hxcol[(size_t)sa.z * 256];
        float h3 = hxcol[(size_t)sa.w * 256];
        float h4 = hxcol[(size_t)sb.x * 256];
        float h5 = hxcol[(size_t)sb.y * 256];
        float h6 = hxcol[(size_t)sb.z * 256];
        float h7 = hxcol[(size_t)sb.w * 256];
        float w0 = bf2f(__builtin_nontemporal_load(wp));
        float w1 = bf2f(__builtin_nontemporal_load(wp + 64));
        float w2 = bf2f(__builtin_nontemporal_load(wp + 128));
        float w3 = bf2f(__builtin_nontemporal_load(wp + 192));
        float w4 = bf2f(__builtin_nontemporal_load(wp + 256));
        float w5 = bf2f(__builtin_nontemporal_load(wp + 320));
        float w6 = bf2f(__builtin_nontemporal_load(wp + 384));
        float w7 = bf2f(__builtin_nontemporal_load(wp + 448));
        wp += 512;
        a0 = fmaf(h0, w0, a0);
        a1 = fmaf(h1, w1, a1);
        a2 = fmaf(h2, w2, a2);
        a3 = fmaf(h3, w3, a3);
        a0 = fmaf(h4, w4, a0);
        a1 = fmaf(h5, w5, a1);
        a2 = fmaf(h6, w6, a2);
        a3 = fmaf(h7, w7, a3);
    }
    if (p + 4 <= p1) {
        int4 s4 = *(const int4*)(srcs + p);
        float h0 = hxcol[(size_t)s4.x * 256];
        float h1 = hxcol[(size_t)s4.y * 256];
        float h2 = hxcol[(size_t)s4.z * 256];
        float h3 = hxcol[(size_t)s4.w * 256];
        float w0 = bf2f(__builtin_nontemporal_load(wp));
        float w1 = bf2f(__builtin_nontemporal_load(wp + 64));
        float w2 = bf2f(__builtin_nontemporal_load(wp + 128));
        float w3 = bf2f(__builtin_nontemporal_load(wp + 192));
        wp += 256;
        a0 = fmaf(h0, w0, a0);
        a1 = fmaf(h1, w1, a1);
        a2 = fmaf(h2, w2, a2);
        a3 = fmaf(h3, w3, a3);
        p += 4;
    }
    for (; p < p1; ++p) {
        int s = srcs[p];
        float hv = hxcol[(size_t)s * 256];
        float wv = bf2f(__builtin_nontemporal_load(wp));
        wp += 64;
        a0 = fmaf(hv, wv, a0);
    }
    agg[(size_t)n * 64 + lane] = ((a0 + a1) + (a2 + a3)) * invdeg[n];
}

// ======== fused GRU: gate GEMM + gi/gh MFMA + inorm + gates, all in-kernel ========
__global__ __launch_bounds__(256) void k_gru_fused(
    float* __restrict__ outp, const float* __restrict__ agg,
    const u16* __restrict__ wb,
    const float* __restrict__ big, const float* __restrict__ bih,
    const float* __restrict__ bhh, int it)
{
    __shared__ u16 hbuf[4][16 * 68];
    int tid = threadIdx.x;
    int wave = tid >> 6, lane = tid & 63;
    int q = lane >> 4, t = lane & 15;
    int nbase = blockIdx.x * 64 + wave * 16;
    u16* hb = hbuf[wave];
    const u16* wigb = wb;
    const u16* whhb = wb + 4096;
    const u16* wihb = wb + 16384;

    // ---- stage hx -> hb (bf16), float4 reads, packed b64 writes ----
    {
        int c = lane & 15;
        int mrow = lane >> 4;
#pragma unroll
        for (int rep = 0; rep < 4; ++rep) {
            int m = rep * 4 + mrow;
            int node = nbase + m;
            float4 v = make_float4(0.f, 0.f, 0.f, 0.f);
            if (node < NN)
                v = *(const float4*)(outp + (size_t)node * 256 + (size_t)it * 64 + c * 4);
            u32x2 pk = {cvtpk(v.x, v.y), cvtpk(v.z, v.w)};
            *(u32x2*)(&hb[m * 68 + c * 4]) = pk;
        }
    }
    // (wave-private buffer; in-order DS pipe makes a barrier unnecessary)

    // ---- hx A-frags + hx rows 4t..4t+3 (C-layout) ----
    s16x8 ahx[2];
    ahx[0] = lds_frag(&hb[t * 68 + q * 8]);
    ahx[1] = lds_frag(&hb[t * 68 + 32 + q * 8]);
    u32 hxpk[4][2];
#pragma unroll
    for (int r = 0; r < 4; ++r)
        *(u32x2*)hxpk[r] = *(const u32x2*)(&hb[(q * 4 + r) * 68 + 4 * t]);

    // ---- gate GEMM: sigmoid(hx @ Wig^T + big) * agg -> inp (to hb) ----
    f32x4 bgv = *(const f32x4*)(big + 4 * t);
    f32x4 gacc[4];
#pragma unroll
    for (int ni = 0; ni < 4; ++ni) {
        s16x8 b0 = gfrag(wigb, ni * 16 + t, 0, q);
        s16x8 b1 = gfrag(wigb, ni * 16 + t, 1, q);
        f32x4 acc = {bgv[ni], bgv[ni], bgv[ni], bgv[ni]};
        acc = __builtin_amdgcn_mfma_f32_16x16x32_bf16(ahx[0], b0, acc, 0, 0, 0);
        acc = __builtin_amdgcn_mfma_f32_16x16x32_bf16(ahx[1], b1, acc, 0, 0, 0);
        gacc[ni] = acc;
    }
#pragma unroll
    for (int r = 0; r < 4; ++r) {
        int node = nbase + q * 4 + r;
        f32x4 av = {0.f, 0.f, 0.f, 0.f};
        if (node < NN) av = *(const f32x4*)(agg + (size_t)node * 64 + 4 * t);
        float i0 = sigmoidf_(gacc[0][r]) * av[0];
        float i1 = sigmoidf_(gacc[1][r]) * av[1];
        float i2 = sigmoidf_(gacc[2][r]) * av[2];
        float i3 = sigmoidf_(gacc[3][r]) * av[3];
        u32x2 pk = {cvtpk(i0, i1), cvtpk(i2, i3)};
        *(u32x2*)(&hb[(q * 4 + r) * 68 + 4 * t]) = pk;
    }

    // ---- gh = hx @ Whh^T  (12 tiles, packed bf16 in regs + stats) ----
    float sgh[4] = {0.f, 0.f, 0.f, 0.f}, qgh[4] = {0.f, 0.f, 0.f, 0.f};
    u32 ghp[12][2];
#pragma unroll
    for (int ni = 0; ni < 12; ++ni) {
        s16x8 b0 = gfrag(whhb, ni * 16 + t, 0, q);
        s16x8 b1 = gfrag(whhb, ni * 16 + t, 1, q);
        f32x4 acc = {0.f, 0.f, 0.f, 0.f};
        acc = __builtin_amdgcn_mfma_f32_16x16x32_bf16(ahx[0], b0, acc, 0, 0, 0);
        acc = __builtin_amdgcn_mfma_f32_16x16x32_bf16(ahx[1], b1, acc, 0, 0, 0);
#pragma unroll
        for (int r = 0; r < 4; ++r) { sgh[r] += acc[r]; qgh[r] += acc[r] * acc[r]; }
        ghp[ni][0] = cvtpk(acc[0], acc[1]);
        ghp[ni][1] = cvtpk(acc[2], acc[3]);
    }

    // ---- inp A-frags (after LDS write above; same-wave ordering) ----
    s16x8 ain[2];
    ain[0] = lds_frag(&hb[t * 68 + q * 8]);
    ain[1] = lds_frag(&hb[t * 68 + 32 + q * 8]);

    // ---- gi = inp @ Wih^T ----
    float sgi[4] = {0.f, 0.f, 0.f, 0.f}, qgi[4] = {0.f, 0.f, 0.f, 0.f};
    u32 gip[12][2];
#pragma unroll
    for (int ni = 0; ni < 12; ++ni) {
        s16x8 b0 = gfrag(wihb, ni * 16 + t, 0, q);
        s16x8 b1 = gfrag(wihb, ni * 16 + t, 1, q);
        f32x4 acc = {0.f, 0.f, 0.f, 0.f};
        acc = __builtin_amdgcn_mfma_f32_16x16x32_bf16(ain[0], b0, acc, 0, 0, 0);
        acc = __builtin_amdgcn_mfma_f32_16x16x32_bf16(ain[1], b1, acc, 0, 0, 0);
#pragma unroll
        for (int r = 0; r < 4; ++r) { sgi[r] += acc[r]; qgi[r] += acc[r] * acc[r]; }
        gip[ni][0] = cvtpk(acc[0], acc[1]);
        gip[ni][1] = cvtpk(acc[2], acc[3]);
    }

    // ---- reduce stats over t-group ----
#pragma unroll
    for (int m = 1; m < 16; m <<= 1) {
#pragma unroll
        for (int r = 0; r < 4; ++r) {
            sgh[r] += __shfl_xor(sgh[r], m, 64);
            qgh[r] += __shfl_xor(qgh[r], m, 64);
            sgi[r] += __shfl_xor(sgi[r], m, 64);
            qgi[r] += __shfl_xor(qgi[r], m, 64);
        }
    }
    float mi_[4], ri_[4], mh_[4], rh_[4];
#pragma unroll
    for (int r = 0; r < 4; ++r) {
        mi_[r] = sgi[r] * (1.f / 192.f);
        mh_[r] = sgh[r] * (1.f / 192.f);
        ri_[r] = rsqrtf(qgi[r] * (1.f / 192.f) - mi_[r] * mi_[r] + EPSI);
        rh_[r] = rsqrtf(qgh[r] * (1.f / 192.f) - mh_[r] * mh_[r] + EPSI);
    }

    // ---- gates + hx update + float4 stores ----
    f32x4 bihr = *(const f32x4*)(bih + 4 * t);
    f32x4 bihi = *(const f32x4*)(bih + 64 + 4 * t);
    f32x4 bihn = *(const f32x4*)(bih + 128 + 4 * t);
    f32x4 bhhr = *(const f32x4*)(bhh + 4 * t);
    f32x4 bhhi = *(const f32x4*)(bhh + 64 + 4 * t);
    f32x4 bhhn = *(const f32x4*)(bhh + 128 + 4 * t);
#pragma unroll
    for (int r = 0; r < 4; ++r) {
        int node = nbase + q * 4 + r;
        f32x4 res;
#pragma unroll
        for (int ni = 0; ni < 4; ++ni) {
            float iv_r = (unpk(gip[ni], r) - mi_[r]) * ri_[r];
            float iv_i = (unpk(gip[ni + 4], r) - mi_[r]) * ri_[r];
            float iv_n = (unpk(gip[ni + 8], r) - mi_[r]) * ri_[r];
            float hv_r = (unpk(ghp[ni], r) - mh_[r]) * rh_[r];
            float hv_i = (unpk(ghp[ni + 4], r) - mh_[r]) * rh_[r];
            float hv_n = (unpk(ghp[ni + 8], r) - mh_[r]) * rh_[r];
            float rg = sigmoidf_(iv_r + bihr[ni] + hv_r + bhhr[ni]);
            float zg = sigmoidf_(iv_i + bihi[ni] + hv_i + bhhi[ni]);
            float ng = tanhf_(iv_n + bihn[ni] + rg * (hv_n + bhhn[ni]));
            float ho = bf2f((u16)((ni & 1) ? (hxpk[r][ni >> 1] >> 16)
                                           : (hxpk[r][ni >> 1] & 0xffffu)));
            res[ni] = ng + zg * (ho - ng);
        }
        if (node < NN)
            *(f32x4*)(outp + (size_t)node * 256 + (size_t)(it + 1) * 64 + 4 * t) = res;
    }
}

extern "C" void kernel_launch(void* const* d_in, const int* in_sizes, int n_in,
                              void* d_out, int out_size, void* d_ws, size_t ws_size,
                              hipStream_t stream)
{
    const float* hx  = (const float*)d_in[0];
    const int*   eix = (const int*)d_in[1];
    const float* ef  = (const float*)d_in[2];
    const float* fW1 = (const float*)d_in[3];
    const float* fb1 = (const float*)d_in[4];
    const float* fW2 = (const float*)d_in[5];
    const float* fb2 = (const float*)d_in[6];
    const float* fW3 = (const float*)d_in[7];
    const float* fb3 = (const float*)d_in[8];
    const float* Wih = (const float*)d_in[9];
    const float* Whh = (const float*)d_in[10];
    const float* bih = (const float*)d_in[11];
    const float* bhh = (const float*)d_in[12];
    const float* Wig = (const float*)d_in[13];
    const float* big = (const float*)d_in[14];
    float* outp = (float*)d_out;
    char* ws = (char*)d_ws;

    u16*    w      = (u16*)(ws + WS_W);
    float*  agg    = (float*)(ws + WS_AGG);
    u16*    wb     = (u16*)(ws + WS_WB);
    float*  invdeg = (float*)(ws + WS_INVDEG);
    int*    counts = (int*)(ws + WS_COUNTS);
    int*    rowst  = (int*)(ws + WS_ROWSTART);
    int*    cursor = (int*)(ws + WS_CURSOR);
    int*    bsum   = (int*)(ws + WS_BSUM);
    int*    bsumex = (int*)(ws + WS_BSUMEX);
    int*    srcs   = (int*)(ws + WS_SRC);
    int*    eperm  = (int*)(ws + WS_EPERM);

    hipMemsetAsync(counts, 0, NN * sizeof(int), stream);
    k_prep_w<<<(WB_TOTAL + 255) / 256, 256, 0, stream>>>(Wig, Whh, Wih, fW1, fW2, fW3, wb);
    k_count<<<(NE + 255) / 256, 256, 0, stream>>>(eix, counts);
    k_scan_partial<<<391, 256, 0, stream>>>(counts, bsum);
    k_scan_bsum<<<1, 512, 0, stream>>>(bsum, bsumex);
    k_scan_final<<<391, 256, 0, stream>>>(counts, bsumex, rowst, cursor, invdeg);
    k_scatter<<<(NE + 255) / 256, 256, 0, stream>>>(eix, cursor, srcs, eperm);
    k_fnet_mfma<<<9766, 256, 0, stream>>>(ef, fb1, fb2, fb3, eperm, wb, w);
    k_init<<<6250, 256, 0, stream>>>((const float4*)hx, outp);

    for (int it = 0; it < 3; ++it) {
        k_agg<<<25000, 256, 0, stream>>>(outp, w, srcs, rowst, invdeg, agg, it);
        k_gru_fused<<<1563, 256, 0, stream>>>(outp, agg, wb, big, bih, bhh, it);
    }
}

// Round 9
// 805.750 us; speedup vs baseline: 1.1231x; 1.0017x over previous
//
#include <hip/hip_runtime.h>
#include <math.h>

#define NN 100000
#define NE 1250000
#define EPSI 1e-5f

// ---- workspace layout (bytes) ----
#define WS_W        0ull          // bf16 [NE*64]            160,000,000  (CSR-ordered)
#define WS_AGG      160000000ull  // f32  [NN*64]             25,600,000
#define WS_WB       185600000ull  // bf16 weights (see k_prep_w)
#define WS_INVDEG   264000000ull  // f32 [NN]
#define WS_COUNTS   264400000ull  // i32 [NN]
#define WS_ROWSTART 264800000ull  // i32 [NN+1]
#define WS_CURSOR   265200128ull  // i32 [NN]
#define WS_BSUM     265600128ull  // i32 [391]
#define WS_BSUMEX   265601792ull  // i32 [391]
#define WS_SRC      265603584ull  // i32 [NE]  src node per CSR slot       5,000,000
#define WS_EPERM    270603584ull  // i32 [NE]  edge id -> CSR slot         5,000,000

// wb (bf16) sub-layout, all row-permuted by p(n)=4*(n&15)+(n>>4) within
// each 64-row block:
//   [0)      Wig   64x64
//   [4096)   Whh  192x64   (perm within each gate's 64 rows)
//   [16384)  Wih  192x64   (perm within each gate's 64 rows)
//   [28672)  W1    64x16   (13 cols + 3 zero pad)
//   [29696)  W2    64x64
//   [33792)  W3    64x64   -> total 37888 elements
#define WB_TOTAL 37888

typedef unsigned short u16;
typedef unsigned int u32;
typedef short s16x4 __attribute__((ext_vector_type(4)));
typedef short s16x8 __attribute__((ext_vector_type(8)));
typedef float f32x4 __attribute__((ext_vector_type(4)));
typedef u32 u32x4 __attribute__((ext_vector_type(4)));
typedef u32 u32x2 __attribute__((ext_vector_type(2)));
typedef float f32x4u __attribute__((ext_vector_type(4), aligned(4)));

__device__ __forceinline__ u16 f2bf(float f) {
    u32 u = __float_as_uint(f);
    return (u16)((u + 0x7fffu + ((u >> 16) & 1u)) >> 16);   // RNE
}
__device__ __forceinline__ float bf2f(u16 b) {
    return __uint_as_float(((u32)b) << 16);
}
// packed f32x2 -> bf16x2 (RNE), 1 VALU op
__device__ __forceinline__ u32 cvtpk(float lo, float hi) {
    u32 r;
    asm("v_cvt_pk_bf16_f32 %0, %1, %2" : "=v"(r) : "v"(lo), "v"(hi));
    return r;
}
__device__ __forceinline__ float sigmoidf_(float x) {
    return 1.f / (1.f + __expf(-x));
}
// tanh via exp, saturating at +-1; ~4 VALU ops vs libm tanhf's ~20
__device__ __forceinline__ float tanhf_(float x) {
    float e = __expf(2.f * x);
    return 1.f - 2.f / (e + 1.f);
}
__device__ __forceinline__ s16x8 lds_frag(const u16* p) {
    s16x4 lo = *(const s16x4*)p;
    s16x4 hi = *(const s16x4*)(p + 4);
    return __builtin_shufflevector(lo, hi, 0, 1, 2, 3, 4, 5, 6, 7);
}
__device__ __forceinline__ s16x8 gfrag(const u16* W, int n, int ks, int q) {
    // W row-major [64 cols], 16-byte aligned chunks
    return *(const s16x8*)(W + n * 64 + ks * 32 + q * 8);
}
__device__ __forceinline__ float unpk(const u32* p, int r) {
    u32 v = p[r >> 1];
    return bf2f((u16)((r & 1) ? (v >> 16) : (v & 0xffffu)));
}

// ============ fnet via MFMA: per-edge MLP 13->64->64->64, bf16 out ============
// R7 structure: LDS weights (vectorized staging), hbuf transitions with
// cvtpk+b64 (row perm p(n) -> lane cols 4t..4t+3 contiguous), layer-3
// registers->global CSR-scattered stores.
__global__ __launch_bounds__(256) void k_fnet_mfma(
    const float* __restrict__ ef,
    const float* __restrict__ b1, const float* __restrict__ b2,
    const float* __restrict__ b3,
    const int* __restrict__ eperm,
    const u16* __restrict__ wbf,
    u16* __restrict__ wout)
{
    __shared__ u16 w1l[64 * 16];
    __shared__ u16 w2l[64 * 68];
    __shared__ u16 w3l[64 * 68];
    __shared__ u16 hbuf[4][32 * 68];

    int tid = threadIdx.x;
    const u16* wf1 = wbf + 28672;
    const u16* wf2 = wbf + 29696;
    const u16* wf3 = wbf + 33792;
    // w1l: 1024 u16 = 128 x 16B chunks, rows contiguous (16B aligned both sides)
    if (tid < 128)
        *(u32x4*)(&w1l[tid * 8]) = *(const u32x4*)(wf1 + tid * 8);
    // w2l/w3l: 512 x 16B chunks each; row stride 136B in LDS -> split to 2x b64
    for (int c = tid; c < 512; c += 256) {
        int n = c >> 3, cc = c & 7;
        u32x4 v2 = *(const u32x4*)(wf2 + c * 8);
        u32x4 v3 = *(const u32x4*)(wf3 + c * 8);
        u16* p2 = &w2l[n * 68 + cc * 8];
        u16* p3 = &w3l[n * 68 + cc * 8];
        *(u32x2*)p2       = __builtin_shufflevector(v2, v2, 0, 1);
        *(u32x2*)(p2 + 4) = __builtin_shufflevector(v2, v2, 2, 3);
        *(u32x2*)p3       = __builtin_shufflevector(v3, v3, 0, 1);
        *(u32x2*)(p3 + 4) = __builtin_shufflevector(v3, v3, 2, 3);
    }
    __syncthreads();

    int wave = tid >> 6, lane = tid & 63;
    int q = lane >> 4, t = lane & 15;
    int ebase = blockIdx.x * 128 + wave * 32;
    u16* hb = hbuf[wave];

    // biases in permuted slot order: slot (ni,t) holds true feat 4t+ni
    f32x4 b1v = *(const f32x4*)(b1 + 4 * t);
    f32x4 b2v = *(const f32x4*)(b2 + 4 * t);
    f32x4 b3v = *(const f32x4*)(b3 + 4 * t);

    const s16x8 zfrag = {0, 0, 0, 0, 0, 0, 0, 0};

    // ---- ef fragments: vector loads + packed converts ----
    s16x8 a1[2];
#pragma unroll
    for (int mi = 0; mi < 2; ++mi) {
        int e = ebase + mi * 16 + t;
        u32 xp[4] = {0u, 0u, 0u, 0u};
        if (e < NE) {
            const float* ep = ef + (size_t)e * 13;
            if (q == 0) {
                f32x4u v0 = *(const f32x4u*)(ep);
                f32x4u v1 = *(const f32x4u*)(ep + 4);
                xp[0] = cvtpk(v0[0], v0[1]); xp[1] = cvtpk(v0[2], v0[3]);
                xp[2] = cvtpk(v1[0], v1[1]); xp[3] = cvtpk(v1[2], v1[3]);
            } else if (q == 1) {
                f32x4u v0 = *(const f32x4u*)(ep + 8);
                float v12 = ep[12];
                xp[0] = cvtpk(v0[0], v0[1]); xp[1] = cvtpk(v0[2], v0[3]);
                xp[2] = cvtpk(v12, 0.f);
            }
        }
        a1[mi] = __builtin_bit_cast(s16x8, *(u32x4*)xp);
    }

    // ---- W1 fragments ----
    s16x8 B1f[4];
#pragma unroll
    for (int ni = 0; ni < 4; ++ni) {
        s16x8 b = zfrag;
        if (q < 2) b = lds_frag(&w1l[(ni * 16 + t) * 16 + q * 8]);
        B1f[ni] = b;
    }

    // ---- layer 1 ----
    f32x4 h1[4][2];
#pragma unroll
    for (int ni = 0; ni < 4; ++ni)
#pragma unroll
        for (int mi = 0; mi < 2; ++mi) {
            f32x4 acc = {b1v[ni], b1v[ni], b1v[ni], b1v[ni]};
            acc = __builtin_amdgcn_mfma_f32_16x16x32_bf16(a1[mi], B1f[ni], acc, 0, 0, 0);
            h1[ni][mi] = acc;
        }
    // transition 1: relu + pack + b64 write (cols 4t..4t+3 contiguous)
#pragma unroll
    for (int mi = 0; mi < 2; ++mi)
#pragma unroll
        for (int r = 0; r < 4; ++r) {
            u32 lo = cvtpk(fmaxf(h1[0][mi][r], 0.f), fmaxf(h1[1][mi][r], 0.f));
            u32 hi = cvtpk(fmaxf(h1[2][mi][r], 0.f), fmaxf(h1[3][mi][r], 0.f));
            u32x2 v = {lo, hi};
            *(u32x2*)(&hb[(mi * 16 + q * 4 + r) * 68 + 4 * t]) = v;
        }

    // ---- layer 2 ----
    s16x8 a2[2][2];
#pragma unroll
    for (int mi = 0; mi < 2; ++mi)
#pragma unroll
        for (int ks = 0; ks < 2; ++ks)
            a2[mi][ks] = lds_frag(&hb[(mi * 16 + t) * 68 + ks * 32 + q * 8]);
    f32x4 h2[4][2];
#pragma unroll
    for (int ni = 0; ni < 4; ++ni) {
        s16x8 w0 = lds_frag(&w2l[(ni * 16 + t) * 68 + q * 8]);
        s16x8 w1_ = lds_frag(&w2l[(ni * 16 + t) * 68 + 32 + q * 8]);
#pragma unroll
        for (int mi = 0; mi < 2; ++mi) {
            f32x4 acc = {b2v[ni], b2v[ni], b2v[ni], b2v[ni]};
            acc = __builtin_amdgcn_mfma_f32_16x16x32_bf16(a2[mi][0], w0, acc, 0, 0, 0);
            acc = __builtin_amdgcn_mfma_f32_16x16x32_bf16(a2[mi][1], w1_, acc, 0, 0, 0);
            h2[ni][mi] = acc;
        }
    }
    // transition 2
#pragma unroll
    for (int mi = 0; mi < 2; ++mi)
#pragma unroll
        for (int r = 0; r < 4; ++r) {
            u32 lo = cvtpk(fmaxf(h2[0][mi][r], 0.f), fmaxf(h2[1][mi][r], 0.f));
            u32 hi = cvtpk(fmaxf(h2[2][mi][r], 0.f), fmaxf(h2[3][mi][r], 0.f));
            u32x2 v = {lo, hi};
            *(u32x2*)(&hb[(mi * 16 + q * 4 + r) * 68 + 4 * t]) = v;
        }

    // ---- layer 3: registers -> global, no LDS epilogue ----
    s16x8 a3[2][2];
#pragma unroll
    for (int mi = 0; mi < 2; ++mi)
#pragma unroll
        for (int ks = 0; ks < 2; ++ks)
            a3[mi][ks] = lds_frag(&hb[(mi * 16 + t) * 68 + ks * 32 + q * 8]);
    f32x4 h3[4][2];
#pragma unroll
    for (int ni = 0; ni < 4; ++ni) {
        s16x8 w0 = lds_frag(&w3l[(ni * 16 + t) * 68 + q * 8]);
        s16x8 w1_ = lds_frag(&w3l[(ni * 16 + t) * 68 + 32 + q * 8]);
#pragma unroll
        for (int mi = 0; mi < 2; ++mi) {
            f32x4 acc = {b3v[ni], b3v[ni], b3v[ni], b3v[ni]};
            acc = __builtin_amdgcn_mfma_f32_16x16x32_bf16(a3[mi][0], w0, acc, 0, 0, 0);
            acc = __builtin_amdgcn_mfma_f32_16x16x32_bf16(a3[mi][1], w1_, acc, 0, 0, 0);
            h3[ni][mi] = acc;
        }
    }
    // CSR positions for this lane's 8 edges (safe-clamped int4 loads)
    int base0 = ebase + q * 4;
    int base1 = ebase + 16 + q * 4;
    int4 pos0 = *(const int4*)(eperm + ((base0 + 3 < NE) ? base0 : 0));
    int4 pos1 = *(const int4*)(eperm + ((base1 + 3 < NE) ? base1 : 0));
#pragma unroll
    for (int mi = 0; mi < 2; ++mi)
#pragma unroll
        for (int r = 0; r < 4; ++r) {
            int e = ebase + mi * 16 + q * 4 + r;
            if (e < NE) {
                int pos = mi ? ((const int*)&pos1)[r] : ((const int*)&pos0)[r];
                u32x2 v = {cvtpk(h3[0][mi][r], h3[1][mi][r]),
                           cvtpk(h3[2][mi][r], h3[3][mi][r])};
                *(u32x2*)(wout + (size_t)pos * 64 + 4 * t) = v;
            }
        }
}

// ------- prep: bf16 weights, row-permuted by p(n) within 64-row blocks -------
__global__ void k_prep_w(const float* __restrict__ Wig, const float* __restrict__ Whh,
                         const float* __restrict__ Wih,
                         const float* __restrict__ W1, const float* __restrict__ W2,
                         const float* __restrict__ W3, u16* __restrict__ wb)
{
    int i = blockIdx.x * 256 + threadIdx.x;   // < WB_TOTAL
    if (i >= WB_TOTAL) return;
    float v;
    if (i < 4096) {
        int n = i >> 6, k = i & 63;
        int pn = ((n & 15) << 2) + (n >> 4);
        v = Wig[pn * 64 + k];
    } else if (i < 16384) {
        int j = i - 4096;
        int n = j >> 6, k = j & 63;
        int g = n >> 6, m = n & 63;
        int pm = ((m & 15) << 2) + (m >> 4);
        v = Whh[(g * 64 + pm) * 64 + k];
    } else if (i < 28672) {
        int j = i - 16384;
        int n = j >> 6, k = j & 63;
        int g = n >> 6, m = n & 63;
        int pm = ((m & 15) << 2) + (m >> 4);
        v = Wih[(g * 64 + pm) * 64 + k];
    } else if (i < 29696) {
        int j = i - 28672;
        int n = j >> 4, k = j & 15;
        int pn = ((n & 15) << 2) + (n >> 4);
        v = (k < 13) ? W1[pn * 13 + k] : 0.f;
    } else if (i < 33792) {
        int j = i - 29696;
        int n = j >> 6, k = j & 63;
        int pn = ((n & 15) << 2) + (n >> 4);
        v = W2[pn * 64 + k];
    } else {
        int j = i - 33792;
        int n = j >> 6, k = j & 63;
        int pn = ((n & 15) << 2) + (n >> 4);
        v = W3[pn * 64 + k];
    }
    wb[i] = f2bf(v);
}

// ---------------- degree counting ----------------
__global__ void k_count(const int* __restrict__ idx, int* __restrict__ counts)
{
    int e = blockIdx.x * 256 + threadIdx.x;
    if (e < NE) atomicAdd(&counts[idx[e]], 1);
}

// ---------------- two-level exclusive scan over counts ----------------
__global__ void k_scan_partial(const int* __restrict__ counts, int* __restrict__ bsum)
{
    __shared__ int s[256];
    int i = blockIdx.x * 256 + threadIdx.x;
    int v = (i < NN) ? counts[i] : 0;
    s[threadIdx.x] = v; __syncthreads();
    for (int off = 128; off > 0; off >>= 1) {
        if (threadIdx.x < off) s[threadIdx.x] += s[threadIdx.x + off];
        __syncthreads();
    }
    if (threadIdx.x == 0) bsum[blockIdx.x] = s[0];
}

__global__ void k_scan_bsum(const int* __restrict__ bsum, int* __restrict__ bsumex)
{
    __shared__ int s[512];
    int t = threadIdx.x;
    int v0 = (t < 391) ? bsum[t] : 0;
    s[t] = v0; __syncthreads();
    for (int off = 1; off < 512; off <<= 1) {
        int add = (t >= off) ? s[t - off] : 0;
        __syncthreads();
        s[t] += add;
        __syncthreads();
    }
    if (t < 391) bsumex[t] = s[t] - v0;
}

__global__ void k_scan_final(const int* __restrict__ counts, const int* __restrict__ bsumex,
                             int* __restrict__ rowstart, int* __restrict__ cursor,
                             float* __restrict__ invdeg)
{
    __shared__ int s[256];
    int t = threadIdx.x;
    int i = blockIdx.x * 256 + t;
    int c = (i < NN) ? counts[i] : 0;
    s[t] = c; __syncthreads();
    for (int off = 1; off < 256; off <<= 1) {
        int add = (t >= off) ? s[t - off] : 0;
        __syncthreads();
        s[t] += add;
        __syncthreads();
    }
    int ex = s[t] - c + bsumex[blockIdx.x];
    if (i < NN) {
        rowstart[i] = ex;
        cursor[i] = ex;
        invdeg[i] = 1.f / (float)(c > 1 ? c : 1);
    }
    if (i == 0) rowstart[NN] = NE;
}

// ------- scatter edges into CSR order: srcs[p]=src (nt), eperm[e]=p -------
__global__ void k_scatter(const int* __restrict__ idx, int* __restrict__ cursor,
                          int* __restrict__ srcs, int* __restrict__ eperm)
{
    int e = blockIdx.x * 256 + threadIdx.x;
    if (e < NE) {
        int d = idx[e];
        int s = idx[NE + e];
        int p = atomicAdd(&cursor[d], 1);
        __builtin_nontemporal_store(s, &srcs[p]);   // random 4B: stream hint
        eperm[e] = p;
    }
}

// ---------------- copy hx0 into out column 0 ----------------
__global__ void k_init(const float4* __restrict__ hx4, float* __restrict__ outp)
{
    int i = blockIdx.x * 256 + threadIdx.x;
    int n = i >> 4, q = i & 15;
    ((float4*)(outp + (size_t)n * 256))[q] = hx4[i];
}

// ------- aggregation v2: wave per node, 4 edges/iteration -------
// Wave splits into 4 x 16-lane groups; group g handles edge p+g. Per lane:
// one 16B float4 hx gather + one 8B w load (nt, CSR-streaming) + 4 FMAs over
// features 4t..4t+3. VMEM instructions /4 and bytes/instruction x4 vs the
// 2B/lane row-sliced loop. Cross-group shfl_xor(16,32) reduce; lanes 0..15
// store agg[n][4t..4t+3] as float4 (true feature order, matches gru read).
__global__ __launch_bounds__(256) void k_agg(
    const float* __restrict__ outp, const u16* __restrict__ w,
    const int* __restrict__ srcs, const int* __restrict__ rowstart,
    const float* __restrict__ invdeg, float* __restrict__ agg, int it)
{
    int lane = threadIdx.x & 63;
    int g = lane >> 4, t = lane & 15;
    int n = blockIdx.x * 4 + (threadIdx.x >> 6);
    n = __builtin_amdgcn_readfirstlane(n);
    int p0 = rowstart[n], p1 = rowstart[n + 1];
    const float* hxb = outp + (size_t)it * 64 + 4 * t;
    f32x4 accA = {0.f, 0.f, 0.f, 0.f};
    f32x4 accB = {0.f, 0.f, 0.f, 0.f};
    int p = p0;
    for (; p + 8 <= p1; p += 8) {
        int sA = srcs[p + g];                 // 16-lane broadcast load
        int sB = srcs[p + 4 + g];
        f32x4 hA = *(const f32x4*)(hxb + (size_t)sA * 256);
        f32x4 hB = *(const f32x4*)(hxb + (size_t)sB * 256);
        s16x4 wA = __builtin_nontemporal_load((const s16x4*)(w + (size_t)(p + g) * 64 + 4 * t));
        s16x4 wB = __builtin_nontemporal_load((const s16x4*)(w + (size_t)(p + 4 + g) * 64 + 4 * t));
#pragma unroll
        for (int j = 0; j < 4; ++j) {
            accA[j] = fmaf(hA[j], bf2f((u16)wA[j]), accA[j]);
            accB[j] = fmaf(hB[j], bf2f((u16)wB[j]), accB[j]);
        }
    }
    if (p + 4 <= p1) {
        int sA = srcs[p + g];
        f32x4 hA = *(const f32x4*)(hxb + (size_t)sA * 256);
        s16x4 wA = __builtin_nontemporal_load((const s16x4*)(w + (size_t)(p + g) * 64 + 4 * t));
#pragma unroll
        for (int j = 0; j < 4; ++j)
            accA[j] = fmaf(hA[j], bf2f((u16)wA[j]), accA[j]);
        p += 4;
    }
    int rem = p1 - p;
    if (g < rem) {
        int sB = srcs[p + g];
        f32x4 hB = *(const f32x4*)(hxb + (size_t)sB * 256);
        s16x4 wB = __builtin_nontemporal_load((const s16x4*)(w + (size_t)(p + g) * 64 + 4 * t));
#pragma unroll
        for (int j = 0; j < 4; ++j)
            accB[j] = fmaf(hB[j], bf2f((u16)wB[j]), accB[j]);
    }
#pragma unroll
    for (int j = 0; j < 4; ++j) accA[j] += accB[j];
    // reduce the 4 groups (lane xor 16, 32)
#pragma unroll
    for (int j = 0; j < 4; ++j) {
        accA[j] += __shfl_xor(accA[j], 16, 64);
        accA[j] += __shfl_xor(accA[j], 32, 64);
    }
    if (g == 0) {
        float inv = invdeg[n];
        f32x4 o = {accA[0] * inv, accA[1] * inv, accA[2] * inv, accA[3] * inv};
        *(f32x4*)(agg + (size_t)n * 64 + 4 * t) = o;
    }
}

// ======== fused GRU: gate GEMM + gi/gh MFMA + inorm + gates, all in-kernel ========
__global__ __launch_bounds__(256) void k_gru_fused(
    float* __restrict__ outp, const float* __restrict__ agg,
    const u16* __restrict__ wb,
    const float* __restrict__ big, const float* __restrict__ bih,
    const float* __restrict__ bhh, int it)
{
    __shared__ u16 hbuf[4][16 * 68];
    int tid = threadIdx.x;
    int wave = tid >> 6, lane = tid & 63;
    int q = lane >> 4, t = lane & 15;
    int nbase = blockIdx.x * 64 + wave * 16;
    u16* hb = hbuf[wave];
    const u16* wigb = wb;
    const u16* whhb = wb + 4096;
    const u16* wihb = wb + 16384;

    // ---- stage hx -> hb (bf16), float4 reads, packed b64 writes ----
    {
        int c = lane & 15;
        int mrow = lane >> 4;
#pragma unroll
        for (int rep = 0; rep < 4; ++rep) {
            int m = rep * 4 + mrow;
            int node = nbase + m;
            float4 v = make_float4(0.f, 0.f, 0.f, 0.f);
            if (node < NN)
                v = *(const float4*)(outp + (size_t)node * 256 + (size_t)it * 64 + c * 4);
            u32x2 pk = {cvtpk(v.x, v.y), cvtpk(v.z, v.w)};
            *(u32x2*)(&hb[m * 68 + c * 4]) = pk;
        }
    }
    // (wave-private buffer; in-order DS pipe makes a barrier unnecessary)

    // ---- hx A-frags + hx rows 4t..4t+3 (C-layout) ----
    s16x8 ahx[2];
    ahx[0] = lds_frag(&hb[t * 68 + q * 8]);
    ahx[1] = lds_frag(&hb[t * 68 + 32 + q * 8]);
    u32 hxpk[4][2];
#pragma unroll
    for (int r = 0; r < 4; ++r)
        *(u32x2*)hxpk[r] = *(const u32x2*)(&hb[(q * 4 + r) * 68 + 4 * t]);

    // ---- gate GEMM: sigmoid(hx @ Wig^T + big) * agg -> inp (to hb) ----
    f32x4 bgv = *(const f32x4*)(big + 4 * t);
    f32x4 gacc[4];
#pragma unroll
    for (int ni = 0; ni < 4; ++ni) {
        s16x8 b0 = gfrag(wigb, ni * 16 + t, 0, q);
        s16x8 b1 = gfrag(wigb, ni * 16 + t, 1, q);
        f32x4 acc = {bgv[ni], bgv[ni], bgv[ni], bgv[ni]};
        acc = __builtin_amdgcn_mfma_f32_16x16x32_bf16(ahx[0], b0, acc, 0, 0, 0);
        acc = __builtin_amdgcn_mfma_f32_16x16x32_bf16(ahx[1], b1, acc, 0, 0, 0);
        gacc[ni] = acc;
    }
#pragma unroll
    for (int r = 0; r < 4; ++r) {
        int node = nbase + q * 4 + r;
        f32x4 av = {0.f, 0.f, 0.f, 0.f};
        if (node < NN) av = *(const f32x4*)(agg + (size_t)node * 64 + 4 * t);
        float i0 = sigmoidf_(gacc[0][r]) * av[0];
        float i1 = sigmoidf_(gacc[1][r]) * av[1];
        float i2 = sigmoidf_(gacc[2][r]) * av[2];
        float i3 = sigmoidf_(gacc[3][r]) * av[3];
        u32x2 pk = {cvtpk(i0, i1), cvtpk(i2, i3)};
        *(u32x2*)(&hb[(q * 4 + r) * 68 + 4 * t]) = pk;
    }

    // ---- gh = hx @ Whh^T  (12 tiles, packed bf16 in regs + stats) ----
    float sgh[4] = {0.f, 0.f, 0.f, 0.f}, qgh[4] = {0.f, 0.f, 0.f, 0.f};
    u32 ghp[12][2];
#pragma unroll
    for (int ni = 0; ni < 12; ++ni) {
        s16x8 b0 = gfrag(whhb, ni * 16 + t, 0, q);
        s16x8 b1 = gfrag(whhb, ni * 16 + t, 1, q);
        f32x4 acc = {0.f, 0.f, 0.f, 0.f};
        acc = __builtin_amdgcn_mfma_f32_16x16x32_bf16(ahx[0], b0, acc, 0, 0, 0);
        acc = __builtin_amdgcn_mfma_f32_16x16x32_bf16(ahx[1], b1, acc, 0, 0, 0);
#pragma unroll
        for (int r = 0; r < 4; ++r) { sgh[r] += acc[r]; qgh[r] += acc[r] * acc[r]; }
        ghp[ni][0] = cvtpk(acc[0], acc[1]);
        ghp[ni][1] = cvtpk(acc[2], acc[3]);
    }

    // ---- inp A-frags (after LDS write above; same-wave ordering) ----
    s16x8 ain[2];
    ain[0] = lds_frag(&hb[t * 68 + q * 8]);
    ain[1] = lds_frag(&hb[t * 68 + 32 + q * 8]);

    // ---- gi = inp @ Wih^T ----
    float sgi[4] = {0.f, 0.f, 0.f, 0.f}, qgi[4] = {0.f, 0.f, 0.f, 0.f};
    u32 gip[12][2];
#pragma unroll
    for (int ni = 0; ni < 12; ++ni) {
        s16x8 b0 = gfrag(wihb, ni * 16 + t, 0, q);
        s16x8 b1 = gfrag(wihb, ni * 16 + t, 1, q);
        f32x4 acc = {0.f, 0.f, 0.f, 0.f};
        acc = __builtin_amdgcn_mfma_f32_16x16x32_bf16(ain[0], b0, acc, 0, 0, 0);
        acc = __builtin_amdgcn_mfma_f32_16x16x32_bf16(ain[1], b1, acc, 0, 0, 0);
#pragma unroll
        for (int r = 0; r < 4; ++r) { sgi[r] += acc[r]; qgi[r] += acc[r] * acc[r]; }
        gip[ni][0] = cvtpk(acc[0], acc[1]);
        gip[ni][1] = cvtpk(acc[2], acc[3]);
    }

    // ---- reduce stats over t-group ----
#pragma unroll
    for (int m = 1; m < 16; m <<= 1) {
#pragma unroll
        for (int r = 0; r < 4; ++r) {
            sgh[r] += __shfl_xor(sgh[r], m, 64);
            qgh[r] += __shfl_xor(qgh[r], m, 64);
            sgi[r] += __shfl_xor(sgi[r], m, 64);
            qgi[r] += __shfl_xor(qgi[r], m, 64);
        }
    }
    float mi_[4], ri_[4], mh_[4], rh_[4];
#pragma unroll
    for (int r = 0; r < 4; ++r) {
        mi_[r] = sgi[r] * (1.f / 192.f);
        mh_[r] = sgh[r] * (1.f / 192.f);
        ri_[r] = rsqrtf(qgi[r] * (1.f / 192.f) - mi_[r] * mi_[r] + EPSI);
        rh_[r] = rsqrtf(qgh[r] * (1.f / 192.f) - mh_[r] * mh_[r] + EPSI);
    }

    // ---- gates + hx update + float4 stores ----
    f32x4 bihr = *(const f32x4*)(bih + 4 * t);
    f32x4 bihi = *(const f32x4*)(bih + 64 + 4 * t);
    f32x4 bihn = *(const f32x4*)(bih + 128 + 4 * t);
    f32x4 bhhr = *(const f32x4*)(bhh + 4 * t);
    f32x4 bhhi = *(const f32x4*)(bhh + 64 + 4 * t);
    f32x4 bhhn = *(const f32x4*)(bhh + 128 + 4 * t);
#pragma unroll
    for (int r = 0; r < 4; ++r) {
        int node = nbase + q * 4 + r;
        f32x4 res;
#pragma unroll
        for (int ni = 0; ni < 4; ++ni) {
            float iv_r = (unpk(gip[ni], r) - mi_[r]) * ri_[r];
            float iv_i = (unpk(gip[ni + 4], r) - mi_[r]) * ri_[r];
            float iv_n = (unpk(gip[ni + 8], r) - mi_[r]) * ri_[r];
            float hv_r = (unpk(ghp[ni], r) - mh_[r]) * rh_[r];
            float hv_i = (unpk(ghp[ni + 4], r) - mh_[r]) * rh_[r];
            float hv_n = (unpk(ghp[ni + 8], r) - mh_[r]) * rh_[r];
            float rg = sigmoidf_(iv_r + bihr[ni] + hv_r + bhhr[ni]);
            float zg = sigmoidf_(iv_i + bihi[ni] + hv_i + bhhi[ni]);
            float ng = tanhf_(iv_n + bihn[ni] + rg * (hv_n + bhhn[ni]));
            float ho = bf2f((u16)((ni & 1) ? (hxpk[r][ni >> 1] >> 16)
                                           : (hxpk[r][ni >> 1] & 0xffffu)));
            res[ni] = ng + zg * (ho - ng);
        }
        if (node < NN)
            *(f32x4*)(outp + (size_t)node * 256 + (size_t)(it + 1) * 64 + 4 * t) = res;
    }
}

extern "C" void kernel_launch(void* const* d_in, const int* in_sizes, int n_in,
                              void* d_out, int out_size, void* d_ws, size_t ws_size,
                              hipStream_t stream)
{
    const float* hx  = (const float*)d_in[0];
    const int*   eix = (const int*)d_in[1];
    const float* ef  = (const float*)d_in[2];
    const float* fW1 = (const float*)d_in[3];
    const float* fb1 = (const float*)d_in[4];
    const float* fW2 = (const float*)d_in[5];
    const float* fb2 = (const float*)d_in[6];
    const float* fW3 = (const float*)d_in[7];
    const float* fb3 = (const float*)d_in[8];
    const float* Wih = (const float*)d_in[9];
    const float* Whh = (const float*)d_in[10];
    const float* bih = (const float*)d_in[11];
    const float* bhh = (const float*)d_in[12];
    const float* Wig = (const float*)d_in[13];
    const float* big = (const float*)d_in[14];
    float* outp = (float*)d_out;
    char* ws = (char*)d_ws;

    u16*    w      = (u16*)(ws + WS_W);
    float*  agg    = (float*)(ws + WS_AGG);
    u16*    wb     = (u16*)(ws + WS_WB);
    float*  invdeg = (float*)(ws + WS_INVDEG);
    int*    counts = (int*)(ws + WS_COUNTS);
    int*    rowst  = (int*)(ws + WS_ROWSTART);
    int*    cursor = (int*)(ws + WS_CURSOR);
    int*    bsum   = (int*)(ws + WS_BSUM);
    int*    bsumex = (int*)(ws + WS_BSUMEX);
    int*    srcs   = (int*)(ws + WS_SRC);
    int*    eperm  = (int*)(ws + WS_EPERM);

    hipMemsetAsync(counts, 0, NN * sizeof(int), stream);
    k_prep_w<<<(WB_TOTAL + 255) / 256, 256, 0, stream>>>(Wig, Whh, Wih, fW1, fW2, fW3, wb);
    k_count<<<(NE + 255) / 256, 256, 0, stream>>>(eix, counts);
    k_scan_partial<<<391, 256, 0, stream>>>(counts, bsum);
    k_scan_bsum<<<1, 512, 0, stream>>>(bsum, bsumex);
    k_scan_final<<<391, 256, 0, stream>>>(counts, bsumex, rowst, cursor, invdeg);
    k_scatter<<<(NE + 255) / 256, 256, 0, stream>>>(eix, cursor, srcs, eperm);
    k_fnet_mfma<<<9766, 256, 0, stream>>>(ef, fb1, fb2, fb3, eperm, wb, w);
    k_init<<<6250, 256, 0, stream>>>((const float4*)hx, outp);

    for (int it = 0; it < 3; ++it) {
        k_agg<<<25000, 256, 0, stream>>>(outp, w, srcs, rowst, invdeg, agg, it);
        k_gru_fused<<<1563, 256, 0, stream>>>(outp, agg, wb, big, bih, bhh, it);
    }
}

// Round 10
// 752.595 us; speedup vs baseline: 1.2024x; 1.0706x over previous
//
#include <hip/hip_runtime.h>
#include <math.h>

#define NN 100000
#define NE 1250000
#define EPSI 1e-5f

// ---- workspace layout (bytes) ----
#define WS_W        0ull          // bf16 [NE*64]            160,000,000  (CSR-ordered)
#define WS_AGG      160000000ull  // f32  [NN*64]             25,600,000  (aliased: cnt8[8][NN] during prep)
#define WS_WB       185600000ull  // bf16 weights (see k_prep_w)
#define WS_INVDEG   264000000ull  // f32 [NN]
#define WS_COUNTS   264400000ull  // i32 [NN]
#define WS_ROWSTART 264800000ull  // i32 [NN+1]
#define WS_CURSOR   265200128ull  // i32 [NN] (unused, kept for layout stability)
#define WS_BSUM     265600128ull  // i32 [391]
#define WS_BSUMEX   265601792ull  // i32 [391]
#define WS_SRC      265603584ull  // i32 [NE]  src node per CSR slot       5,000,000
#define WS_EPERM    270603584ull  // i32 [NE]  rank during prep, then CSR slot

// wb (bf16) sub-layout, all row-permuted by p(n)=4*(n&15)+(n>>4) within
// each 64-row block:
//   [0)      Wig   64x64
//   [4096)   Whh  192x64   (perm within each gate's 64 rows)
//   [16384)  Wih  192x64   (perm within each gate's 64 rows)
//   [28672)  W1    64x16   (13 cols + 3 zero pad)
//   [29696)  W2    64x64
//   [33792)  W3    64x64   -> total 37888 elements
#define WB_TOTAL 37888

typedef unsigned short u16;
typedef unsigned int u32;
typedef short s16x4 __attribute__((ext_vector_type(4)));
typedef short s16x8 __attribute__((ext_vector_type(8)));
typedef float f32x4 __attribute__((ext_vector_type(4)));
typedef u32 u32x4 __attribute__((ext_vector_type(4)));
typedef u32 u32x2 __attribute__((ext_vector_type(2)));
typedef float f32x4u __attribute__((ext_vector_type(4), aligned(4)));

__device__ __forceinline__ u16 f2bf(float f) {
    u32 u = __float_as_uint(f);
    return (u16)((u + 0x7fffu + ((u >> 16) & 1u)) >> 16);   // RNE
}
__device__ __forceinline__ float bf2f(u16 b) {
    return __uint_as_float(((u32)b) << 16);
}
// packed f32x2 -> bf16x2 (RNE), 1 VALU op
__device__ __forceinline__ u32 cvtpk(float lo, float hi) {
    u32 r;
    asm("v_cvt_pk_bf16_f32 %0, %1, %2" : "=v"(r) : "v"(lo), "v"(hi));
    return r;
}
__device__ __forceinline__ float sigmoidf_(float x) {
    return 1.f / (1.f + __expf(-x));
}
// tanh via exp, saturating at +-1; ~4 VALU ops vs libm tanhf's ~20
__device__ __forceinline__ float tanhf_(float x) {
    float e = __expf(2.f * x);
    return 1.f - 2.f / (e + 1.f);
}
__device__ __forceinline__ s16x8 lds_frag(const u16* p) {
    s16x4 lo = *(const s16x4*)p;
    s16x4 hi = *(const s16x4*)(p + 4);
    return __builtin_shufflevector(lo, hi, 0, 1, 2, 3, 4, 5, 6, 7);
}
__device__ __forceinline__ s16x8 gfrag(const u16* W, int n, int ks, int q) {
    // W row-major [64 cols], 16-byte aligned chunks
    return *(const s16x8*)(W + n * 64 + ks * 32 + q * 8);
}
__device__ __forceinline__ float unpk(const u32* p, int r) {
    u32 v = p[r >> 1];
    return bf2f((u16)((r & 1) ? (v >> 16) : (v & 0xffffu)));
}

// ============ fnet via MFMA: per-edge MLP 13->64->64->64, bf16 out ============
// R7 structure: LDS weights (vectorized staging), hbuf transitions with
// cvtpk+b64 (row perm p(n) -> lane cols 4t..4t+3 contiguous), layer-3
// registers->global CSR-scattered stores.
__global__ __launch_bounds__(256) void k_fnet_mfma(
    const float* __restrict__ ef,
    const float* __restrict__ b1, const float* __restrict__ b2,
    const float* __restrict__ b3,
    const int* __restrict__ eperm,
    const u16* __restrict__ wbf,
    u16* __restrict__ wout)
{
    __shared__ u16 w1l[64 * 16];
    __shared__ u16 w2l[64 * 68];
    __shared__ u16 w3l[64 * 68];
    __shared__ u16 hbuf[4][32 * 68];

    int tid = threadIdx.x;
    const u16* wf1 = wbf + 28672;
    const u16* wf2 = wbf + 29696;
    const u16* wf3 = wbf + 33792;
    // w1l: 1024 u16 = 128 x 16B chunks, rows contiguous (16B aligned both sides)
    if (tid < 128)
        *(u32x4*)(&w1l[tid * 8]) = *(const u32x4*)(wf1 + tid * 8);
    // w2l/w3l: 512 x 16B chunks each; row stride 136B in LDS -> split to 2x b64
    for (int c = tid; c < 512; c += 256) {
        int n = c >> 3, cc = c & 7;
        u32x4 v2 = *(const u32x4*)(wf2 + c * 8);
        u32x4 v3 = *(const u32x4*)(wf3 + c * 8);
        u16* p2 = &w2l[n * 68 + cc * 8];
        u16* p3 = &w3l[n * 68 + cc * 8];
        *(u32x2*)p2       = __builtin_shufflevector(v2, v2, 0, 1);
        *(u32x2*)(p2 + 4) = __builtin_shufflevector(v2, v2, 2, 3);
        *(u32x2*)p3       = __builtin_shufflevector(v3, v3, 0, 1);
        *(u32x2*)(p3 + 4) = __builtin_shufflevector(v3, v3, 2, 3);
    }
    __syncthreads();

    int wave = tid >> 6, lane = tid & 63;
    int q = lane >> 4, t = lane & 15;
    int ebase = blockIdx.x * 128 + wave * 32;
    u16* hb = hbuf[wave];

    // biases in permuted slot order: slot (ni,t) holds true feat 4t+ni
    f32x4 b1v = *(const f32x4*)(b1 + 4 * t);
    f32x4 b2v = *(const f32x4*)(b2 + 4 * t);
    f32x4 b3v = *(const f32x4*)(b3 + 4 * t);

    const s16x8 zfrag = {0, 0, 0, 0, 0, 0, 0, 0};

    // ---- ef fragments: vector loads + packed converts ----
    s16x8 a1[2];
#pragma unroll
    for (int mi = 0; mi < 2; ++mi) {
        int e = ebase + mi * 16 + t;
        u32 xp[4] = {0u, 0u, 0u, 0u};
        if (e < NE) {
            const float* ep = ef + (size_t)e * 13;
            if (q == 0) {
                f32x4u v0 = *(const f32x4u*)(ep);
                f32x4u v1 = *(const f32x4u*)(ep + 4);
                xp[0] = cvtpk(v0[0], v0[1]); xp[1] = cvtpk(v0[2], v0[3]);
                xp[2] = cvtpk(v1[0], v1[1]); xp[3] = cvtpk(v1[2], v1[3]);
            } else if (q == 1) {
                f32x4u v0 = *(const f32x4u*)(ep + 8);
                float v12 = ep[12];
                xp[0] = cvtpk(v0[0], v0[1]); xp[1] = cvtpk(v0[2], v0[3]);
                xp[2] = cvtpk(v12, 0.f);
            }
        }
        a1[mi] = __builtin_bit_cast(s16x8, *(u32x4*)xp);
    }

    // ---- W1 fragments ----
    s16x8 B1f[4];
#pragma unroll
    for (int ni = 0; ni < 4; ++ni) {
        s16x8 b = zfrag;
        if (q < 2) b = lds_frag(&w1l[(ni * 16 + t) * 16 + q * 8]);
        B1f[ni] = b;
    }

    // ---- layer 1 ----
    f32x4 h1[4][2];
#pragma unroll
    for (int ni = 0; ni < 4; ++ni)
#pragma unroll
        for (int mi = 0; mi < 2; ++mi) {
            f32x4 acc = {b1v[ni], b1v[ni], b1v[ni], b1v[ni]};
            acc = __builtin_amdgcn_mfma_f32_16x16x32_bf16(a1[mi], B1f[ni], acc, 0, 0, 0);
            h1[ni][mi] = acc;
        }
    // transition 1: relu + pack + b64 write (cols 4t..4t+3 contiguous)
#pragma unroll
    for (int mi = 0; mi < 2; ++mi)
#pragma unroll
        for (int r = 0; r < 4; ++r) {
            u32 lo = cvtpk(fmaxf(h1[0][mi][r], 0.f), fmaxf(h1[1][mi][r], 0.f));
            u32 hi = cvtpk(fmaxf(h1[2][mi][r], 0.f), fmaxf(h1[3][mi][r], 0.f));
            u32x2 v = {lo, hi};
            *(u32x2*)(&hb[(mi * 16 + q * 4 + r) * 68 + 4 * t]) = v;
        }

    // ---- layer 2 ----
    s16x8 a2[2][2];
#pragma unroll
    for (int mi = 0; mi < 2; ++mi)
#pragma unroll
        for (int ks = 0; ks < 2; ++ks)
            a2[mi][ks] = lds_frag(&hb[(mi * 16 + t) * 68 + ks * 32 + q * 8]);
    f32x4 h2[4][2];
#pragma unroll
    for (int ni = 0; ni < 4; ++ni) {
        s16x8 w0 = lds_frag(&w2l[(ni * 16 + t) * 68 + q * 8]);
        s16x8 w1_ = lds_frag(&w2l[(ni * 16 + t) * 68 + 32 + q * 8]);
#pragma unroll
        for (int mi = 0; mi < 2; ++mi) {
            f32x4 acc = {b2v[ni], b2v[ni], b2v[ni], b2v[ni]};
            acc = __builtin_amdgcn_mfma_f32_16x16x32_bf16(a2[mi][0], w0, acc, 0, 0, 0);
            acc = __builtin_amdgcn_mfma_f32_16x16x32_bf16(a2[mi][1], w1_, acc, 0, 0, 0);
            h2[ni][mi] = acc;
        }
    }
    // transition 2
#pragma unroll
    for (int mi = 0; mi < 2; ++mi)
#pragma unroll
        for (int r = 0; r < 4; ++r) {
            u32 lo = cvtpk(fmaxf(h2[0][mi][r], 0.f), fmaxf(h2[1][mi][r], 0.f));
            u32 hi = cvtpk(fmaxf(h2[2][mi][r], 0.f), fmaxf(h2[3][mi][r], 0.f));
            u32x2 v = {lo, hi};
            *(u32x2*)(&hb[(mi * 16 + q * 4 + r) * 68 + 4 * t]) = v;
        }

    // ---- layer 3: registers -> global, no LDS epilogue ----
    s16x8 a3[2][2];
#pragma unroll
    for (int mi = 0; mi < 2; ++mi)
#pragma unroll
        for (int ks = 0; ks < 2; ++ks)
            a3[mi][ks] = lds_frag(&hb[(mi * 16 + t) * 68 + ks * 32 + q * 8]);
    f32x4 h3[4][2];
#pragma unroll
    for (int ni = 0; ni < 4; ++ni) {
        s16x8 w0 = lds_frag(&w3l[(ni * 16 + t) * 68 + q * 8]);
        s16x8 w1_ = lds_frag(&w3l[(ni * 16 + t) * 68 + 32 + q * 8]);
#pragma unroll
        for (int mi = 0; mi < 2; ++mi) {
            f32x4 acc = {b3v[ni], b3v[ni], b3v[ni], b3v[ni]};
            acc = __builtin_amdgcn_mfma_f32_16x16x32_bf16(a3[mi][0], w0, acc, 0, 0, 0);
            acc = __builtin_amdgcn_mfma_f32_16x16x32_bf16(a3[mi][1], w1_, acc, 0, 0, 0);
            h3[ni][mi] = acc;
        }
    }
    // CSR positions for this lane's 8 edges (safe-clamped int4 loads)
    int base0 = ebase + q * 4;
    int base1 = ebase + 16 + q * 4;
    int4 pos0 = *(const int4*)(eperm + ((base0 + 3 < NE) ? base0 : 0));
    int4 pos1 = *(const int4*)(eperm + ((base1 + 3 < NE) ? base1 : 0));
#pragma unroll
    for (int mi = 0; mi < 2; ++mi)
#pragma unroll
        for (int r = 0; r < 4; ++r) {
            int e = ebase + mi * 16 + q * 4 + r;
            if (e < NE) {
                int pos = mi ? ((const int*)&pos1)[r] : ((const int*)&pos0)[r];
                u32x2 v = {cvtpk(h3[0][mi][r], h3[1][mi][r]),
                           cvtpk(h3[2][mi][r], h3[3][mi][r])};
                *(u32x2*)(wout + (size_t)pos * 64 + 4 * t) = v;
            }
        }
}

// ------- prep: bf16 weights, row-permuted by p(n) within 64-row blocks -------
__global__ void k_prep_w(const float* __restrict__ Wig, const float* __restrict__ Whh,
                         const float* __restrict__ Wih,
                         const float* __restrict__ W1, const float* __restrict__ W2,
                         const float* __restrict__ W3, u16* __restrict__ wb)
{
    int i = blockIdx.x * 256 + threadIdx.x;   // < WB_TOTAL
    if (i >= WB_TOTAL) return;
    float v;
    if (i < 4096) {
        int n = i >> 6, k = i & 63;
        int pn = ((n & 15) << 2) + (n >> 4);
        v = Wig[pn * 64 + k];
    } else if (i < 16384) {
        int j = i - 4096;
        int n = j >> 6, k = j & 63;
        int g = n >> 6, m = n & 63;
        int pm = ((m & 15) << 2) + (m >> 4);
        v = Whh[(g * 64 + pm) * 64 + k];
    } else if (i < 28672) {
        int j = i - 16384;
        int n = j >> 6, k = j & 63;
        int g = n >> 6, m = n & 63;
        int pm = ((m & 15) << 2) + (m >> 4);
        v = Wih[(g * 64 + pm) * 64 + k];
    } else if (i < 29696) {
        int j = i - 28672;
        int n = j >> 4, k = j & 15;
        int pn = ((n & 15) << 2) + (n >> 4);
        v = (k < 13) ? W1[pn * 13 + k] : 0.f;
    } else if (i < 33792) {
        int j = i - 29696;
        int n = j >> 6, k = j & 63;
        int pn = ((n & 15) << 2) + (n >> 4);
        v = W2[pn * 64 + k];
    } else {
        int j = i - 33792;
        int n = j >> 6, k = j & 63;
        int pn = ((n & 15) << 2) + (n >> 4);
        v = W3[pn * 64 + k];
    }
    wb[i] = f2bf(v);
}

// ------- rank pass: ONE atomic pass, 8-way partitioned counters -------
// Partition k = blockIdx&7 (~XCD-local on round-robin dispatch): counter
// lines of partition k are touched by ~1/8 of blocks -> no cross-XCD L2
// line ping-pong. rank stored coalesced into eperm (temp). Replaces the
// old k_count + k_scatter atomic double-pass.
__global__ void k_rank(const int* __restrict__ idx, int* __restrict__ cnt8,
                       int* __restrict__ rank_out)
{
    int e = blockIdx.x * 256 + threadIdx.x;
    int k = blockIdx.x & 7;
    if (e < NE) {
        int d = idx[e];
        int r = atomicAdd(&cnt8[k * NN + d], 1);
        rank_out[e] = r;                       // coalesced
    }
}

// ------- fold 8 partition counts: totals -> counts, cnt8 -> excl prefix -----
__global__ void k_sumcnt(int* __restrict__ cnt8, int* __restrict__ counts)
{
    int d = blockIdx.x * 256 + threadIdx.x;
    if (d >= NN) return;
    int c[8], run = 0;
#pragma unroll
    for (int k = 0; k < 8; ++k) c[k] = cnt8[k * NN + d];
#pragma unroll
    for (int k = 0; k < 8; ++k) { int t = c[k]; cnt8[k * NN + d] = run; run += t; }
    counts[d] = run;
}

// ---------------- two-level exclusive scan over counts ----------------
__global__ void k_scan_partial(const int* __restrict__ counts, int* __restrict__ bsum)
{
    __shared__ int s[256];
    int i = blockIdx.x * 256 + threadIdx.x;
    int v = (i < NN) ? counts[i] : 0;
    s[threadIdx.x] = v; __syncthreads();
    for (int off = 128; off > 0; off >>= 1) {
        if (threadIdx.x < off) s[threadIdx.x] += s[threadIdx.x + off];
        __syncthreads();
    }
    if (threadIdx.x == 0) bsum[blockIdx.x] = s[0];
}

__global__ void k_scan_bsum(const int* __restrict__ bsum, int* __restrict__ bsumex)
{
    __shared__ int s[512];
    int t = threadIdx.x;
    int v0 = (t < 391) ? bsum[t] : 0;
    s[t] = v0; __syncthreads();
    for (int off = 1; off < 512; off <<= 1) {
        int add = (t >= off) ? s[t - off] : 0;
        __syncthreads();
        s[t] += add;
        __syncthreads();
    }
    if (t < 391) bsumex[t] = s[t] - v0;
}

__global__ void k_scan_final(const int* __restrict__ counts, const int* __restrict__ bsumex,
                             int* __restrict__ rowstart, float* __restrict__ invdeg)
{
    __shared__ int s[256];
    int t = threadIdx.x;
    int i = blockIdx.x * 256 + t;
    int c = (i < NN) ? counts[i] : 0;
    s[t] = c; __syncthreads();
    for (int off = 1; off < 256; off <<= 1) {
        int add = (t >= off) ? s[t - off] : 0;
        __syncthreads();
        s[t] += add;
        __syncthreads();
    }
    int ex = s[t] - c + bsumex[blockIdx.x];
    if (i < NN) {
        rowstart[i] = ex;
        invdeg[i] = 1.f / (float)(c > 1 ? c : 1);
    }
    if (i == 0) rowstart[NN] = NE;
}

// ------- finalize: p = rowstart[d] + partition offset + rank; streaming -----
__global__ void k_finalize(const int* __restrict__ idx, const int* __restrict__ cnt8,
                           const int* __restrict__ rowstart,
                           int* __restrict__ eperm, int* __restrict__ srcs)
{
    int e = blockIdx.x * 256 + threadIdx.x;
    if (e < NE) {
        int d = idx[e];
        int s = idx[NE + e];
        int k = (e >> 8) & 7;                  // == blockIdx&7 of k_rank
        int r = eperm[e];                      // temp rank (coalesced)
        int p = rowstart[d] + cnt8[k * NN + d] + r;
        eperm[e] = p;                          // coalesced
        __builtin_nontemporal_store(s, &srcs[p]);  // random 4B, fire-and-forget
    }
}

// ---------------- copy hx0 into out column 0 ----------------
__global__ void k_init(const float4* __restrict__ hx4, float* __restrict__ outp)
{
    int i = blockIdx.x * 256 + threadIdx.x;
    int n = i >> 4, q = i & 15;
    ((float4*)(outp + (size_t)n * 256))[q] = hx4[i];
}

// ------- aggregation v2: wave per node, 4 edges/iteration -------
// Wave splits into 4 x 16-lane groups; group g handles edge p+g. Per lane:
// one 16B float4 hx gather + one 8B w load (nt, CSR-streaming) + 4 FMAs over
// features 4t..4t+3. Cross-group shfl_xor(16,32) reduce; lanes 0..15 store
// agg[n][4t..4t+3] as float4 (true feature order, matches gru read).
__global__ __launch_bounds__(256) void k_agg(
    const float* __restrict__ outp, const u16* __restrict__ w,
    const int* __restrict__ srcs, const int* __restrict__ rowstart,
    const float* __restrict__ invdeg, float* __restrict__ agg, int it)
{
    int lane = threadIdx.x & 63;
    int g = lane >> 4, t = lane & 15;
    int n = blockIdx.x * 4 + (threadIdx.x >> 6);
    n = __builtin_amdgcn_readfirstlane(n);
    int p0 = rowstart[n], p1 = rowstart[n + 1];
    const float* hxb = outp + (size_t)it * 64 + 4 * t;
    f32x4 accA = {0.f, 0.f, 0.f, 0.f};
    f32x4 accB = {0.f, 0.f, 0.f, 0.f};
    int p = p0;
    for (; p + 8 <= p1; p += 8) {
        int sA = srcs[p + g];                 // 16-lane broadcast load
        int sB = srcs[p + 4 + g];
        f32x4 hA = *(const f32x4*)(hxb + (size_t)sA * 256);
        f32x4 hB = *(const f32x4*)(hxb + (size_t)sB * 256);
        s16x4 wA = __builtin_nontemporal_load((const s16x4*)(w + (size_t)(p + g) * 64 + 4 * t));
        s16x4 wB = __builtin_nontemporal_load((const s16x4*)(w + (size_t)(p + 4 + g) * 64 + 4 * t));
#pragma unroll
        for (int j = 0; j < 4; ++j) {
            accA[j] = fmaf(hA[j], bf2f((u16)wA[j]), accA[j]);
            accB[j] = fmaf(hB[j], bf2f((u16)wB[j]), accB[j]);
        }
    }
    if (p + 4 <= p1) {
        int sA = srcs[p + g];
        f32x4 hA = *(const f32x4*)(hxb + (size_t)sA * 256);
        s16x4 wA = __builtin_nontemporal_load((const s16x4*)(w + (size_t)(p + g) * 64 + 4 * t));
#pragma unroll
        for (int j = 0; j < 4; ++j)
            accA[j] = fmaf(hA[j], bf2f((u16)wA[j]), accA[j]);
        p += 4;
    }
    int rem = p1 - p;
    if (g < rem) {
        int sB = srcs[p + g];
        f32x4 hB = *(const f32x4*)(hxb + (size_t)sB * 256);
        s16x4 wB = __builtin_nontemporal_load((const s16x4*)(w + (size_t)(p + g) * 64 + 4 * t));
#pragma unroll
        for (int j = 0; j < 4; ++j)
            accB[j] = fmaf(hB[j], bf2f((u16)wB[j]), accB[j]);
    }
#pragma unroll
    for (int j = 0; j < 4; ++j) accA[j] += accB[j];
    // reduce the 4 groups (lane xor 16, 32)
#pragma unroll
    for (int j = 0; j < 4; ++j) {
        accA[j] += __shfl_xor(accA[j], 16, 64);
        accA[j] += __shfl_xor(accA[j], 32, 64);
    }
    if (g == 0) {
        float inv = invdeg[n];
        f32x4 o = {accA[0] * inv, accA[1] * inv, accA[2] * inv, accA[3] * inv};
        *(f32x4*)(agg + (size_t)n * 64 + 4 * t) = o;
    }
}

// ======== fused GRU: gate GEMM + gi/gh MFMA + inorm + gates, all in-kernel ========
__global__ __launch_bounds__(256) void k_gru_fused(
    float* __restrict__ outp, const float* __restrict__ agg,
    const u16* __restrict__ wb,
    const float* __restrict__ big, const float* __restrict__ bih,
    const float* __restrict__ bhh, int it)
{
    __shared__ u16 hbuf[4][16 * 68];
    int tid = threadIdx.x;
    int wave = tid >> 6, lane = tid & 63;
    int q = lane >> 4, t = lane & 15;
    int nbase = blockIdx.x * 64 + wave * 16;
    u16* hb = hbuf[wave];
    const u16* wigb = wb;
    const u16* whhb = wb + 4096;
    const u16* wihb = wb + 16384;

    // ---- stage hx -> hb (bf16), float4 reads, packed b64 writes ----
    {
        int c = lane & 15;
        int mrow = lane >> 4;
#pragma unroll
        for (int rep = 0; rep < 4; ++rep) {
            int m = rep * 4 + mrow;
            int node = nbase + m;
            float4 v = make_float4(0.f, 0.f, 0.f, 0.f);
            if (node < NN)
                v = *(const float4*)(outp + (size_t)node * 256 + (size_t)it * 64 + c * 4);
            u32x2 pk = {cvtpk(v.x, v.y), cvtpk(v.z, v.w)};
            *(u32x2*)(&hb[m * 68 + c * 4]) = pk;
        }
    }
    // (wave-private buffer; in-order DS pipe makes a barrier unnecessary)

    // ---- hx A-frags + hx rows 4t..4t+3 (C-layout) ----
    s16x8 ahx[2];
    ahx[0] = lds_frag(&hb[t * 68 + q * 8]);
    ahx[1] = lds_frag(&hb[t * 68 + 32 + q * 8]);
    u32 hxpk[4][2];
#pragma unroll
    for (int r = 0; r < 4; ++r)
        *(u32x2*)hxpk[r] = *(const u32x2*)(&hb[(q * 4 + r) * 68 + 4 * t]);

    // ---- gate GEMM: sigmoid(hx @ Wig^T + big) * agg -> inp (to hb) ----
    f32x4 bgv = *(const f32x4*)(big + 4 * t);
    f32x4 gacc[4];
#pragma unroll
    for (int ni = 0; ni < 4; ++ni) {
        s16x8 b0 = gfrag(wigb, ni * 16 + t, 0, q);
        s16x8 b1 = gfrag(wigb, ni * 16 + t, 1, q);
        f32x4 acc = {bgv[ni], bgv[ni], bgv[ni], bgv[ni]};
        acc = __builtin_amdgcn_mfma_f32_16x16x32_bf16(ahx[0], b0, acc, 0, 0, 0);
        acc = __builtin_amdgcn_mfma_f32_16x16x32_bf16(ahx[1], b1, acc, 0, 0, 0);
        gacc[ni] = acc;
    }
#pragma unroll
    for (int r = 0; r < 4; ++r) {
        int node = nbase + q * 4 + r;
        f32x4 av = {0.f, 0.f, 0.f, 0.f};
        if (node < NN) av = *(const f32x4*)(agg + (size_t)node * 64 + 4 * t);
        float i0 = sigmoidf_(gacc[0][r]) * av[0];
        float i1 = sigmoidf_(gacc[1][r]) * av[1];
        float i2 = sigmoidf_(gacc[2][r]) * av[2];
        float i3 = sigmoidf_(gacc[3][r]) * av[3];
        u32x2 pk = {cvtpk(i0, i1), cvtpk(i2, i3)};
        *(u32x2*)(&hb[(q * 4 + r) * 68 + 4 * t]) = pk;
    }

    // ---- gh = hx @ Whh^T  (12 tiles, packed bf16 in regs + stats) ----
    float sgh[4] = {0.f, 0.f, 0.f, 0.f}, qgh[4] = {0.f, 0.f, 0.f, 0.f};
    u32 ghp[12][2];
#pragma unroll
    for (int ni = 0; ni < 12; ++ni) {
        s16x8 b0 = gfrag(whhb, ni * 16 + t, 0, q);
        s16x8 b1 = gfrag(whhb, ni * 16 + t, 1, q);
        f32x4 acc = {0.f, 0.f, 0.f, 0.f};
        acc = __builtin_amdgcn_mfma_f32_16x16x32_bf16(ahx[0], b0, acc, 0, 0, 0);
        acc = __builtin_amdgcn_mfma_f32_16x16x32_bf16(ahx[1], b1, acc, 0, 0, 0);
#pragma unroll
        for (int r = 0; r < 4; ++r) { sgh[r] += acc[r]; qgh[r] += acc[r] * acc[r]; }
        ghp[ni][0] = cvtpk(acc[0], acc[1]);
        ghp[ni][1] = cvtpk(acc[2], acc[3]);
    }

    // ---- inp A-frags (after LDS write above; same-wave ordering) ----
    s16x8 ain[2];
    ain[0] = lds_frag(&hb[t * 68 + q * 8]);
    ain[1] = lds_frag(&hb[t * 68 + 32 + q * 8]);

    // ---- gi = inp @ Wih^T ----
    float sgi[4] = {0.f, 0.f, 0.f, 0.f}, qgi[4] = {0.f, 0.f, 0.f, 0.f};
    u32 gip[12][2];
#pragma unroll
    for (int ni = 0; ni < 12; ++ni) {
        s16x8 b0 = gfrag(wihb, ni * 16 + t, 0, q);
        s16x8 b1 = gfrag(wihb, ni * 16 + t, 1, q);
        f32x4 acc = {0.f, 0.f, 0.f, 0.f};
        acc = __builtin_amdgcn_mfma_f32_16x16x32_bf16(ain[0], b0, acc, 0, 0, 0);
        acc = __builtin_amdgcn_mfma_f32_16x16x32_bf16(ain[1], b1, acc, 0, 0, 0);
#pragma unroll
        for (int r = 0; r < 4; ++r) { sgi[r] += acc[r]; qgi[r] += acc[r] * acc[r]; }
        gip[ni][0] = cvtpk(acc[0], acc[1]);
        gip[ni][1] = cvtpk(acc[2], acc[3]);
    }

    // ---- reduce stats over t-group ----
#pragma unroll
    for (int m = 1; m < 16; m <<= 1) {
#pragma unroll
        for (int r = 0; r < 4; ++r) {
            sgh[r] += __shfl_xor(sgh[r], m, 64);
            qgh[r] += __shfl_xor(qgh[r], m, 64);
            sgi[r] += __shfl_xor(sgi[r], m, 64);
            qgi[r] += __shfl_xor(qgi[r], m, 64);
        }
    }
    float mi_[4], ri_[4], mh_[4], rh_[4];
#pragma unroll
    for (int r = 0; r < 4; ++r) {
        mi_[r] = sgi[r] * (1.f / 192.f);
        mh_[r] = sgh[r] * (1.f / 192.f);
        ri_[r] = rsqrtf(qgi[r] * (1.f / 192.f) - mi_[r] * mi_[r] + EPSI);
        rh_[r] = rsqrtf(qgh[r] * (1.f / 192.f) - mh_[r] * mh_[r] + EPSI);
    }

    // ---- gates + hx update + float4 stores ----
    f32x4 bihr = *(const f32x4*)(bih + 4 * t);
    f32x4 bihi = *(const f32x4*)(bih + 64 + 4 * t);
    f32x4 bihn = *(const f32x4*)(bih + 128 + 4 * t);
    f32x4 bhhr = *(const f32x4*)(bhh + 4 * t);
    f32x4 bhhi = *(const f32x4*)(bhh + 64 + 4 * t);
    f32x4 bhhn = *(const f32x4*)(bhh + 128 + 4 * t);
#pragma unroll
    for (int r = 0; r < 4; ++r) {
        int node = nbase + q * 4 + r;
        f32x4 res;
#pragma unroll
        for (int ni = 0; ni < 4; ++ni) {
            float iv_r = (unpk(gip[ni], r) - mi_[r]) * ri_[r];
            float iv_i = (unpk(gip[ni + 4], r) - mi_[r]) * ri_[r];
            float iv_n = (unpk(gip[ni + 8], r) - mi_[r]) * ri_[r];
            float hv_r = (unpk(ghp[ni], r) - mh_[r]) * rh_[r];
            float hv_i = (unpk(ghp[ni + 4], r) - mh_[r]) * rh_[r];
            float hv_n = (unpk(ghp[ni + 8], r) - mh_[r]) * rh_[r];
            float rg = sigmoidf_(iv_r + bihr[ni] + hv_r + bhhr[ni]);
            float zg = sigmoidf_(iv_i + bihi[ni] + hv_i + bhhi[ni]);
            float ng = tanhf_(iv_n + bihn[ni] + rg * (hv_n + bhhn[ni]));
            float ho = bf2f((u16)((ni & 1) ? (hxpk[r][ni >> 1] >> 16)
                                           : (hxpk[r][ni >> 1] & 0xffffu)));
            res[ni] = ng + zg * (ho - ng);
        }
        if (node < NN)
            *(f32x4*)(outp + (size_t)node * 256 + (size_t)(it + 1) * 64 + 4 * t) = res;
    }
}

extern "C" void kernel_launch(void* const* d_in, const int* in_sizes, int n_in,
                              void* d_out, int out_size, void* d_ws, size_t ws_size,
                              hipStream_t stream)
{
    const float* hx  = (const float*)d_in[0];
    const int*   eix = (const int*)d_in[1];
    const float* ef  = (const float*)d_in[2];
    const float* fW1 = (const float*)d_in[3];
    const float* fb1 = (const float*)d_in[4];
    const float* fW2 = (const float*)d_in[5];
    const float* fb2 = (const float*)d_in[6];
    const float* fW3 = (const float*)d_in[7];
    const float* fb3 = (const float*)d_in[8];
    const float* Wih = (const float*)d_in[9];
    const float* Whh = (const float*)d_in[10];
    const float* bih = (const float*)d_in[11];
    const float* bhh = (const float*)d_in[12];
    const float* Wig = (const float*)d_in[13];
    const float* big = (const float*)d_in[14];
    float* outp = (float*)d_out;
    char* ws = (char*)d_ws;

    u16*    w      = (u16*)(ws + WS_W);
    float*  agg    = (float*)(ws + WS_AGG);
    int*    cnt8   = (int*)(ws + WS_AGG);     // aliased: prep-phase only
    u16*    wb     = (u16*)(ws + WS_WB);
    float*  invdeg = (float*)(ws + WS_INVDEG);
    int*    counts = (int*)(ws + WS_COUNTS);
    int*    rowst  = (int*)(ws + WS_ROWSTART);
    int*    bsum   = (int*)(ws + WS_BSUM);
    int*    bsumex = (int*)(ws + WS_BSUMEX);
    int*    srcs   = (int*)(ws + WS_SRC);
    int*    eperm  = (int*)(ws + WS_EPERM);

    hipMemsetAsync(cnt8, 0, 8 * NN * sizeof(int), stream);
    k_prep_w<<<(WB_TOTAL + 255) / 256, 256, 0, stream>>>(Wig, Whh, Wih, fW1, fW2, fW3, wb);
    k_rank<<<(NE + 255) / 256, 256, 0, stream>>>(eix, cnt8, eperm);
    k_sumcnt<<<391, 256, 0, stream>>>(cnt8, counts);
    k_scan_partial<<<391, 256, 0, stream>>>(counts, bsum);
    k_scan_bsum<<<1, 512, 0, stream>>>(bsum, bsumex);
    k_scan_final<<<391, 256, 0, stream>>>(counts, bsumex, rowst, invdeg);
    k_finalize<<<(NE + 255) / 256, 256, 0, stream>>>(eix, cnt8, rowst, eperm, srcs);
    k_fnet_mfma<<<9766, 256, 0, stream>>>(ef, fb1, fb2, fb3, eperm, wb, w);
    k_init<<<6250, 256, 0, stream>>>((const float4*)hx, outp);

    for (int it = 0; it < 3; ++it) {
        k_agg<<<25000, 256, 0, stream>>>(outp, w, srcs, rowst, invdeg, agg, it);
        k_gru_fused<<<1563, 256, 0, stream>>>(outp, agg, wb, big, bih, bhh, it);
    }
}

// Round 12
// 706.201 us; speedup vs baseline: 1.2814x; 1.0657x over previous
//
#include <hip/hip_runtime.h>
#include <math.h>

#define NN 100000
#define NE 1250000
#define EPSI 1e-5f

// ---- workspace layout (bytes) ----
#define WS_W        0ull          // bf16 [NE*64]            160,000,000  (CSR-ordered)
#define WS_AGG      160000000ull  // f32  [NN*64]             25,600,000  (aliased: cnt8[8][NN] during prep)
#define WS_WB       185600000ull  // bf16 weights (see k_prep_w)
#define WS_INVDEG   264000000ull  // f32 [NN]
#define WS_COUNTS   264400000ull  // i32 [NN]
#define WS_ROWSTART 264800000ull  // i32 [NN+1]
#define WS_CURSOR   265200128ull  // i32 [NN] (unused, kept for layout stability)
#define WS_BSUM     265600128ull  // i32 [391]
#define WS_BSUMEX   265601792ull  // i32 [391]
#define WS_SRC      265603584ull  // i32 [NE]  src node per CSR slot       5,000,000
#define WS_EPERM    270603584ull  // i32 [NE]  rank during prep, then CSR slot

// wb (bf16) sub-layout, all row-permuted by p(n)=4*(n&15)+(n>>4) within
// each 64-row block:
//   [0)      Wig   64x64
//   [4096)   Whh  192x64   (perm within each gate's 64 rows)
//   [16384)  Wih  192x64   (perm within each gate's 64 rows)
//   [28672)  W1    64x16   (13 cols + 3 zero pad)
//   [29696)  W2    64x64
//   [33792)  W3    64x64   -> total 37888 elements
#define WB_TOTAL 37888

typedef unsigned short u16;
typedef unsigned int u32;
typedef short s16x4 __attribute__((ext_vector_type(4)));
typedef short s16x8 __attribute__((ext_vector_type(8)));
typedef float f32x4 __attribute__((ext_vector_type(4)));
typedef u32 u32x4 __attribute__((ext_vector_type(4)));
typedef u32 u32x2 __attribute__((ext_vector_type(2)));
typedef float f32x4u __attribute__((ext_vector_type(4), aligned(4)));

__device__ __forceinline__ u16 f2bf(float f) {
    u32 u = __float_as_uint(f);
    return (u16)((u + 0x7fffu + ((u >> 16) & 1u)) >> 16);   // RNE
}
__device__ __forceinline__ float bf2f(u16 b) {
    return __uint_as_float(((u32)b) << 16);
}
// packed f32x2 -> bf16x2 (RNE), 1 VALU op
__device__ __forceinline__ u32 cvtpk(float lo, float hi) {
    u32 r;
    asm("v_cvt_pk_bf16_f32 %0, %1, %2" : "=v"(r) : "v"(lo), "v"(hi));
    return r;
}
__device__ __forceinline__ float sigmoidf_(float x) {
    return 1.f / (1.f + __expf(-x));
}
// tanh via exp, saturating at +-1; ~4 VALU ops vs libm tanhf's ~20
__device__ __forceinline__ float tanhf_(float x) {
    float e = __expf(2.f * x);
    return 1.f - 2.f / (e + 1.f);
}
__device__ __forceinline__ s16x8 lds_frag(const u16* p) {
    s16x4 lo = *(const s16x4*)p;
    s16x4 hi = *(const s16x4*)(p + 4);
    return __builtin_shufflevector(lo, hi, 0, 1, 2, 3, 4, 5, 6, 7);
}
__device__ __forceinline__ s16x8 gfrag(const u16* W, int n, int ks, int q) {
    // W row-major [64 cols], 16-byte aligned chunks
    return *(const s16x8*)(W + n * 64 + ks * 32 + q * 8);
}
__device__ __forceinline__ float unpk(const u32* p, int r) {
    u32 v = p[r >> 1];
    return bf2f((u16)((r & 1) ? (v >> 16) : (v & 0xffffu)));
}

// ============ fnet via MFMA: per-edge MLP 13->64->64->64, bf16 out ============
// R10-proven structure: LDS weights (vectorized staging), hbuf transitions
// with cvtpk+b64 (row perm p(n) -> lane cols 4t..4t+3 contiguous), layer-3
// registers->global CSR-scattered stores.
__global__ __launch_bounds__(256) void k_fnet_mfma(
    const float* __restrict__ ef,
    const float* __restrict__ b1, const float* __restrict__ b2,
    const float* __restrict__ b3,
    const int* __restrict__ eperm,
    const u16* __restrict__ wbf,
    u16* __restrict__ wout)
{
    __shared__ u16 w1l[64 * 16];
    __shared__ u16 w2l[64 * 68];
    __shared__ u16 w3l[64 * 68];
    __shared__ u16 hbuf[4][32 * 68];

    int tid = threadIdx.x;
    const u16* wf1 = wbf + 28672;
    const u16* wf2 = wbf + 29696;
    const u16* wf3 = wbf + 33792;
    // w1l: 1024 u16 = 128 x 16B chunks, rows contiguous (16B aligned both sides)
    if (tid < 128)
        *(u32x4*)(&w1l[tid * 8]) = *(const u32x4*)(wf1 + tid * 8);
    // w2l/w3l: 512 x 16B chunks each; row stride 136B in LDS -> split to 2x b64
    for (int c = tid; c < 512; c += 256) {
        int n = c >> 3, cc = c & 7;
        u32x4 v2 = *(const u32x4*)(wf2 + c * 8);
        u32x4 v3 = *(const u32x4*)(wf3 + c * 8);
        u16* p2 = &w2l[n * 68 + cc * 8];
        u16* p3 = &w3l[n * 68 + cc * 8];
        *(u32x2*)p2       = __builtin_shufflevector(v2, v2, 0, 1);
        *(u32x2*)(p2 + 4) = __builtin_shufflevector(v2, v2, 2, 3);
        *(u32x2*)p3       = __builtin_shufflevector(v3, v3, 0, 1);
        *(u32x2*)(p3 + 4) = __builtin_shufflevector(v3, v3, 2, 3);
    }
    __syncthreads();

    int wave = tid >> 6, lane = tid & 63;
    int q = lane >> 4, t = lane & 15;
    int ebase = blockIdx.x * 128 + wave * 32;
    u16* hb = hbuf[wave];

    // biases in permuted slot order: slot (ni,t) holds true feat 4t+ni
    f32x4 b1v = *(const f32x4*)(b1 + 4 * t);
    f32x4 b2v = *(const f32x4*)(b2 + 4 * t);
    f32x4 b3v = *(const f32x4*)(b3 + 4 * t);

    const s16x8 zfrag = {0, 0, 0, 0, 0, 0, 0, 0};

    // ---- ef fragments: vector loads + packed converts ----
    s16x8 a1[2];
#pragma unroll
    for (int mi = 0; mi < 2; ++mi) {
        int e = ebase + mi * 16 + t;
        u32 xp[4] = {0u, 0u, 0u, 0u};
        if (e < NE) {
            const float* ep = ef + (size_t)e * 13;
            if (q == 0) {
                f32x4u v0 = *(const f32x4u*)(ep);
                f32x4u v1 = *(const f32x4u*)(ep + 4);
                xp[0] = cvtpk(v0[0], v0[1]); xp[1] = cvtpk(v0[2], v0[3]);
                xp[2] = cvtpk(v1[0], v1[1]); xp[3] = cvtpk(v1[2], v1[3]);
            } else if (q == 1) {
                f32x4u v0 = *(const f32x4u*)(ep + 8);
                float v12 = ep[12];
                xp[0] = cvtpk(v0[0], v0[1]); xp[1] = cvtpk(v0[2], v0[3]);
                xp[2] = cvtpk(v12, 0.f);
            }
        }
        a1[mi] = __builtin_bit_cast(s16x8, *(u32x4*)xp);
    }

    // ---- W1 fragments ----
    s16x8 B1f[4];
#pragma unroll
    for (int ni = 0; ni < 4; ++ni) {
        s16x8 b = zfrag;
        if (q < 2) b = lds_frag(&w1l[(ni * 16 + t) * 16 + q * 8]);
        B1f[ni] = b;
    }

    // ---- layer 1 ----
    f32x4 h1[4][2];
#pragma unroll
    for (int ni = 0; ni < 4; ++ni)
#pragma unroll
        for (int mi = 0; mi < 2; ++mi) {
            f32x4 acc = {b1v[ni], b1v[ni], b1v[ni], b1v[ni]};
            acc = __builtin_amdgcn_mfma_f32_16x16x32_bf16(a1[mi], B1f[ni], acc, 0, 0, 0);
            h1[ni][mi] = acc;
        }
    // transition 1: relu + pack + b64 write (cols 4t..4t+3 contiguous)
#pragma unroll
    for (int mi = 0; mi < 2; ++mi)
#pragma unroll
        for (int r = 0; r < 4; ++r) {
            u32 lo = cvtpk(fmaxf(h1[0][mi][r], 0.f), fmaxf(h1[1][mi][r], 0.f));
            u32 hi = cvtpk(fmaxf(h1[2][mi][r], 0.f), fmaxf(h1[3][mi][r], 0.f));
            u32x2 v = {lo, hi};
            *(u32x2*)(&hb[(mi * 16 + q * 4 + r) * 68 + 4 * t]) = v;
        }

    // ---- layer 2 ----
    s16x8 a2[2][2];
#pragma unroll
    for (int mi = 0; mi < 2; ++mi)
#pragma unroll
        for (int ks = 0; ks < 2; ++ks)
            a2[mi][ks] = lds_frag(&hb[(mi * 16 + t) * 68 + ks * 32 + q * 8]);
    f32x4 h2[4][2];
#pragma unroll
    for (int ni = 0; ni < 4; ++ni) {
        s16x8 w0 = lds_frag(&w2l[(ni * 16 + t) * 68 + q * 8]);
        s16x8 w1_ = lds_frag(&w2l[(ni * 16 + t) * 68 + 32 + q * 8]);
#pragma unroll
        for (int mi = 0; mi < 2; ++mi) {
            f32x4 acc = {b2v[ni], b2v[ni], b2v[ni], b2v[ni]};
            acc = __builtin_amdgcn_mfma_f32_16x16x32_bf16(a2[mi][0], w0, acc, 0, 0, 0);
            acc = __builtin_amdgcn_mfma_f32_16x16x32_bf16(a2[mi][1], w1_, acc, 0, 0, 0);
            h2[ni][mi] = acc;
        }
    }
    // transition 2
#pragma unroll
    for (int mi = 0; mi < 2; ++mi)
#pragma unroll
        for (int r = 0; r < 4; ++r) {
            u32 lo = cvtpk(fmaxf(h2[0][mi][r], 0.f), fmaxf(h2[1][mi][r], 0.f));
            u32 hi = cvtpk(fmaxf(h2[2][mi][r], 0.f), fmaxf(h2[3][mi][r], 0.f));
            u32x2 v = {lo, hi};
            *(u32x2*)(&hb[(mi * 16 + q * 4 + r) * 68 + 4 * t]) = v;
        }

    // ---- layer 3: registers -> global, no LDS epilogue ----
    s16x8 a3[2][2];
#pragma unroll
    for (int mi = 0; mi < 2; ++mi)
#pragma unroll
        for (int ks = 0; ks < 2; ++ks)
            a3[mi][ks] = lds_frag(&hb[(mi * 16 + t) * 68 + ks * 32 + q * 8]);
    f32x4 h3[4][2];
#pragma unroll
    for (int ni = 0; ni < 4; ++ni) {
        s16x8 w0 = lds_frag(&w3l[(ni * 16 + t) * 68 + q * 8]);
        s16x8 w1_ = lds_frag(&w3l[(ni * 16 + t) * 68 + 32 + q * 8]);
#pragma unroll
        for (int mi = 0; mi < 2; ++mi) {
            f32x4 acc = {b3v[ni], b3v[ni], b3v[ni], b3v[ni]};
            acc = __builtin_amdgcn_mfma_f32_16x16x32_bf16(a3[mi][0], w0, acc, 0, 0, 0);
            acc = __builtin_amdgcn_mfma_f32_16x16x32_bf16(a3[mi][1], w1_, acc, 0, 0, 0);
            h3[ni][mi] = acc;
        }
    }
    // CSR positions for this lane's 8 edges (safe-clamped int4 loads)
    int base0 = ebase + q * 4;
    int base1 = ebase + 16 + q * 4;
    int4 pos0 = *(const int4*)(eperm + ((base0 + 3 < NE) ? base0 : 0));
    int4 pos1 = *(const int4*)(eperm + ((base1 + 3 < NE) ? base1 : 0));
#pragma unroll
    for (int mi = 0; mi < 2; ++mi)
#pragma unroll
        for (int r = 0; r < 4; ++r) {
            int e = ebase + mi * 16 + q * 4 + r;
            if (e < NE) {
                int pos = mi ? ((const int*)&pos1)[r] : ((const int*)&pos0)[r];
                u32x2 v = {cvtpk(h3[0][mi][r], h3[1][mi][r]),
                           cvtpk(h3[2][mi][r], h3[3][mi][r])};
                *(u32x2*)(wout + (size_t)pos * 64 + 4 * t) = v;
            }
        }
}

// ------- prep: bf16 weights, row-permuted by p(n) within 64-row blocks -------
__global__ void k_prep_w(const float* __restrict__ Wig, const float* __restrict__ Whh,
                         const float* __restrict__ Wih,
                         const float* __restrict__ W1, const float* __restrict__ W2,
                         const float* __restrict__ W3, u16* __restrict__ wb)
{
    int i = blockIdx.x * 256 + threadIdx.x;   // < WB_TOTAL
    if (i >= WB_TOTAL) return;
    float v;
    if (i < 4096) {
        int n = i >> 6, k = i & 63;
        int pn = ((n & 15) << 2) + (n >> 4);
        v = Wig[pn * 64 + k];
    } else if (i < 16384) {
        int j = i - 4096;
        int n = j >> 6, k = j & 63;
        int g = n >> 6, m = n & 63;
        int pm = ((m & 15) << 2) + (m >> 4);
        v = Whh[(g * 64 + pm) * 64 + k];
    } else if (i < 28672) {
        int j = i - 16384;
        int n = j >> 6, k = j & 63;
        int g = n >> 6, m = n & 63;
        int pm = ((m & 15) << 2) + (m >> 4);
        v = Wih[(g * 64 + pm) * 64 + k];
    } else if (i < 29696) {
        int j = i - 28672;
        int n = j >> 4, k = j & 15;
        int pn = ((n & 15) << 2) + (n >> 4);
        v = (k < 13) ? W1[pn * 13 + k] : 0.f;
    } else if (i < 33792) {
        int j = i - 29696;
        int n = j >> 6, k = j & 63;
        int pn = ((n & 15) << 2) + (n >> 4);
        v = W2[pn * 64 + k];
    } else {
        int j = i - 33792;
        int n = j >> 6, k = j & 63;
        int pn = ((n & 15) << 2) + (n >> 4);
        v = W3[pn * 64 + k];
    }
    wb[i] = f2bf(v);
}

// ------- rank pass: ONE atomic pass, 8-way partitioned counters -------
__global__ void k_rank(const int* __restrict__ idx, int* __restrict__ cnt8,
                       int* __restrict__ rank_out)
{
    int e = blockIdx.x * 256 + threadIdx.x;
    int k = blockIdx.x & 7;
    if (e < NE) {
        int d = idx[e];
        int r = atomicAdd(&cnt8[k * NN + d], 1);
        rank_out[e] = r;                       // coalesced
    }
}

// ------- fold 8 partition counts: totals -> counts, cnt8 -> excl prefix -----
__global__ void k_sumcnt(int* __restrict__ cnt8, int* __restrict__ counts)
{
    int d = blockIdx.x * 256 + threadIdx.x;
    if (d >= NN) return;
    int c[8], run = 0;
#pragma unroll
    for (int k = 0; k < 8; ++k) c[k] = cnt8[k * NN + d];
#pragma unroll
    for (int k = 0; k < 8; ++k) { int t = c[k]; cnt8[k * NN + d] = run; run += t; }
    counts[d] = run;
}

// ---------------- two-level exclusive scan over counts ----------------
__global__ void k_scan_partial(const int* __restrict__ counts, int* __restrict__ bsum)
{
    __shared__ int s[256];
    int i = blockIdx.x * 256 + threadIdx.x;
    int v = (i < NN) ? counts[i] : 0;
    s[threadIdx.x] = v; __syncthreads();
    for (int off = 128; off > 0; off >>= 1) {
        if (threadIdx.x < off) s[threadIdx.x] += s[threadIdx.x + off];
        __syncthreads();
    }
    if (threadIdx.x == 0) bsum[blockIdx.x] = s[0];
}

__global__ void k_scan_bsum(const int* __restrict__ bsum, int* __restrict__ bsumex)
{
    __shared__ int s[512];
    int t = threadIdx.x;
    int v0 = (t < 391) ? bsum[t] : 0;
    s[t] = v0; __syncthreads();
    for (int off = 1; off < 512; off <<= 1) {
        int add = (t >= off) ? s[t - off] : 0;
        __syncthreads();
        s[t] += add;
        __syncthreads();
    }
    if (t < 391) bsumex[t] = s[t] - v0;
}

__global__ void k_scan_final(const int* __restrict__ counts, const int* __restrict__ bsumex,
                             int* __restrict__ rowstart, float* __restrict__ invdeg)
{
    __shared__ int s[256];
    int t = threadIdx.x;
    int i = blockIdx.x * 256 + t;
    int c = (i < NN) ? counts[i] : 0;
    s[t] = c; __syncthreads();
    for (int off = 1; off < 256; off <<= 1) {
        int add = (t >= off) ? s[t - off] : 0;
        __syncthreads();
        s[t] += add;
        __syncthreads();
    }
    int ex = s[t] - c + bsumex[blockIdx.x];
    if (i < NN) {
        rowstart[i] = ex;
        invdeg[i] = 1.f / (float)(c > 1 ? c : 1);
    }
    if (i == 0) rowstart[NN] = NE;
}

// ------- finalize: p = rowstart[d] + partition offset + rank; streaming -----
__global__ void k_finalize(const int* __restrict__ idx, const int* __restrict__ cnt8,
                           const int* __restrict__ rowstart,
                           int* __restrict__ eperm, int* __restrict__ srcs)
{
    int e = blockIdx.x * 256 + threadIdx.x;
    if (e < NE) {
        int d = idx[e];
        int s = idx[NE + e];
        int k = (e >> 8) & 7;                  // == blockIdx&7 of k_rank
        int r = eperm[e];                      // temp rank (coalesced)
        int p = rowstart[d] + cnt8[k * NN + d] + r;
        eperm[e] = p;                          // coalesced
        __builtin_nontemporal_store(s, &srcs[p]);  // random 4B, fire-and-forget
    }
}

// ---------------- copy hx0 into out column 0 ----------------
__global__ void k_init(const float4* __restrict__ hx4, float* __restrict__ outp)
{
    int i = blockIdx.x * 256 + threadIdx.x;
    int n = i >> 4, q = i & 15;
    ((float4*)(outp + (size_t)n * 256))[q] = hx4[i];
}

// ------- aggregation v2: wave per node, 4 edges/iteration -------
__global__ __launch_bounds__(256) void k_agg(
    const float* __restrict__ outp, const u16* __restrict__ w,
    const int* __restrict__ srcs, const int* __restrict__ rowstart,
    const float* __restrict__ invdeg, float* __restrict__ agg, int it)
{
    int lane = threadIdx.x & 63;
    int g = lane >> 4, t = lane & 15;
    int n = blockIdx.x * 4 + (threadIdx.x >> 6);
    n = __builtin_amdgcn_readfirstlane(n);
    int p0 = rowstart[n], p1 = rowstart[n + 1];
    const float* hxb = outp + (size_t)it * 64 + 4 * t;
    f32x4 accA = {0.f, 0.f, 0.f, 0.f};
    f32x4 accB = {0.f, 0.f, 0.f, 0.f};
    int p = p0;
    for (; p + 8 <= p1; p += 8) {
        int sA = srcs[p + g];                 // 16-lane broadcast load
        int sB = srcs[p + 4 + g];
        f32x4 hA = *(const f32x4*)(hxb + (size_t)sA * 256);
        f32x4 hB = *(const f32x4*)(hxb + (size_t)sB * 256);
        s16x4 wA = __builtin_nontemporal_load((const s16x4*)(w + (size_t)(p + g) * 64 + 4 * t));
        s16x4 wB = __builtin_nontemporal_load((const s16x4*)(w + (size_t)(p + 4 + g) * 64 + 4 * t));
#pragma unroll
        for (int j = 0; j < 4; ++j) {
            accA[j] = fmaf(hA[j], bf2f((u16)wA[j]), accA[j]);
            accB[j] = fmaf(hB[j], bf2f((u16)wB[j]), accB[j]);
        }
    }
    if (p + 4 <= p1) {
        int sA = srcs[p + g];
        f32x4 hA = *(const f32x4*)(hxb + (size_t)sA * 256);
        s16x4 wA = __builtin_nontemporal_load((const s16x4*)(w + (size_t)(p + g) * 64 + 4 * t));
#pragma unroll
        for (int j = 0; j < 4; ++j)
            accA[j] = fmaf(hA[j], bf2f((u16)wA[j]), accA[j]);
        p += 4;
    }
    int rem = p1 - p;
    if (g < rem) {
        int sB = srcs[p + g];
        f32x4 hB = *(const f32x4*)(hxb + (size_t)sB * 256);
        s16x4 wB = __builtin_nontemporal_load((const s16x4*)(w + (size_t)(p + g) * 64 + 4 * t));
#pragma unroll
        for (int j = 0; j < 4; ++j)
            accB[j] = fmaf(hB[j], bf2f((u16)wB[j]), accB[j]);
    }
#pragma unroll
    for (int j = 0; j < 4; ++j) accA[j] += accB[j];
    // reduce the 4 groups (lane xor 16, 32)
#pragma unroll
    for (int j = 0; j < 4; ++j) {
        accA[j] += __shfl_xor(accA[j], 16, 64);
        accA[j] += __shfl_xor(accA[j], 32, 64);
    }
    if (g == 0) {
        float inv = invdeg[n];
        f32x4 o = {accA[0] * inv, accA[1] * inv, accA[2] * inv, accA[3] * inv};
        *(f32x4*)(agg + (size_t)n * 64 + 4 * t) = o;
    }
}

// ======== fused GRU: gate GEMM + gi/gh MFMA + inorm + gates, all in-kernel ========
// R12: Whh+Wih (48KB = 48 of the 56 per-wave fragment loads) staged to LDS
// (68-u16 row stride, bank-spread); Wig (8KB) stays global and is now
// L1-resident since the global hot set shrank 57KB->8KB. 60.9KB LDS/block
// (<= 64KB static limit), 256 threads, wave-private hbuf — the proven
// configuration class. One added __syncthreads() for wl visibility.
__global__ __launch_bounds__(256) void k_gru_fused(
    float* __restrict__ outp, const float* __restrict__ agg,
    const u16* __restrict__ wb,
    const float* __restrict__ big, const float* __restrict__ bih,
    const float* __restrict__ bhh, int it)
{
    __shared__ u16 wl[384 * 68];       // Whh rows 0-191, Wih rows 192-383
    __shared__ u16 hbuf[4][16 * 68];
    int tid = threadIdx.x;
    const u16* wigb = wb;

    // ---- stage Whh+Wih (wb[4096..28672)): 3072 x 16B chunks ----
    for (int c = tid; c < 3072; c += 256) {
        int n = c >> 3, cc = c & 7;
        u32x4 v = *(const u32x4*)(wb + 4096 + c * 8);
        u16* pp = &wl[n * 68 + cc * 8];
        *(u32x2*)pp       = __builtin_shufflevector(v, v, 0, 1);
        *(u32x2*)(pp + 4) = __builtin_shufflevector(v, v, 2, 3);
    }

    int wave = tid >> 6, lane = tid & 63;
    int q = lane >> 4, t = lane & 15;
    int nbase = blockIdx.x * 64 + wave * 16;
    u16* hb = hbuf[wave];

    // ---- stage hx -> hb (bf16), float4 reads, packed b64 writes ----
    {
        int c = lane & 15;
        int mrow = lane >> 4;
#pragma unroll
        for (int rep = 0; rep < 4; ++rep) {
            int m = rep * 4 + mrow;
            int node = nbase + m;
            float4 v = make_float4(0.f, 0.f, 0.f, 0.f);
            if (node < NN)
                v = *(const float4*)(outp + (size_t)node * 256 + (size_t)it * 64 + c * 4);
            u32x2 pk = {cvtpk(v.x, v.y), cvtpk(v.z, v.w)};
            *(u32x2*)(&hb[m * 68 + c * 4]) = pk;
        }
    }
    __syncthreads();   // wl visible to all waves (hbuf stays wave-private)

    // ---- hx A-frags + hx rows 4t..4t+3 (C-layout) ----
    s16x8 ahx[2];
    ahx[0] = lds_frag(&hb[t * 68 + q * 8]);
    ahx[1] = lds_frag(&hb[t * 68 + 32 + q * 8]);
    u32 hxpk[4][2];
#pragma unroll
    for (int r = 0; r < 4; ++r)
        *(u32x2*)hxpk[r] = *(const u32x2*)(&hb[(q * 4 + r) * 68 + 4 * t]);

    // ---- gate GEMM: sigmoid(hx @ Wig^T + big) * agg -> inp (to hb) ----
    f32x4 bgv = *(const f32x4*)(big + 4 * t);
    f32x4 gacc[4];
#pragma unroll
    for (int ni = 0; ni < 4; ++ni) {
        s16x8 b0 = gfrag(wigb, ni * 16 + t, 0, q);
        s16x8 b1 = gfrag(wigb, ni * 16 + t, 1, q);
        f32x4 acc = {bgv[ni], bgv[ni], bgv[ni], bgv[ni]};
        acc = __builtin_amdgcn_mfma_f32_16x16x32_bf16(ahx[0], b0, acc, 0, 0, 0);
        acc = __builtin_amdgcn_mfma_f32_16x16x32_bf16(ahx[1], b1, acc, 0, 0, 0);
        gacc[ni] = acc;
    }
#pragma unroll
    for (int r = 0; r < 4; ++r) {
        int node = nbase + q * 4 + r;
        f32x4 av = {0.f, 0.f, 0.f, 0.f};
        if (node < NN) av = *(const f32x4*)(agg + (size_t)node * 64 + 4 * t);
        float i0 = sigmoidf_(gacc[0][r]) * av[0];
        float i1 = sigmoidf_(gacc[1][r]) * av[1];
        float i2 = sigmoidf_(gacc[2][r]) * av[2];
        float i3 = sigmoidf_(gacc[3][r]) * av[3];
        u32x2 pk = {cvtpk(i0, i1), cvtpk(i2, i3)};
        *(u32x2*)(&hb[(q * 4 + r) * 68 + 4 * t]) = pk;
    }

    // ---- gh = hx @ Whh^T  (12 tiles, Whh frags from LDS) ----
    float sgh[4] = {0.f, 0.f, 0.f, 0.f}, qgh[4] = {0.f, 0.f, 0.f, 0.f};
    u32 ghp[12][2];
#pragma unroll
    for (int ni = 0; ni < 12; ++ni) {
        s16x8 b0 = lds_frag(&wl[(ni * 16 + t) * 68 + q * 8]);
        s16x8 b1 = lds_frag(&wl[(ni * 16 + t) * 68 + 32 + q * 8]);
        f32x4 acc = {0.f, 0.f, 0.f, 0.f};
        acc = __builtin_amdgcn_mfma_f32_16x16x32_bf16(ahx[0], b0, acc, 0, 0, 0);
        acc = __builtin_amdgcn_mfma_f32_16x16x32_bf16(ahx[1], b1, acc, 0, 0, 0);
#pragma unroll
        for (int r = 0; r < 4; ++r) { sgh[r] += acc[r]; qgh[r] += acc[r] * acc[r]; }
        ghp[ni][0] = cvtpk(acc[0], acc[1]);
        ghp[ni][1] = cvtpk(acc[2], acc[3]);
    }

    // ---- inp A-frags (after LDS write above; same-wave ordering) ----
    s16x8 ain[2];
    ain[0] = lds_frag(&hb[t * 68 + q * 8]);
    ain[1] = lds_frag(&hb[t * 68 + 32 + q * 8]);

    // ---- gi = inp @ Wih^T  (Wih frags from LDS rows 192..383) ----
    float sgi[4] = {0.f, 0.f, 0.f, 0.f}, qgi[4] = {0.f, 0.f, 0.f, 0.f};
    u32 gip[12][2];
#pragma unroll
    for (int ni = 0; ni < 12; ++ni) {
        s16x8 b0 = lds_frag(&wl[(192 + ni * 16 + t) * 68 + q * 8]);
        s16x8 b1 = lds_frag(&wl[(192 + ni * 16 + t) * 68 + 32 + q * 8]);
        f32x4 acc = {0.f, 0.f, 0.f, 0.f};
        acc = __builtin_amdgcn_mfma_f32_16x16x32_bf16(ain[0], b0, acc, 0, 0, 0);
        acc = __builtin_amdgcn_mfma_f32_16x16x32_bf16(ain[1], b1, acc, 0, 0, 0);
#pragma unroll
        for (int r = 0; r < 4; ++r) { sgi[r] += acc[r]; qgi[r] += acc[r] * acc[r]; }
        gip[ni][0] = cvtpk(acc[0], acc[1]);
        gip[ni][1] = cvtpk(acc[2], acc[3]);
    }

    // ---- reduce stats over t-group ----
#pragma unroll
    for (int m = 1; m < 16; m <<= 1) {
#pragma unroll
        for (int r = 0; r < 4; ++r) {
            sgh[r] += __shfl_xor(sgh[r], m, 64);
            qgh[r] += __shfl_xor(qgh[r], m, 64);
            sgi[r] += __shfl_xor(sgi[r], m, 64);
            qgi[r] += __shfl_xor(qgi[r], m, 64);
        }
    }
    float mi_[4], ri_[4], mh_[4], rh_[4];
#pragma unroll
    for (int r = 0; r < 4; ++r) {
        mi_[r] = sgi[r] * (1.f / 192.f);
        mh_[r] = sgh[r] * (1.f / 192.f);
        ri_[r] = rsqrtf(qgi[r] * (1.f / 192.f) - mi_[r] * mi_[r] + EPSI);
        rh_[r] = rsqrtf(qgh[r] * (1.f / 192.f) - mh_[r] * mh_[r] + EPSI);
    }

    // ---- gates + hx update + float4 stores ----
    f32x4 bihr = *(const f32x4*)(bih + 4 * t);
    f32x4 bihi = *(const f32x4*)(bih + 64 + 4 * t);
    f32x4 bihn = *(const f32x4*)(bih + 128 + 4 * t);
    f32x4 bhhr = *(const f32x4*)(bhh + 4 * t);
    f32x4 bhhi = *(const f32x4*)(bhh + 64 + 4 * t);
    f32x4 bhhn = *(const f32x4*)(bhh + 128 + 4 * t);
#pragma unroll
    for (int r = 0; r < 4; ++r) {
        int node = nbase + q * 4 + r;
        f32x4 res;
#pragma unroll
        for (int ni = 0; ni < 4; ++ni) {
            float iv_r = (unpk(gip[ni], r) - mi_[r]) * ri_[r];
            float iv_i = (unpk(gip[ni + 4], r) - mi_[r]) * ri_[r];
            float iv_n = (unpk(gip[ni + 8], r) - mi_[r]) * ri_[r];
            float hv_r = (unpk(ghp[ni], r) - mh_[r]) * rh_[r];
            float hv_i = (unpk(ghp[ni + 4], r) - mh_[r]) * rh_[r];
            float hv_n = (unpk(ghp[ni + 8], r) - mh_[r]) * rh_[r];
            float rg = sigmoidf_(iv_r + bihr[ni] + hv_r + bhhr[ni]);
            float zg = sigmoidf_(iv_i + bihi[ni] + hv_i + bhhi[ni]);
            float ng = tanhf_(iv_n + bihn[ni] + rg * (hv_n + bhhn[ni]));
            float ho = bf2f((u16)((ni & 1) ? (hxpk[r][ni >> 1] >> 16)
                                           : (hxpk[r][ni >> 1] & 0xffffu)));
            res[ni] = ng + zg * (ho - ng);
        }
        if (node < NN)
            *(f32x4*)(outp + (size_t)node * 256 + (size_t)(it + 1) * 64 + 4 * t) = res;
    }
}

extern "C" void kernel_launch(void* const* d_in, const int* in_sizes, int n_in,
                              void* d_out, int out_size, void* d_ws, size_t ws_size,
                              hipStream_t stream)
{
    const float* hx  = (const float*)d_in[0];
    const int*   eix = (const int*)d_in[1];
    const float* ef  = (const float*)d_in[2];
    const float* fW1 = (const float*)d_in[3];
    const float* fb1 = (const float*)d_in[4];
    const float* fW2 = (const float*)d_in[5];
    const float* fb2 = (const float*)d_in[6];
    const float* fW3 = (const float*)d_in[7];
    const float* fb3 = (const float*)d_in[8];
    const float* Wih = (const float*)d_in[9];
    const float* Whh = (const float*)d_in[10];
    const float* bih = (const float*)d_in[11];
    const float* bhh = (const float*)d_in[12];
    const float* Wig = (const float*)d_in[13];
    const float* big = (const float*)d_in[14];
    float* outp = (float*)d_out;
    char* ws = (char*)d_ws;

    u16*    w      = (u16*)(ws + WS_W);
    float*  agg    = (float*)(ws + WS_AGG);
    int*    cnt8   = (int*)(ws + WS_AGG);     // aliased: prep-phase only
    u16*    wb     = (u16*)(ws + WS_WB);
    float*  invdeg = (float*)(ws + WS_INVDEG);
    int*    counts = (int*)(ws + WS_COUNTS);
    int*    rowst  = (int*)(ws + WS_ROWSTART);
    int*    bsum   = (int*)(ws + WS_BSUM);
    int*    bsumex = (int*)(ws + WS_BSUMEX);
    int*    srcs   = (int*)(ws + WS_SRC);
    int*    eperm  = (int*)(ws + WS_EPERM);

    hipMemsetAsync(cnt8, 0, 8 * NN * sizeof(int), stream);
    k_prep_w<<<(WB_TOTAL + 255) / 256, 256, 0, stream>>>(Wig, Whh, Wih, fW1, fW2, fW3, wb);
    k_rank<<<(NE + 255) / 256, 256, 0, stream>>>(eix, cnt8, eperm);
    k_sumcnt<<<391, 256, 0, stream>>>(cnt8, counts);
    k_scan_partial<<<391, 256, 0, stream>>>(counts, bsum);
    k_scan_bsum<<<1, 512, 0, stream>>>(bsum, bsumex);
    k_scan_final<<<391, 256, 0, stream>>>(counts, bsumex, rowst, invdeg);
    k_finalize<<<(NE + 255) / 256, 256, 0, stream>>>(eix, cnt8, rowst, eperm, srcs);
    k_fnet_mfma<<<9766, 256, 0, stream>>>(ef, fb1, fb2, fb3, eperm, wb, w);
    k_init<<<6250, 256, 0, stream>>>((const float4*)hx, outp);

    for (int it = 0; it < 3; ++it) {
        k_agg<<<25000, 256, 0, stream>>>(outp, w, srcs, rowst, invdeg, agg, it);
        k_gru_fused<<<1563, 256, 0, stream>>>(outp, agg, wb, big, bih, bhh, it);
    }
}

// Round 13
// 678.651 us; speedup vs baseline: 1.3334x; 1.0406x over previous
//
#include <hip/hip_runtime.h>
#include <math.h>

#define NN 100000
#define NE 1250000
#define EPSI 1e-5f

// ---- workspace layout (bytes) ----
#define WS_W        0ull          // bf16 [NE*64]            160,000,000  (CSR-ordered)
#define WS_AGG      160000000ull  // f32  [NN*64]             25,600,000  (aliased: cnt8[8][NN] during prep)
#define WS_WB       185600000ull  // bf16 weights (see k_prep_w)          75,776
#define WS_HXB      186000000ull  // bf16 [NN*64] hx shadow               12,800,000
#define WS_INVDEG   264000000ull  // f32 [NN]
#define WS_COUNTS   264400000ull  // i32 [NN]
#define WS_ROWSTART 264800000ull  // i32 [NN+1]
#define WS_CURSOR   265200128ull  // i32 [NN] (unused, kept for layout stability)
#define WS_BSUM     265600128ull  // i32 [391]
#define WS_BSUMEX   265601792ull  // i32 [391]
#define WS_SRC      265603584ull  // i32 [NE]  src node per CSR slot       5,000,000
#define WS_EPERM    270603584ull  // i32 [NE]  rank during prep, then CSR slot

// wb (bf16) sub-layout, all row-permuted by p(n)=4*(n&15)+(n>>4) within
// each 64-row block:
//   [0)      Wig   64x64
//   [4096)   Whh  192x64   (perm within each gate's 64 rows)
//   [16384)  Wih  192x64   (perm within each gate's 64 rows)
//   [28672)  W1    64x16   (13 cols + 3 zero pad)
//   [29696)  W2    64x64
//   [33792)  W3    64x64   -> total 37888 elements
#define WB_TOTAL 37888

typedef unsigned short u16;
typedef unsigned int u32;
typedef short s16x4 __attribute__((ext_vector_type(4)));
typedef short s16x8 __attribute__((ext_vector_type(8)));
typedef float f32x4 __attribute__((ext_vector_type(4)));
typedef u32 u32x4 __attribute__((ext_vector_type(4)));
typedef u32 u32x2 __attribute__((ext_vector_type(2)));
typedef float f32x4u __attribute__((ext_vector_type(4), aligned(4)));

__device__ __forceinline__ u16 f2bf(float f) {
    u32 u = __float_as_uint(f);
    return (u16)((u + 0x7fffu + ((u >> 16) & 1u)) >> 16);   // RNE
}
__device__ __forceinline__ float bf2f(u16 b) {
    return __uint_as_float(((u32)b) << 16);
}
// packed f32x2 -> bf16x2 (RNE), 1 VALU op
__device__ __forceinline__ u32 cvtpk(float lo, float hi) {
    u32 r;
    asm("v_cvt_pk_bf16_f32 %0, %1, %2" : "=v"(r) : "v"(lo), "v"(hi));
    return r;
}
__device__ __forceinline__ float sigmoidf_(float x) {
    return 1.f / (1.f + __expf(-x));
}
// tanh via exp, saturating at +-1; ~4 VALU ops vs libm tanhf's ~20
__device__ __forceinline__ float tanhf_(float x) {
    float e = __expf(2.f * x);
    return 1.f - 2.f / (e + 1.f);
}
__device__ __forceinline__ s16x8 lds_frag(const u16* p) {
    s16x4 lo = *(const s16x4*)p;
    s16x4 hi = *(const s16x4*)(p + 4);
    return __builtin_shufflevector(lo, hi, 0, 1, 2, 3, 4, 5, 6, 7);
}
__device__ __forceinline__ s16x8 gfrag(const u16* W, int n, int ks, int q) {
    // W row-major [64 cols], 16-byte aligned chunks
    return *(const s16x8*)(W + n * 64 + ks * 32 + q * 8);
}
__device__ __forceinline__ float unpk(const u32* p, int r) {
    u32 v = p[r >> 1];
    return bf2f((u16)((r & 1) ? (v >> 16) : (v & 0xffffu)));
}

// ============ fnet via MFMA: per-edge MLP 13->64->64->64, bf16 out ============
// R12-proven structure (unchanged).
__global__ __launch_bounds__(256) void k_fnet_mfma(
    const float* __restrict__ ef,
    const float* __restrict__ b1, const float* __restrict__ b2,
    const float* __restrict__ b3,
    const int* __restrict__ eperm,
    const u16* __restrict__ wbf,
    u16* __restrict__ wout)
{
    __shared__ u16 w1l[64 * 16];
    __shared__ u16 w2l[64 * 68];
    __shared__ u16 w3l[64 * 68];
    __shared__ u16 hbuf[4][32 * 68];

    int tid = threadIdx.x;
    const u16* wf1 = wbf + 28672;
    const u16* wf2 = wbf + 29696;
    const u16* wf3 = wbf + 33792;
    if (tid < 128)
        *(u32x4*)(&w1l[tid * 8]) = *(const u32x4*)(wf1 + tid * 8);
    for (int c = tid; c < 512; c += 256) {
        int n = c >> 3, cc = c & 7;
        u32x4 v2 = *(const u32x4*)(wf2 + c * 8);
        u32x4 v3 = *(const u32x4*)(wf3 + c * 8);
        u16* p2 = &w2l[n * 68 + cc * 8];
        u16* p3 = &w3l[n * 68 + cc * 8];
        *(u32x2*)p2       = __builtin_shufflevector(v2, v2, 0, 1);
        *(u32x2*)(p2 + 4) = __builtin_shufflevector(v2, v2, 2, 3);
        *(u32x2*)p3       = __builtin_shufflevector(v3, v3, 0, 1);
        *(u32x2*)(p3 + 4) = __builtin_shufflevector(v3, v3, 2, 3);
    }
    __syncthreads();

    int wave = tid >> 6, lane = tid & 63;
    int q = lane >> 4, t = lane & 15;
    int ebase = blockIdx.x * 128 + wave * 32;
    u16* hb = hbuf[wave];

    f32x4 b1v = *(const f32x4*)(b1 + 4 * t);
    f32x4 b2v = *(const f32x4*)(b2 + 4 * t);
    f32x4 b3v = *(const f32x4*)(b3 + 4 * t);

    const s16x8 zfrag = {0, 0, 0, 0, 0, 0, 0, 0};

    // ---- ef fragments: vector loads + packed converts ----
    s16x8 a1[2];
#pragma unroll
    for (int mi = 0; mi < 2; ++mi) {
        int e = ebase + mi * 16 + t;
        u32 xp[4] = {0u, 0u, 0u, 0u};
        if (e < NE) {
            const float* ep = ef + (size_t)e * 13;
            if (q == 0) {
                f32x4u v0 = *(const f32x4u*)(ep);
                f32x4u v1 = *(const f32x4u*)(ep + 4);
                xp[0] = cvtpk(v0[0], v0[1]); xp[1] = cvtpk(v0[2], v0[3]);
                xp[2] = cvtpk(v1[0], v1[1]); xp[3] = cvtpk(v1[2], v1[3]);
            } else if (q == 1) {
                f32x4u v0 = *(const f32x4u*)(ep + 8);
                float v12 = ep[12];
                xp[0] = cvtpk(v0[0], v0[1]); xp[1] = cvtpk(v0[2], v0[3]);
                xp[2] = cvtpk(v12, 0.f);
            }
        }
        a1[mi] = __builtin_bit_cast(s16x8, *(u32x4*)xp);
    }

    // ---- W1 fragments ----
    s16x8 B1f[4];
#pragma unroll
    for (int ni = 0; ni < 4; ++ni) {
        s16x8 b = zfrag;
        if (q < 2) b = lds_frag(&w1l[(ni * 16 + t) * 16 + q * 8]);
        B1f[ni] = b;
    }

    // ---- layer 1 ----
    f32x4 h1[4][2];
#pragma unroll
    for (int ni = 0; ni < 4; ++ni)
#pragma unroll
        for (int mi = 0; mi < 2; ++mi) {
            f32x4 acc = {b1v[ni], b1v[ni], b1v[ni], b1v[ni]};
            acc = __builtin_amdgcn_mfma_f32_16x16x32_bf16(a1[mi], B1f[ni], acc, 0, 0, 0);
            h1[ni][mi] = acc;
        }
#pragma unroll
    for (int mi = 0; mi < 2; ++mi)
#pragma unroll
        for (int r = 0; r < 4; ++r) {
            u32 lo = cvtpk(fmaxf(h1[0][mi][r], 0.f), fmaxf(h1[1][mi][r], 0.f));
            u32 hi = cvtpk(fmaxf(h1[2][mi][r], 0.f), fmaxf(h1[3][mi][r], 0.f));
            u32x2 v = {lo, hi};
            *(u32x2*)(&hb[(mi * 16 + q * 4 + r) * 68 + 4 * t]) = v;
        }

    // ---- layer 2 ----
    s16x8 a2[2][2];
#pragma unroll
    for (int mi = 0; mi < 2; ++mi)
#pragma unroll
        for (int ks = 0; ks < 2; ++ks)
            a2[mi][ks] = lds_frag(&hb[(mi * 16 + t) * 68 + ks * 32 + q * 8]);
    f32x4 h2[4][2];
#pragma unroll
    for (int ni = 0; ni < 4; ++ni) {
        s16x8 w0 = lds_frag(&w2l[(ni * 16 + t) * 68 + q * 8]);
        s16x8 w1_ = lds_frag(&w2l[(ni * 16 + t) * 68 + 32 + q * 8]);
#pragma unroll
        for (int mi = 0; mi < 2; ++mi) {
            f32x4 acc = {b2v[ni], b2v[ni], b2v[ni], b2v[ni]};
            acc = __builtin_amdgcn_mfma_f32_16x16x32_bf16(a2[mi][0], w0, acc, 0, 0, 0);
            acc = __builtin_amdgcn_mfma_f32_16x16x32_bf16(a2[mi][1], w1_, acc, 0, 0, 0);
            h2[ni][mi] = acc;
        }
    }
#pragma unroll
    for (int mi = 0; mi < 2; ++mi)
#pragma unroll
        for (int r = 0; r < 4; ++r) {
            u32 lo = cvtpk(fmaxf(h2[0][mi][r], 0.f), fmaxf(h2[1][mi][r], 0.f));
            u32 hi = cvtpk(fmaxf(h2[2][mi][r], 0.f), fmaxf(h2[3][mi][r], 0.f));
            u32x2 v = {lo, hi};
            *(u32x2*)(&hb[(mi * 16 + q * 4 + r) * 68 + 4 * t]) = v;
        }

    // ---- layer 3: registers -> global, no LDS epilogue ----
    s16x8 a3[2][2];
#pragma unroll
    for (int mi = 0; mi < 2; ++mi)
#pragma unroll
        for (int ks = 0; ks < 2; ++ks)
            a3[mi][ks] = lds_frag(&hb[(mi * 16 + t) * 68 + ks * 32 + q * 8]);
    f32x4 h3[4][2];
#pragma unroll
    for (int ni = 0; ni < 4; ++ni) {
        s16x8 w0 = lds_frag(&w3l[(ni * 16 + t) * 68 + q * 8]);
        s16x8 w1_ = lds_frag(&w3l[(ni * 16 + t) * 68 + 32 + q * 8]);
#pragma unroll
        for (int mi = 0; mi < 2; ++mi) {
            f32x4 acc = {b3v[ni], b3v[ni], b3v[ni], b3v[ni]};
            acc = __builtin_amdgcn_mfma_f32_16x16x32_bf16(a3[mi][0], w0, acc, 0, 0, 0);
            acc = __builtin_amdgcn_mfma_f32_16x16x32_bf16(a3[mi][1], w1_, acc, 0, 0, 0);
            h3[ni][mi] = acc;
        }
    }
    int base0 = ebase + q * 4;
    int base1 = ebase + 16 + q * 4;
    int4 pos0 = *(const int4*)(eperm + ((base0 + 3 < NE) ? base0 : 0));
    int4 pos1 = *(const int4*)(eperm + ((base1 + 3 < NE) ? base1 : 0));
#pragma unroll
    for (int mi = 0; mi < 2; ++mi)
#pragma unroll
        for (int r = 0; r < 4; ++r) {
            int e = ebase + mi * 16 + q * 4 + r;
            if (e < NE) {
                int pos = mi ? ((const int*)&pos1)[r] : ((const int*)&pos0)[r];
                u32x2 v = {cvtpk(h3[0][mi][r], h3[1][mi][r]),
                           cvtpk(h3[2][mi][r], h3[3][mi][r])};
                *(u32x2*)(wout + (size_t)pos * 64 + 4 * t) = v;
            }
        }
}

// ------- prep: bf16 weights, row-permuted by p(n) within 64-row blocks -------
__global__ void k_prep_w(const float* __restrict__ Wig, const float* __restrict__ Whh,
                         const float* __restrict__ Wih,
                         const float* __restrict__ W1, const float* __restrict__ W2,
                         const float* __restrict__ W3, u16* __restrict__ wb)
{
    int i = blockIdx.x * 256 + threadIdx.x;   // < WB_TOTAL
    if (i >= WB_TOTAL) return;
    float v;
    if (i < 4096) {
        int n = i >> 6, k = i & 63;
        int pn = ((n & 15) << 2) + (n >> 4);
        v = Wig[pn * 64 + k];
    } else if (i < 16384) {
        int j = i - 4096;
        int n = j >> 6, k = j & 63;
        int g = n >> 6, m = n & 63;
        int pm = ((m & 15) << 2) + (m >> 4);
        v = Whh[(g * 64 + pm) * 64 + k];
    } else if (i < 28672) {
        int j = i - 16384;
        int n = j >> 6, k = j & 63;
        int g = n >> 6, m = n & 63;
        int pm = ((m & 15) << 2) + (m >> 4);
        v = Wih[(g * 64 + pm) * 64 + k];
    } else if (i < 29696) {
        int j = i - 28672;
        int n = j >> 4, k = j & 15;
        int pn = ((n & 15) << 2) + (n >> 4);
        v = (k < 13) ? W1[pn * 13 + k] : 0.f;
    } else if (i < 33792) {
        int j = i - 29696;
        int n = j >> 6, k = j & 63;
        int pn = ((n & 15) << 2) + (n >> 4);
        v = W2[pn * 64 + k];
    } else {
        int j = i - 33792;
        int n = j >> 6, k = j & 63;
        int pn = ((n & 15) << 2) + (n >> 4);
        v = W3[pn * 64 + k];
    }
    wb[i] = f2bf(v);
}

// ------- rank pass: ONE atomic pass, 8-way partitioned counters -------
__global__ void k_rank(const int* __restrict__ idx, int* __restrict__ cnt8,
                       int* __restrict__ rank_out)
{
    int e = blockIdx.x * 256 + threadIdx.x;
    int k = blockIdx.x & 7;
    if (e < NE) {
        int d = idx[e];
        int r = atomicAdd(&cnt8[k * NN + d], 1);
        rank_out[e] = r;                       // coalesced
    }
}

// ------- fold 8 partition counts: totals -> counts, cnt8 -> excl prefix -----
__global__ void k_sumcnt(int* __restrict__ cnt8, int* __restrict__ counts)
{
    int d = blockIdx.x * 256 + threadIdx.x;
    if (d >= NN) return;
    int c[8], run = 0;
#pragma unroll
    for (int k = 0; k < 8; ++k) c[k] = cnt8[k * NN + d];
#pragma unroll
    for (int k = 0; k < 8; ++k) { int t = c[k]; cnt8[k * NN + d] = run; run += t; }
    counts[d] = run;
}

// ---------------- two-level exclusive scan over counts ----------------
__global__ void k_scan_partial(const int* __restrict__ counts, int* __restrict__ bsum)
{
    __shared__ int s[256];
    int i = blockIdx.x * 256 + threadIdx.x;
    int v = (i < NN) ? counts[i] : 0;
    s[threadIdx.x] = v; __syncthreads();
    for (int off = 128; off > 0; off >>= 1) {
        if (threadIdx.x < off) s[threadIdx.x] += s[threadIdx.x + off];
        __syncthreads();
    }
    if (threadIdx.x == 0) bsum[blockIdx.x] = s[0];
}

__global__ void k_scan_bsum(const int* __restrict__ bsum, int* __restrict__ bsumex)
{
    __shared__ int s[512];
    int t = threadIdx.x;
    int v0 = (t < 391) ? bsum[t] : 0;
    s[t] = v0; __syncthreads();
    for (int off = 1; off < 512; off <<= 1) {
        int add = (t >= off) ? s[t - off] : 0;
        __syncthreads();
        s[t] += add;
        __syncthreads();
    }
    if (t < 391) bsumex[t] = s[t] - v0;
}

__global__ void k_scan_final(const int* __restrict__ counts, const int* __restrict__ bsumex,
                             int* __restrict__ rowstart, float* __restrict__ invdeg)
{
    __shared__ int s[256];
    int t = threadIdx.x;
    int i = blockIdx.x * 256 + t;
    int c = (i < NN) ? counts[i] : 0;
    s[t] = c; __syncthreads();
    for (int off = 1; off < 256; off <<= 1) {
        int add = (t >= off) ? s[t - off] : 0;
        __syncthreads();
        s[t] += add;
        __syncthreads();
    }
    int ex = s[t] - c + bsumex[blockIdx.x];
    if (i < NN) {
        rowstart[i] = ex;
        invdeg[i] = 1.f / (float)(c > 1 ? c : 1);
    }
    if (i == 0) rowstart[NN] = NE;
}

// ------- finalize: p = rowstart[d] + partition offset + rank; streaming -----
__global__ void k_finalize(const int* __restrict__ idx, const int* __restrict__ cnt8,
                           const int* __restrict__ rowstart,
                           int* __restrict__ eperm, int* __restrict__ srcs)
{
    int e = blockIdx.x * 256 + threadIdx.x;
    if (e < NE) {
        int d = idx[e];
        int s = idx[NE + e];
        int k = (e >> 8) & 7;                  // == blockIdx&7 of k_rank
        int r = eperm[e];                      // temp rank (coalesced)
        int p = rowstart[d] + cnt8[k * NN + d] + r;
        eperm[e] = p;                          // coalesced
        __builtin_nontemporal_store(s, &srcs[p]);  // random 4B, fire-and-forget
    }
}

// ------- copy hx0 into out column 0 + bf16 shadow -------
__global__ void k_init(const float4* __restrict__ hx4, float* __restrict__ outp,
                       u16* __restrict__ hxb16)
{
    int i = blockIdx.x * 256 + threadIdx.x;
    int n = i >> 4, q = i & 15;
    float4 v = hx4[i];
    ((float4*)(outp + (size_t)n * 256))[q] = v;
    u32x2 pk = {cvtpk(v.x, v.y), cvtpk(v.z, v.w)};
    *(u32x2*)(hxb16 + (size_t)n * 64 + q * 4) = pk;
}

// ------- aggregation v3: wave per node, 4 edges/iter, bf16 hx gather -------
// hx gathered from the bf16 shadow (8B/lane): 2 scattered 64B lines per edge
// instead of 4 (fp32), and the gather working set halves (12.8MB). The GRU
// already rounds hx to bf16 internally, so msg-path bf16 adds ~0.4% relative.
__global__ __launch_bounds__(256) void k_agg(
    const u16* __restrict__ hxb16, const u16* __restrict__ w,
    const int* __restrict__ srcs, const int* __restrict__ rowstart,
    const float* __restrict__ invdeg, float* __restrict__ agg, int it)
{
    int lane = threadIdx.x & 63;
    int g = lane >> 4, t = lane & 15;
    int n = blockIdx.x * 4 + (threadIdx.x >> 6);
    n = __builtin_amdgcn_readfirstlane(n);
    int p0 = rowstart[n], p1 = rowstart[n + 1];
    const u16* hxb = hxb16 + 4 * t;
    f32x4 accA = {0.f, 0.f, 0.f, 0.f};
    f32x4 accB = {0.f, 0.f, 0.f, 0.f};
    int p = p0;
    for (; p + 8 <= p1; p += 8) {
        int sA = srcs[p + g];                 // 16-lane broadcast load
        int sB = srcs[p + 4 + g];
        s16x4 hA = *(const s16x4*)(hxb + (size_t)sA * 64);
        s16x4 hB = *(const s16x4*)(hxb + (size_t)sB * 64);
        s16x4 wA = __builtin_nontemporal_load((const s16x4*)(w + (size_t)(p + g) * 64 + 4 * t));
        s16x4 wB = __builtin_nontemporal_load((const s16x4*)(w + (size_t)(p + 4 + g) * 64 + 4 * t));
#pragma unroll
        for (int j = 0; j < 4; ++j) {
            accA[j] = fmaf(bf2f((u16)hA[j]), bf2f((u16)wA[j]), accA[j]);
            accB[j] = fmaf(bf2f((u16)hB[j]), bf2f((u16)wB[j]), accB[j]);
        }
    }
    if (p + 4 <= p1) {
        int sA = srcs[p + g];
        s16x4 hA = *(const s16x4*)(hxb + (size_t)sA * 64);
        s16x4 wA = __builtin_nontemporal_load((const s16x4*)(w + (size_t)(p + g) * 64 + 4 * t));
#pragma unroll
        for (int j = 0; j < 4; ++j)
            accA[j] = fmaf(bf2f((u16)hA[j]), bf2f((u16)wA[j]), accA[j]);
        p += 4;
    }
    int rem = p1 - p;
    if (g < rem) {
        int sB = srcs[p + g];
        s16x4 hB = *(const s16x4*)(hxb + (size_t)sB * 64);
        s16x4 wB = __builtin_nontemporal_load((const s16x4*)(w + (size_t)(p + g) * 64 + 4 * t));
#pragma unroll
        for (int j = 0; j < 4; ++j)
            accB[j] = fmaf(bf2f((u16)hB[j]), bf2f((u16)wB[j]), accB[j]);
    }
#pragma unroll
    for (int j = 0; j < 4; ++j) accA[j] += accB[j];
    // reduce the 4 groups (lane xor 16, 32)
#pragma unroll
    for (int j = 0; j < 4; ++j) {
        accA[j] += __shfl_xor(accA[j], 16, 64);
        accA[j] += __shfl_xor(accA[j], 32, 64);
    }
    if (g == 0) {
        float inv = invdeg[n];
        f32x4 o = {accA[0] * inv, accA[1] * inv, accA[2] * inv, accA[3] * inv};
        *(f32x4*)(agg + (size_t)n * 64 + 4 * t) = o;
    }
}

// ======== fused GRU: gate GEMM + gi/gh MFMA + inorm + gates, all in-kernel ========
// R12 structure (Whh+Wih in LDS, Wig global/L1) + bf16 shadow write of hx'.
__global__ __launch_bounds__(256) void k_gru_fused(
    float* __restrict__ outp, const float* __restrict__ agg,
    const u16* __restrict__ wb,
    const float* __restrict__ big, const float* __restrict__ bih,
    const float* __restrict__ bhh, u16* __restrict__ hxb16, int it)
{
    __shared__ u16 wl[384 * 68];       // Whh rows 0-191, Wih rows 192-383
    __shared__ u16 hbuf[4][16 * 68];
    int tid = threadIdx.x;
    const u16* wigb = wb;

    // ---- stage Whh+Wih (wb[4096..28672)): 3072 x 16B chunks ----
    for (int c = tid; c < 3072; c += 256) {
        int n = c >> 3, cc = c & 7;
        u32x4 v = *(const u32x4*)(wb + 4096 + c * 8);
        u16* pp = &wl[n * 68 + cc * 8];
        *(u32x2*)pp       = __builtin_shufflevector(v, v, 0, 1);
        *(u32x2*)(pp + 4) = __builtin_shufflevector(v, v, 2, 3);
    }

    int wave = tid >> 6, lane = tid & 63;
    int q = lane >> 4, t = lane & 15;
    int nbase = blockIdx.x * 64 + wave * 16;
    u16* hb = hbuf[wave];

    // ---- stage hx -> hb (bf16), float4 reads, packed b64 writes ----
    {
        int c = lane & 15;
        int mrow = lane >> 4;
#pragma unroll
        for (int rep = 0; rep < 4; ++rep) {
            int m = rep * 4 + mrow;
            int node = nbase + m;
            float4 v = make_float4(0.f, 0.f, 0.f, 0.f);
            if (node < NN)
                v = *(const float4*)(outp + (size_t)node * 256 + (size_t)it * 64 + c * 4);
            u32x2 pk = {cvtpk(v.x, v.y), cvtpk(v.z, v.w)};
            *(u32x2*)(&hb[m * 68 + c * 4]) = pk;
        }
    }
    __syncthreads();   // wl visible to all waves (hbuf stays wave-private)

    // ---- hx A-frags + hx rows 4t..4t+3 (C-layout) ----
    s16x8 ahx[2];
    ahx[0] = lds_frag(&hb[t * 68 + q * 8]);
    ahx[1] = lds_frag(&hb[t * 68 + 32 + q * 8]);
    u32 hxpk[4][2];
#pragma unroll
    for (int r = 0; r < 4; ++r)
        *(u32x2*)hxpk[r] = *(const u32x2*)(&hb[(q * 4 + r) * 68 + 4 * t]);

    // ---- gate GEMM: sigmoid(hx @ Wig^T + big) * agg -> inp (to hb) ----
    f32x4 bgv = *(const f32x4*)(big + 4 * t);
    f32x4 gacc[4];
#pragma unroll
    for (int ni = 0; ni < 4; ++ni) {
        s16x8 b0 = gfrag(wigb, ni * 16 + t, 0, q);
        s16x8 b1 = gfrag(wigb, ni * 16 + t, 1, q);
        f32x4 acc = {bgv[ni], bgv[ni], bgv[ni], bgv[ni]};
        acc = __builtin_amdgcn_mfma_f32_16x16x32_bf16(ahx[0], b0, acc, 0, 0, 0);
        acc = __builtin_amdgcn_mfma_f32_16x16x32_bf16(ahx[1], b1, acc, 0, 0, 0);
        gacc[ni] = acc;
    }
#pragma unroll
    for (int r = 0; r < 4; ++r) {
        int node = nbase + q * 4 + r;
        f32x4 av = {0.f, 0.f, 0.f, 0.f};
        if (node < NN) av = *(const f32x4*)(agg + (size_t)node * 64 + 4 * t);
        float i0 = sigmoidf_(gacc[0][r]) * av[0];
        float i1 = sigmoidf_(gacc[1][r]) * av[1];
        float i2 = sigmoidf_(gacc[2][r]) * av[2];
        float i3 = sigmoidf_(gacc[3][r]) * av[3];
        u32x2 pk = {cvtpk(i0, i1), cvtpk(i2, i3)};
        *(u32x2*)(&hb[(q * 4 + r) * 68 + 4 * t]) = pk;
    }

    // ---- gh = hx @ Whh^T  (12 tiles, Whh frags from LDS) ----
    float sgh[4] = {0.f, 0.f, 0.f, 0.f}, qgh[4] = {0.f, 0.f, 0.f, 0.f};
    u32 ghp[12][2];
#pragma unroll
    for (int ni = 0; ni < 12; ++ni) {
        s16x8 b0 = lds_frag(&wl[(ni * 16 + t) * 68 + q * 8]);
        s16x8 b1 = lds_frag(&wl[(ni * 16 + t) * 68 + 32 + q * 8]);
        f32x4 acc = {0.f, 0.f, 0.f, 0.f};
        acc = __builtin_amdgcn_mfma_f32_16x16x32_bf16(ahx[0], b0, acc, 0, 0, 0);
        acc = __builtin_amdgcn_mfma_f32_16x16x32_bf16(ahx[1], b1, acc, 0, 0, 0);
#pragma unroll
        for (int r = 0; r < 4; ++r) { sgh[r] += acc[r]; qgh[r] += acc[r] * acc[r]; }
        ghp[ni][0] = cvtpk(acc[0], acc[1]);
        ghp[ni][1] = cvtpk(acc[2], acc[3]);
    }

    // ---- inp A-frags (after LDS write above; same-wave ordering) ----
    s16x8 ain[2];
    ain[0] = lds_frag(&hb[t * 68 + q * 8]);
    ain[1] = lds_frag(&hb[t * 68 + 32 + q * 8]);

    // ---- gi = inp @ Wih^T  (Wih frags from LDS rows 192..383) ----
    float sgi[4] = {0.f, 0.f, 0.f, 0.f}, qgi[4] = {0.f, 0.f, 0.f, 0.f};
    u32 gip[12][2];
#pragma unroll
    for (int ni = 0; ni < 12; ++ni) {
        s16x8 b0 = lds_frag(&wl[(192 + ni * 16 + t) * 68 + q * 8]);
        s16x8 b1 = lds_frag(&wl[(192 + ni * 16 + t) * 68 + 32 + q * 8]);
        f32x4 acc = {0.f, 0.f, 0.f, 0.f};
        acc = __builtin_amdgcn_mfma_f32_16x16x32_bf16(ain[0], b0, acc, 0, 0, 0);
        acc = __builtin_amdgcn_mfma_f32_16x16x32_bf16(ain[1], b1, acc, 0, 0, 0);
#pragma unroll
        for (int r = 0; r < 4; ++r) { sgi[r] += acc[r]; qgi[r] += acc[r] * acc[r]; }
        gip[ni][0] = cvtpk(acc[0], acc[1]);
        gip[ni][1] = cvtpk(acc[2], acc[3]);
    }

    // ---- reduce stats over t-group ----
#pragma unroll
    for (int m = 1; m < 16; m <<= 1) {
#pragma unroll
        for (int r = 0; r < 4; ++r) {
            sgh[r] += __shfl_xor(sgh[r], m, 64);
            qgh[r] += __shfl_xor(qgh[r], m, 64);
            sgi[r] += __shfl_xor(sgi[r], m, 64);
            qgi[r] += __shfl_xor(qgi[r], m, 64);
        }
    }
    float mi_[4], ri_[4], mh_[4], rh_[4];
#pragma unroll
    for (int r = 0; r < 4; ++r) {
        mi_[r] = sgi[r] * (1.f / 192.f);
        mh_[r] = sgh[r] * (1.f / 192.f);
        ri_[r] = rsqrtf(qgi[r] * (1.f / 192.f) - mi_[r] * mi_[r] + EPSI);
        rh_[r] = rsqrtf(qgh[r] * (1.f / 192.f) - mh_[r] * mh_[r] + EPSI);
    }

    // ---- gates + hx update + float4 stores + bf16 shadow ----
    f32x4 bihr = *(const f32x4*)(bih + 4 * t);
    f32x4 bihi = *(const f32x4*)(bih + 64 + 4 * t);
    f32x4 bihn = *(const f32x4*)(bih + 128 + 4 * t);
    f32x4 bhhr = *(const f32x4*)(bhh + 4 * t);
    f32x4 bhhi = *(const f32x4*)(bhh + 64 + 4 * t);
    f32x4 bhhn = *(const f32x4*)(bhh + 128 + 4 * t);
#pragma unroll
    for (int r = 0; r < 4; ++r) {
        int node = nbase + q * 4 + r;
        f32x4 res;
#pragma unroll
        for (int ni = 0; ni < 4; ++ni) {
            float iv_r = (unpk(gip[ni], r) - mi_[r]) * ri_[r];
            float iv_i = (unpk(gip[ni + 4], r) - mi_[r]) * ri_[r];
            float iv_n = (unpk(gip[ni + 8], r) - mi_[r]) * ri_[r];
            float hv_r = (unpk(ghp[ni], r) - mh_[r]) * rh_[r];
            float hv_i = (unpk(ghp[ni + 4], r) - mh_[r]) * rh_[r];
            float hv_n = (unpk(ghp[ni + 8], r) - mh_[r]) * rh_[r];
            float rg = sigmoidf_(iv_r + bihr[ni] + hv_r + bhhr[ni]);
            float zg = sigmoidf_(iv_i + bihi[ni] + hv_i + bhhi[ni]);
            float ng = tanhf_(iv_n + bihn[ni] + rg * (hv_n + bhhn[ni]));
            float ho = bf2f((u16)((ni & 1) ? (hxpk[r][ni >> 1] >> 16)
                                           : (hxpk[r][ni >> 1] & 0xffffu)));
            res[ni] = ng + zg * (ho - ng);
        }
        if (node < NN) {
            *(f32x4*)(outp + (size_t)node * 256 + (size_t)(it + 1) * 64 + 4 * t) = res;
            u32x2 pk = {cvtpk(res[0], res[1]), cvtpk(res[2], res[3])};
            *(u32x2*)(hxb16 + (size_t)node * 64 + 4 * t) = pk;
        }
    }
}

extern "C" void kernel_launch(void* const* d_in, const int* in_sizes, int n_in,
                              void* d_out, int out_size, void* d_ws, size_t ws_size,
                              hipStream_t stream)
{
    const float* hx  = (const float*)d_in[0];
    const int*   eix = (const int*)d_in[1];
    const float* ef  = (const float*)d_in[2];
    const float* fW1 = (const float*)d_in[3];
    const float* fb1 = (const float*)d_in[4];
    const float* fW2 = (const float*)d_in[5];
    const float* fb2 = (const float*)d_in[6];
    const float* fW3 = (const float*)d_in[7];
    const float* fb3 = (const float*)d_in[8];
    const float* Wih = (const float*)d_in[9];
    const float* Whh = (const float*)d_in[10];
    const float* bih = (const float*)d_in[11];
    const float* bhh = (const float*)d_in[12];
    const float* Wig = (const float*)d_in[13];
    const float* big = (const float*)d_in[14];
    float* outp = (float*)d_out;
    char* ws = (char*)d_ws;

    u16*    w      = (u16*)(ws + WS_W);
    float*  agg    = (float*)(ws + WS_AGG);
    int*    cnt8   = (int*)(ws + WS_AGG);     // aliased: prep-phase only
    u16*    wb     = (u16*)(ws + WS_WB);
    u16*    hxb16  = (u16*)(ws + WS_HXB);
    float*  invdeg = (float*)(ws + WS_INVDEG);
    int*    counts = (int*)(ws + WS_COUNTS);
    int*    rowst  = (int*)(ws + WS_ROWSTART);
    int*    bsum   = (int*)(ws + WS_BSUM);
    int*    bsumex = (int*)(ws + WS_BSUMEX);
    int*    srcs   = (int*)(ws + WS_SRC);
    int*    eperm  = (int*)(ws + WS_EPERM);

    hipMemsetAsync(cnt8, 0, 8 * NN * sizeof(int), stream);
    k_prep_w<<<(WB_TOTAL + 255) / 256, 256, 0, stream>>>(Wig, Whh, Wih, fW1, fW2, fW3, wb);
    k_rank<<<(NE + 255) / 256, 256, 0, stream>>>(eix, cnt8, eperm);
    k_sumcnt<<<391, 256, 0, stream>>>(cnt8, counts);
    k_scan_partial<<<391, 256, 0, stream>>>(counts, bsum);
    k_scan_bsum<<<1, 512, 0, stream>>>(bsum, bsumex);
    k_scan_final<<<391, 256, 0, stream>>>(counts, bsumex, rowst, invdeg);
    k_finalize<<<(NE + 255) / 256, 256, 0, stream>>>(eix, cnt8, rowst, eperm, srcs);
    k_fnet_mfma<<<9766, 256, 0, stream>>>(ef, fb1, fb2, fb3, eperm, wb, w);
    k_init<<<6250, 256, 0, stream>>>((const float4*)hx, outp, hxb16);

    for (int it = 0; it < 3; ++it) {
        k_agg<<<25000, 256, 0, stream>>>(hxb16, w, srcs, rowst, invdeg, agg, it);
        k_gru_fused<<<1563, 256, 0, stream>>>(outp, agg, wb, big, bih, bhh, hxb16, it);
    }
}

// Round 14
// 677.659 us; speedup vs baseline: 1.3353x; 1.0015x over previous
//
#include <hip/hip_runtime.h>
#include <math.h>

#define NN 100000
#define NE 1250000
#define EPSI 1e-5f

// ---- workspace layout (bytes) ----
#define WS_W        0ull          // bf16 [NE*64]            160,000,000  (CSR-ordered)
#define WS_AGG      160000000ull  // f32  [NN*64]             25,600,000  (aliased: cnt8[8][NN] during prep)
#define WS_WB       185600000ull  // bf16 weights (see k_prep_w)          75,776
#define WS_HXB      186000000ull  // bf16 [NN*64] hx shadow               12,800,000
#define WS_INVDEG   264000000ull  // f32 [NN]
#define WS_COUNTS   264400000ull  // i32 [NN]
#define WS_ROWSTART 264800000ull  // i32 [NN+1]
#define WS_CURSOR   265200128ull  // i32 [NN] (unused, kept for layout stability)
#define WS_BSUM     265600128ull  // i32 [391]
#define WS_BSUMEX   265601792ull  // i32 [391]
#define WS_SRC      265603584ull  // i32 [NE]  src node per CSR slot       5,000,000
#define WS_EPERM    270603584ull  // i32 [NE]  rank during prep, then CSR slot

// wb (bf16) sub-layout, all row-permuted by p(n)=4*(n&15)+(n>>4) within
// each 64-row block:
//   [0)      Wig   64x64
//   [4096)   Whh  192x64   (perm within each gate's 64 rows)
//   [16384)  Wih  192x64   (perm within each gate's 64 rows)
//   [28672)  W1    64x16   (13 cols + 3 zero pad)
//   [29696)  W2    64x64
//   [33792)  W3    64x64   -> total 37888 elements
#define WB_TOTAL 37888

typedef unsigned short u16;
typedef unsigned int u32;
typedef short s16x4 __attribute__((ext_vector_type(4)));
typedef short s16x8 __attribute__((ext_vector_type(8)));
typedef float f32x4 __attribute__((ext_vector_type(4)));
typedef u32 u32x4 __attribute__((ext_vector_type(4)));
typedef u32 u32x2 __attribute__((ext_vector_type(2)));
typedef float f32x4u __attribute__((ext_vector_type(4), aligned(4)));

__device__ __forceinline__ u16 f2bf(float f) {
    u32 u = __float_as_uint(f);
    return (u16)((u + 0x7fffu + ((u >> 16) & 1u)) >> 16);   // RNE
}
__device__ __forceinline__ float bf2f(u16 b) {
    return __uint_as_float(((u32)b) << 16);
}
// packed f32x2 -> bf16x2 (RNE), 1 VALU op
__device__ __forceinline__ u32 cvtpk(float lo, float hi) {
    u32 r;
    asm("v_cvt_pk_bf16_f32 %0, %1, %2" : "=v"(r) : "v"(lo), "v"(hi));
    return r;
}
__device__ __forceinline__ float sigmoidf_(float x) {
    return 1.f / (1.f + __expf(-x));
}
// tanh via exp, saturating at +-1; ~4 VALU ops vs libm tanhf's ~20
__device__ __forceinline__ float tanhf_(float x) {
    float e = __expf(2.f * x);
    return 1.f - 2.f / (e + 1.f);
}
__device__ __forceinline__ s16x8 lds_frag(const u16* p) {
    s16x4 lo = *(const s16x4*)p;
    s16x4 hi = *(const s16x4*)(p + 4);
    return __builtin_shufflevector(lo, hi, 0, 1, 2, 3, 4, 5, 6, 7);
}
__device__ __forceinline__ s16x8 gfrag(const u16* W, int n, int ks, int q) {
    // W row-major [64 cols], 16-byte aligned chunks
    return *(const s16x8*)(W + n * 64 + ks * 32 + q * 8);
}
__device__ __forceinline__ float unpk(const u32* p, int r) {
    u32 v = p[r >> 1];
    return bf2f((u16)((r & 1) ? (v >> 16) : (v & 0xffffu)));
}

// ============ fnet via MFMA: per-edge MLP 13->64->64->64, bf16 out ============
// R14: mi-split — the two 16-edge tiles run sequentially through all 3
// layers, halving hbuf (32->16 rows/wave). LDS 36.9->28.2 KB -> 5 blocks/CU
// (LDS occupancy cap 50->62.5%). Per-wave DS in-order pipe handles the
// buffer-reuse hazards (same reliance as the 32-row version). Isolated test
// of R11's fnet half (R12 confirmed the gru half was R11's failure cause).
__global__ __launch_bounds__(256) void k_fnet_mfma(
    const float* __restrict__ ef,
    const float* __restrict__ b1, const float* __restrict__ b2,
    const float* __restrict__ b3,
    const int* __restrict__ eperm,
    const u16* __restrict__ wbf,
    u16* __restrict__ wout)
{
    __shared__ u16 w1l[64 * 16];
    __shared__ u16 w2l[64 * 68];
    __shared__ u16 w3l[64 * 68];
    __shared__ u16 hbuf[4][16 * 68];

    int tid = threadIdx.x;
    const u16* wf1 = wbf + 28672;
    const u16* wf2 = wbf + 29696;
    const u16* wf3 = wbf + 33792;
    // w1l: 1024 u16 = 128 x 16B chunks, rows contiguous (16B aligned both sides)
    if (tid < 128)
        *(u32x4*)(&w1l[tid * 8]) = *(const u32x4*)(wf1 + tid * 8);
    // w2l/w3l: 512 x 16B chunks each; row stride 136B in LDS -> split to 2x b64
    for (int c = tid; c < 512; c += 256) {
        int n = c >> 3, cc = c & 7;
        u32x4 v2 = *(const u32x4*)(wf2 + c * 8);
        u32x4 v3 = *(const u32x4*)(wf3 + c * 8);
        u16* p2 = &w2l[n * 68 + cc * 8];
        u16* p3 = &w3l[n * 68 + cc * 8];
        *(u32x2*)p2       = __builtin_shufflevector(v2, v2, 0, 1);
        *(u32x2*)(p2 + 4) = __builtin_shufflevector(v2, v2, 2, 3);
        *(u32x2*)p3       = __builtin_shufflevector(v3, v3, 0, 1);
        *(u32x2*)(p3 + 4) = __builtin_shufflevector(v3, v3, 2, 3);
    }
    __syncthreads();

    int wave = tid >> 6, lane = tid & 63;
    int q = lane >> 4, t = lane & 15;
    int ebase = blockIdx.x * 128 + wave * 32;
    u16* hb = hbuf[wave];

    // biases in permuted slot order: slot (ni,t) holds true feat 4t+ni
    f32x4 b1v = *(const f32x4*)(b1 + 4 * t);
    f32x4 b2v = *(const f32x4*)(b2 + 4 * t);
    f32x4 b3v = *(const f32x4*)(b3 + 4 * t);

    const s16x8 zfrag = {0, 0, 0, 0, 0, 0, 0, 0};

    // ---- ef fragments for both tiles upfront (early global issue) ----
    s16x8 a1[2];
#pragma unroll
    for (int mi = 0; mi < 2; ++mi) {
        int e = ebase + mi * 16 + t;
        u32 xp[4] = {0u, 0u, 0u, 0u};
        if (e < NE) {
            const float* ep = ef + (size_t)e * 13;
            if (q == 0) {
                f32x4u v0 = *(const f32x4u*)(ep);
                f32x4u v1 = *(const f32x4u*)(ep + 4);
                xp[0] = cvtpk(v0[0], v0[1]); xp[1] = cvtpk(v0[2], v0[3]);
                xp[2] = cvtpk(v1[0], v1[1]); xp[3] = cvtpk(v1[2], v1[3]);
            } else if (q == 1) {
                f32x4u v0 = *(const f32x4u*)(ep + 8);
                float v12 = ep[12];
                xp[0] = cvtpk(v0[0], v0[1]); xp[1] = cvtpk(v0[2], v0[3]);
                xp[2] = cvtpk(v12, 0.f);
            }
        }
        a1[mi] = __builtin_bit_cast(s16x8, *(u32x4*)xp);
    }

    // ---- W1 fragments ----
    s16x8 B1f[4];
#pragma unroll
    for (int ni = 0; ni < 4; ++ni) {
        s16x8 b = zfrag;
        if (q < 2) b = lds_frag(&w1l[(ni * 16 + t) * 16 + q * 8]);
        B1f[ni] = b;
    }

    // ---- two sequential 16-edge passes through layers 1-3 ----
#pragma unroll
    for (int mi = 0; mi < 2; ++mi) {
        // layer 1
        f32x4 h1[4];
#pragma unroll
        for (int ni = 0; ni < 4; ++ni) {
            f32x4 acc = {b1v[ni], b1v[ni], b1v[ni], b1v[ni]};
            h1[ni] = __builtin_amdgcn_mfma_f32_16x16x32_bf16(a1[mi], B1f[ni], acc, 0, 0, 0);
        }
        // transition 1: relu + pack + b64 write (cols 4t..4t+3 contiguous)
#pragma unroll
        for (int r = 0; r < 4; ++r) {
            u32 lo = cvtpk(fmaxf(h1[0][r], 0.f), fmaxf(h1[1][r], 0.f));
            u32 hi = cvtpk(fmaxf(h1[2][r], 0.f), fmaxf(h1[3][r], 0.f));
            u32x2 v = {lo, hi};
            *(u32x2*)(&hb[(q * 4 + r) * 68 + 4 * t]) = v;
        }
        // layer 2
        s16x8 a2[2];
#pragma unroll
        for (int ks = 0; ks < 2; ++ks)
            a2[ks] = lds_frag(&hb[t * 68 + ks * 32 + q * 8]);
        f32x4 h2[4];
#pragma unroll
        for (int ni = 0; ni < 4; ++ni) {
            s16x8 w0 = lds_frag(&w2l[(ni * 16 + t) * 68 + q * 8]);
            s16x8 w1_ = lds_frag(&w2l[(ni * 16 + t) * 68 + 32 + q * 8]);
            f32x4 acc = {b2v[ni], b2v[ni], b2v[ni], b2v[ni]};
            acc = __builtin_amdgcn_mfma_f32_16x16x32_bf16(a2[0], w0, acc, 0, 0, 0);
            acc = __builtin_amdgcn_mfma_f32_16x16x32_bf16(a2[1], w1_, acc, 0, 0, 0);
            h2[ni] = acc;
        }
        // transition 2
#pragma unroll
        for (int r = 0; r < 4; ++r) {
            u32 lo = cvtpk(fmaxf(h2[0][r], 0.f), fmaxf(h2[1][r], 0.f));
            u32 hi = cvtpk(fmaxf(h2[2][r], 0.f), fmaxf(h2[3][r], 0.f));
            u32x2 v = {lo, hi};
            *(u32x2*)(&hb[(q * 4 + r) * 68 + 4 * t]) = v;
        }
        // layer 3 + direct CSR-scattered store
        s16x8 a3[2];
#pragma unroll
        for (int ks = 0; ks < 2; ++ks)
            a3[ks] = lds_frag(&hb[t * 68 + ks * 32 + q * 8]);
        f32x4 h3[4];
#pragma unroll
        for (int ni = 0; ni < 4; ++ni) {
            s16x8 w0 = lds_frag(&w3l[(ni * 16 + t) * 68 + q * 8]);
            s16x8 w1_ = lds_frag(&w3l[(ni * 16 + t) * 68 + 32 + q * 8]);
            f32x4 acc = {b3v[ni], b3v[ni], b3v[ni], b3v[ni]};
            acc = __builtin_amdgcn_mfma_f32_16x16x32_bf16(a3[0], w0, acc, 0, 0, 0);
            acc = __builtin_amdgcn_mfma_f32_16x16x32_bf16(a3[1], w1_, acc, 0, 0, 0);
            h3[ni] = acc;
        }
        int baseE = ebase + mi * 16 + q * 4;
        int4 pos = *(const int4*)(eperm + ((baseE + 3 < NE) ? baseE : 0));
#pragma unroll
        for (int r = 0; r < 4; ++r) {
            int e = baseE + r;
            if (e < NE) {
                int p_ = ((const int*)&pos)[r];
                u32x2 v = {cvtpk(h3[0][r], h3[1][r]), cvtpk(h3[2][r], h3[3][r])};
                *(u32x2*)(wout + (size_t)p_ * 64 + 4 * t) = v;
            }
        }
    }
}

// ------- prep: bf16 weights, row-permuted by p(n) within 64-row blocks -------
__global__ void k_prep_w(const float* __restrict__ Wig, const float* __restrict__ Whh,
                         const float* __restrict__ Wih,
                         const float* __restrict__ W1, const float* __restrict__ W2,
                         const float* __restrict__ W3, u16* __restrict__ wb)
{
    int i = blockIdx.x * 256 + threadIdx.x;   // < WB_TOTAL
    if (i >= WB_TOTAL) return;
    float v;
    if (i < 4096) {
        int n = i >> 6, k = i & 63;
        int pn = ((n & 15) << 2) + (n >> 4);
        v = Wig[pn * 64 + k];
    } else if (i < 16384) {
        int j = i - 4096;
        int n = j >> 6, k = j & 63;
        int g = n >> 6, m = n & 63;
        int pm = ((m & 15) << 2) + (m >> 4);
        v = Whh[(g * 64 + pm) * 64 + k];
    } else if (i < 28672) {
        int j = i - 16384;
        int n = j >> 6, k = j & 63;
        int g = n >> 6, m = n & 63;
        int pm = ((m & 15) << 2) + (m >> 4);
        v = Wih[(g * 64 + pm) * 64 + k];
    } else if (i < 29696) {
        int j = i - 28672;
        int n = j >> 4, k = j & 15;
        int pn = ((n & 15) << 2) + (n >> 4);
        v = (k < 13) ? W1[pn * 13 + k] : 0.f;
    } else if (i < 33792) {
        int j = i - 29696;
        int n = j >> 6, k = j & 63;
        int pn = ((n & 15) << 2) + (n >> 4);
        v = W2[pn * 64 + k];
    } else {
        int j = i - 33792;
        int n = j >> 6, k = j & 63;
        int pn = ((n & 15) << 2) + (n >> 4);
        v = W3[pn * 64 + k];
    }
    wb[i] = f2bf(v);
}

// ------- rank pass: ONE atomic pass, 8-way partitioned counters -------
__global__ void k_rank(const int* __restrict__ idx, int* __restrict__ cnt8,
                       int* __restrict__ rank_out)
{
    int e = blockIdx.x * 256 + threadIdx.x;
    int k = blockIdx.x & 7;
    if (e < NE) {
        int d = idx[e];
        int r = atomicAdd(&cnt8[k * NN + d], 1);
        rank_out[e] = r;                       // coalesced
    }
}

// ------- fold 8 partition counts: totals -> counts, cnt8 -> excl prefix -----
__global__ void k_sumcnt(int* __restrict__ cnt8, int* __restrict__ counts)
{
    int d = blockIdx.x * 256 + threadIdx.x;
    if (d >= NN) return;
    int c[8], run = 0;
#pragma unroll
    for (int k = 0; k < 8; ++k) c[k] = cnt8[k * NN + d];
#pragma unroll
    for (int k = 0; k < 8; ++k) { int t = c[k]; cnt8[k * NN + d] = run; run += t; }
    counts[d] = run;
}

// ---------------- two-level exclusive scan over counts ----------------
__global__ void k_scan_partial(const int* __restrict__ counts, int* __restrict__ bsum)
{
    __shared__ int s[256];
    int i = blockIdx.x * 256 + threadIdx.x;
    int v = (i < NN) ? counts[i] : 0;
    s[threadIdx.x] = v; __syncthreads();
    for (int off = 128; off > 0; off >>= 1) {
        if (threadIdx.x < off) s[threadIdx.x] += s[threadIdx.x + off];
        __syncthreads();
    }
    if (threadIdx.x == 0) bsum[blockIdx.x] = s[0];
}

__global__ void k_scan_bsum(const int* __restrict__ bsum, int* __restrict__ bsumex)
{
    __shared__ int s[512];
    int t = threadIdx.x;
    int v0 = (t < 391) ? bsum[t] : 0;
    s[t] = v0; __syncthreads();
    for (int off = 1; off < 512; off <<= 1) {
        int add = (t >= off) ? s[t - off] : 0;
        __syncthreads();
        s[t] += add;
        __syncthreads();
    }
    if (t < 391) bsumex[t] = s[t] - v0;
}

__global__ void k_scan_final(const int* __restrict__ counts, const int* __restrict__ bsumex,
                             int* __restrict__ rowstart, float* __restrict__ invdeg)
{
    __shared__ int s[256];
    int t = threadIdx.x;
    int i = blockIdx.x * 256 + t;
    int c = (i < NN) ? counts[i] : 0;
    s[t] = c; __syncthreads();
    for (int off = 1; off < 256; off <<= 1) {
        int add = (t >= off) ? s[t - off] : 0;
        __syncthreads();
        s[t] += add;
        __syncthreads();
    }
    int ex = s[t] - c + bsumex[blockIdx.x];
    if (i < NN) {
        rowstart[i] = ex;
        invdeg[i] = 1.f / (float)(c > 1 ? c : 1);
    }
    if (i == 0) rowstart[NN] = NE;
}

// ------- finalize: p = rowstart[d] + partition offset + rank; streaming -----
__global__ void k_finalize(const int* __restrict__ idx, const int* __restrict__ cnt8,
                           const int* __restrict__ rowstart,
                           int* __restrict__ eperm, int* __restrict__ srcs)
{
    int e = blockIdx.x * 256 + threadIdx.x;
    if (e < NE) {
        int d = idx[e];
        int s = idx[NE + e];
        int k = (e >> 8) & 7;                  // == blockIdx&7 of k_rank
        int r = eperm[e];                      // temp rank (coalesced)
        int p = rowstart[d] + cnt8[k * NN + d] + r;
        eperm[e] = p;                          // coalesced
        __builtin_nontemporal_store(s, &srcs[p]);  // random 4B, fire-and-forget
    }
}

// ------- copy hx0 into out column 0 + bf16 shadow -------
__global__ void k_init(const float4* __restrict__ hx4, float* __restrict__ outp,
                       u16* __restrict__ hxb16)
{
    int i = blockIdx.x * 256 + threadIdx.x;
    int n = i >> 4, q = i & 15;
    float4 v = hx4[i];
    ((float4*)(outp + (size_t)n * 256))[q] = v;
    u32x2 pk = {cvtpk(v.x, v.y), cvtpk(v.z, v.w)};
    *(u32x2*)(hxb16 + (size_t)n * 64 + q * 4) = pk;
}

// ------- aggregation v3: wave per node, 4 edges/iter, bf16 hx gather -------
__global__ __launch_bounds__(256) void k_agg(
    const u16* __restrict__ hxb16, const u16* __restrict__ w,
    const int* __restrict__ srcs, const int* __restrict__ rowstart,
    const float* __restrict__ invdeg, float* __restrict__ agg, int it)
{
    int lane = threadIdx.x & 63;
    int g = lane >> 4, t = lane & 15;
    int n = blockIdx.x * 4 + (threadIdx.x >> 6);
    n = __builtin_amdgcn_readfirstlane(n);
    int p0 = rowstart[n], p1 = rowstart[n + 1];
    const u16* hxb = hxb16 + 4 * t;
    f32x4 accA = {0.f, 0.f, 0.f, 0.f};
    f32x4 accB = {0.f, 0.f, 0.f, 0.f};
    int p = p0;
    for (; p + 8 <= p1; p += 8) {
        int sA = srcs[p + g];                 // 16-lane broadcast load
        int sB = srcs[p + 4 + g];
        s16x4 hA = *(const s16x4*)(hxb + (size_t)sA * 64);
        s16x4 hB = *(const s16x4*)(hxb + (size_t)sB * 64);
        s16x4 wA = __builtin_nontemporal_load((const s16x4*)(w + (size_t)(p + g) * 64 + 4 * t));
        s16x4 wB = __builtin_nontemporal_load((const s16x4*)(w + (size_t)(p + 4 + g) * 64 + 4 * t));
#pragma unroll
        for (int j = 0; j < 4; ++j) {
            accA[j] = fmaf(bf2f((u16)hA[j]), bf2f((u16)wA[j]), accA[j]);
            accB[j] = fmaf(bf2f((u16)hB[j]), bf2f((u16)wB[j]), accB[j]);
        }
    }
    if (p + 4 <= p1) {
        int sA = srcs[p + g];
        s16x4 hA = *(const s16x4*)(hxb + (size_t)sA * 64);
        s16x4 wA = __builtin_nontemporal_load((const s16x4*)(w + (size_t)(p + g) * 64 + 4 * t));
#pragma unroll
        for (int j = 0; j < 4; ++j)
            accA[j] = fmaf(bf2f((u16)hA[j]), bf2f((u16)wA[j]), accA[j]);
        p += 4;
    }
    int rem = p1 - p;
    if (g < rem) {
        int sB = srcs[p + g];
        s16x4 hB = *(const s16x4*)(hxb + (size_t)sB * 64);
        s16x4 wB = __builtin_nontemporal_load((const s16x4*)(w + (size_t)(p + g) * 64 + 4 * t));
#pragma unroll
        for (int j = 0; j < 4; ++j)
            accB[j] = fmaf(bf2f((u16)hB[j]), bf2f((u16)wB[j]), accB[j]);
    }
#pragma unroll
    for (int j = 0; j < 4; ++j) accA[j] += accB[j];
    // reduce the 4 groups (lane xor 16, 32)
#pragma unroll
    for (int j = 0; j < 4; ++j) {
        accA[j] += __shfl_xor(accA[j], 16, 64);
        accA[j] += __shfl_xor(accA[j], 32, 64);
    }
    if (g == 0) {
        float inv = invdeg[n];
        f32x4 o = {accA[0] * inv, accA[1] * inv, accA[2] * inv, accA[3] * inv};
        *(f32x4*)(agg + (size_t)n * 64 + 4 * t) = o;
    }
}

// ======== fused GRU: gate GEMM + gi/gh MFMA + inorm + gates, all in-kernel ========
// R12 structure (Whh+Wih in LDS, Wig global/L1) + bf16 shadow write of hx'.
__global__ __launch_bounds__(256) void k_gru_fused(
    float* __restrict__ outp, const float* __restrict__ agg,
    const u16* __restrict__ wb,
    const float* __restrict__ big, const float* __restrict__ bih,
    const float* __restrict__ bhh, u16* __restrict__ hxb16, int it)
{
    __shared__ u16 wl[384 * 68];       // Whh rows 0-191, Wih rows 192-383
    __shared__ u16 hbuf[4][16 * 68];
    int tid = threadIdx.x;
    const u16* wigb = wb;

    // ---- stage Whh+Wih (wb[4096..28672)): 3072 x 16B chunks ----
    for (int c = tid; c < 3072; c += 256) {
        int n = c >> 3, cc = c & 7;
        u32x4 v = *(const u32x4*)(wb + 4096 + c * 8);
        u16* pp = &wl[n * 68 + cc * 8];
        *(u32x2*)pp       = __builtin_shufflevector(v, v, 0, 1);
        *(u32x2*)(pp + 4) = __builtin_shufflevector(v, v, 2, 3);
    }

    int wave = tid >> 6, lane = tid & 63;
    int q = lane >> 4, t = lane & 15;
    int nbase = blockIdx.x * 64 + wave * 16;
    u16* hb = hbuf[wave];

    // ---- stage hx -> hb (bf16), float4 reads, packed b64 writes ----
    {
        int c = lane & 15;
        int mrow = lane >> 4;
#pragma unroll
        for (int rep = 0; rep < 4; ++rep) {
            int m = rep * 4 + mrow;
            int node = nbase + m;
            float4 v = make_float4(0.f, 0.f, 0.f, 0.f);
            if (node < NN)
                v = *(const float4*)(outp + (size_t)node * 256 + (size_t)it * 64 + c * 4);
            u32x2 pk = {cvtpk(v.x, v.y), cvtpk(v.z, v.w)};
            *(u32x2*)(&hb[m * 68 + c * 4]) = pk;
        }
    }
    __syncthreads();   // wl visible to all waves (hbuf stays wave-private)

    // ---- hx A-frags + hx rows 4t..4t+3 (C-layout) ----
    s16x8 ahx[2];
    ahx[0] = lds_frag(&hb[t * 68 + q * 8]);
    ahx[1] = lds_frag(&hb[t * 68 + 32 + q * 8]);
    u32 hxpk[4][2];
#pragma unroll
    for (int r = 0; r < 4; ++r)
        *(u32x2*)hxpk[r] = *(const u32x2*)(&hb[(q * 4 + r) * 68 + 4 * t]);

    // ---- gate GEMM: sigmoid(hx @ Wig^T + big) * agg -> inp (to hb) ----
    f32x4 bgv = *(const f32x4*)(big + 4 * t);
    f32x4 gacc[4];
#pragma unroll
    for (int ni = 0; ni < 4; ++ni) {
        s16x8 b0 = gfrag(wigb, ni * 16 + t, 0, q);
        s16x8 b1 = gfrag(wigb, ni * 16 + t, 1, q);
        f32x4 acc = {bgv[ni], bgv[ni], bgv[ni], bgv[ni]};
        acc = __builtin_amdgcn_mfma_f32_16x16x32_bf16(ahx[0], b0, acc, 0, 0, 0);
        acc = __builtin_amdgcn_mfma_f32_16x16x32_bf16(ahx[1], b1, acc, 0, 0, 0);
        gacc[ni] = acc;
    }
#pragma unroll
    for (int r = 0; r < 4; ++r) {
        int node = nbase + q * 4 + r;
        f32x4 av = {0.f, 0.f, 0.f, 0.f};
        if (node < NN) av = *(const f32x4*)(agg + (size_t)node * 64 + 4 * t);
        float i0 = sigmoidf_(gacc[0][r]) * av[0];
        float i1 = sigmoidf_(gacc[1][r]) * av[1];
        float i2 = sigmoidf_(gacc[2][r]) * av[2];
        float i3 = sigmoidf_(gacc[3][r]) * av[3];
        u32x2 pk = {cvtpk(i0, i1), cvtpk(i2, i3)};
        *(u32x2*)(&hb[(q * 4 + r) * 68 + 4 * t]) = pk;
    }

    // ---- gh = hx @ Whh^T  (12 tiles, Whh frags from LDS) ----
    float sgh[4] = {0.f, 0.f, 0.f, 0.f}, qgh[4] = {0.f, 0.f, 0.f, 0.f};
    u32 ghp[12][2];
#pragma unroll
    for (int ni = 0; ni < 12; ++ni) {
        s16x8 b0 = lds_frag(&wl[(ni * 16 + t) * 68 + q * 8]);
        s16x8 b1 = lds_frag(&wl[(ni * 16 + t) * 68 + 32 + q * 8]);
        f32x4 acc = {0.f, 0.f, 0.f, 0.f};
        acc = __builtin_amdgcn_mfma_f32_16x16x32_bf16(ahx[0], b0, acc, 0, 0, 0);
        acc = __builtin_amdgcn_mfma_f32_16x16x32_bf16(ahx[1], b1, acc, 0, 0, 0);
#pragma unroll
        for (int r = 0; r < 4; ++r) { sgh[r] += acc[r]; qgh[r] += acc[r] * acc[r]; }
        ghp[ni][0] = cvtpk(acc[0], acc[1]);
        ghp[ni][1] = cvtpk(acc[2], acc[3]);
    }

    // ---- inp A-frags (after LDS write above; same-wave ordering) ----
    s16x8 ain[2];
    ain[0] = lds_frag(&hb[t * 68 + q * 8]);
    ain[1] = lds_frag(&hb[t * 68 + 32 + q * 8]);

    // ---- gi = inp @ Wih^T  (Wih frags from LDS rows 192..383) ----
    float sgi[4] = {0.f, 0.f, 0.f, 0.f}, qgi[4] = {0.f, 0.f, 0.f, 0.f};
    u32 gip[12][2];
#pragma unroll
    for (int ni = 0; ni < 12; ++ni) {
        s16x8 b0 = lds_frag(&wl[(192 + ni * 16 + t) * 68 + q * 8]);
        s16x8 b1 = lds_frag(&wl[(192 + ni * 16 + t) * 68 + 32 + q * 8]);
        f32x4 acc = {0.f, 0.f, 0.f, 0.f};
        acc = __builtin_amdgcn_mfma_f32_16x16x32_bf16(ain[0], b0, acc, 0, 0, 0);
        acc = __builtin_amdgcn_mfma_f32_16x16x32_bf16(ain[1], b1, acc, 0, 0, 0);
#pragma unroll
        for (int r = 0; r < 4; ++r) { sgi[r] += acc[r]; qgi[r] += acc[r] * acc[r]; }
        gip[ni][0] = cvtpk(acc[0], acc[1]);
        gip[ni][1] = cvtpk(acc[2], acc[3]);
    }

    // ---- reduce stats over t-group ----
#pragma unroll
    for (int m = 1; m < 16; m <<= 1) {
#pragma unroll
        for (int r = 0; r < 4; ++r) {
            sgh[r] += __shfl_xor(sgh[r], m, 64);
            qgh[r] += __shfl_xor(qgh[r], m, 64);
            sgi[r] += __shfl_xor(sgi[r], m, 64);
            qgi[r] += __shfl_xor(qgi[r], m, 64);
        }
    }
    float mi_[4], ri_[4], mh_[4], rh_[4];
#pragma unroll
    for (int r = 0; r < 4; ++r) {
        mi_[r] = sgi[r] * (1.f / 192.f);
        mh_[r] = sgh[r] * (1.f / 192.f);
        ri_[r] = rsqrtf(qgi[r] * (1.f / 192.f) - mi_[r] * mi_[r] + EPSI);
        rh_[r] = rsqrtf(qgh[r] * (1.f / 192.f) - mh_[r] * mh_[r] + EPSI);
    }

    // ---- gates + hx update + float4 stores + bf16 shadow ----
    f32x4 bihr = *(const f32x4*)(bih + 4 * t);
    f32x4 bihi = *(const f32x4*)(bih + 64 + 4 * t);
    f32x4 bihn = *(const f32x4*)(bih + 128 + 4 * t);
    f32x4 bhhr = *(const f32x4*)(bhh + 4 * t);
    f32x4 bhhi = *(const f32x4*)(bhh + 64 + 4 * t);
    f32x4 bhhn = *(const f32x4*)(bhh + 128 + 4 * t);
#pragma unroll
    for (int r = 0; r < 4; ++r) {
        int node = nbase + q * 4 + r;
        f32x4 res;
#pragma unroll
        for (int ni = 0; ni < 4; ++ni) {
            float iv_r = (unpk(gip[ni], r) - mi_[r]) * ri_[r];
            float iv_i = (unpk(gip[ni + 4], r) - mi_[r]) * ri_[r];
            float iv_n = (unpk(gip[ni + 8], r) - mi_[r]) * ri_[r];
            float hv_r = (unpk(ghp[ni], r) - mh_[r]) * rh_[r];
            float hv_i = (unpk(ghp[ni + 4], r) - mh_[r]) * rh_[r];
            float hv_n = (unpk(ghp[ni + 8], r) - mh_[r]) * rh_[r];
            float rg = sigmoidf_(iv_r + bihr[ni] + hv_r + bhhr[ni]);
            float zg = sigmoidf_(iv_i + bihi[ni] + hv_i + bhhi[ni]);
            float ng = tanhf_(iv_n + bihn[ni] + rg * (hv_n + bhhn[ni]));
            float ho = bf2f((u16)((ni & 1) ? (hxpk[r][ni >> 1] >> 16)
                                           : (hxpk[r][ni >> 1] & 0xffffu)));
            res[ni] = ng + zg * (ho - ng);
        }
        if (node < NN) {
            *(f32x4*)(outp + (size_t)node * 256 + (size_t)(it + 1) * 64 + 4 * t) = res;
            u32x2 pk = {cvtpk(res[0], res[1]), cvtpk(res[2], res[3])};
            *(u32x2*)(hxb16 + (size_t)node * 64 + 4 * t) = pk;
        }
    }
}

extern "C" void kernel_launch(void* const* d_in, const int* in_sizes, int n_in,
                              void* d_out, int out_size, void* d_ws, size_t ws_size,
                              hipStream_t stream)
{
    const float* hx  = (const float*)d_in[0];
    const int*   eix = (const int*)d_in[1];
    const float* ef  = (const float*)d_in[2];
    const float* fW1 = (const float*)d_in[3];
    const float* fb1 = (const float*)d_in[4];
    const float* fW2 = (const float*)d_in[5];
    const float* fb2 = (const float*)d_in[6];
    const float* fW3 = (const float*)d_in[7];
    const float* fb3 = (const float*)d_in[8];
    const float* Wih = (const float*)d_in[9];
    const float* Whh = (const float*)d_in[10];
    const float* bih = (const float*)d_in[11];
    const float* bhh = (const float*)d_in[12];
    const float* Wig = (const float*)d_in[13];
    const float* big = (const float*)d_in[14];
    float* outp = (float*)d_out;
    char* ws = (char*)d_ws;

    u16*    w      = (u16*)(ws + WS_W);
    float*  agg    = (float*)(ws + WS_AGG);
    int*    cnt8   = (int*)(ws + WS_AGG);     // aliased: prep-phase only
    u16*    wb     = (u16*)(ws + WS_WB);
    u16*    hxb16  = (u16*)(ws + WS_HXB);
    float*  invdeg = (float*)(ws + WS_INVDEG);
    int*    counts = (int*)(ws + WS_COUNTS);
    int*    rowst  = (int*)(ws + WS_ROWSTART);
    int*    bsum   = (int*)(ws + WS_BSUM);
    int*    bsumex = (int*)(ws + WS_BSUMEX);
    int*    srcs   = (int*)(ws + WS_SRC);
    int*    eperm  = (int*)(ws + WS_EPERM);

    hipMemsetAsync(cnt8, 0, 8 * NN * sizeof(int), stream);
    k_prep_w<<<(WB_TOTAL + 255) / 256, 256, 0, stream>>>(Wig, Whh, Wih, fW1, fW2, fW3, wb);
    k_rank<<<(NE + 255) / 256, 256, 0, stream>>>(eix, cnt8, eperm);
    k_sumcnt<<<391, 256, 0, stream>>>(cnt8, counts);
    k_scan_partial<<<391, 256, 0, stream>>>(counts, bsum);
    k_scan_bsum<<<1, 512, 0, stream>>>(bsum, bsumex);
    k_scan_final<<<391, 256, 0, stream>>>(counts, bsumex, rowst, invdeg);
    k_finalize<<<(NE + 255) / 256, 256, 0, stream>>>(eix, cnt8, rowst, eperm, srcs);
    k_fnet_mfma<<<9766, 256, 0, stream>>>(ef, fb1, fb2, fb3, eperm, wb, w);
    k_init<<<6250, 256, 0, stream>>>((const float4*)hx, outp, hxb16);

    for (int it = 0; it < 3; ++it) {
        k_agg<<<25000, 256, 0, stream>>>(hxb16, w, srcs, rowst, invdeg, agg, it);
        k_gru_fused<<<1563, 256, 0, stream>>>(outp, agg, wb, big, bih, bhh, hxb16, it);
    }
}

// Round 15
// 676.920 us; speedup vs baseline: 1.3368x; 1.0011x over previous
//
#include <hip/hip_runtime.h>
#include <math.h>

#define NN 100000
#define NE 1250000
#define EPSI 1e-5f

// ---- workspace layout (bytes) ----
#define WS_W        0ull          // bf16 [NE*64]            160,000,000  (CSR-ordered)
#define WS_AGG      160000000ull  // f32  [NN*64]             25,600,000  (aliased: cnt8[8][NN] during prep)
#define WS_WB       185600000ull  // bf16 weights (see k_prep_w)          75,776
#define WS_HXB      186000000ull  // bf16 [NN*64] hx shadow               12,800,000
#define WS_INVDEG   264000000ull  // f32 [NN]
#define WS_COUNTS   264400000ull  // i32 [NN]
#define WS_ROWSTART 264800000ull  // i32 [NN+1]
#define WS_CURSOR   265200128ull  // i32 [NN] (unused, kept for layout stability)
#define WS_BSUM     265600128ull  // i32 [391]
#define WS_BSUMEX   265601792ull  // i32 [391]
#define WS_SRC      265603584ull  // i32 [NE]  src node per CSR slot       5,000,000
#define WS_EPERM    270603584ull  // i32 [NE]  rank during prep, then CSR slot

// wb (bf16) sub-layout, all row-permuted by p(n)=4*(n&15)+(n>>4) within
// each 64-row block:
//   [0)      Wig   64x64
//   [4096)   Whh  192x64   (perm within each gate's 64 rows)
//   [16384)  Wih  192x64   (perm within each gate's 64 rows)
//   [28672)  W1    64x16   (13 cols + 3 zero pad)
//   [29696)  W2    64x64
//   [33792)  W3    64x64   -> total 37888 elements
#define WB_TOTAL 37888

typedef unsigned short u16;
typedef unsigned int u32;
typedef short s16x4 __attribute__((ext_vector_type(4)));
typedef short s16x8 __attribute__((ext_vector_type(8)));
typedef float f32x4 __attribute__((ext_vector_type(4)));
typedef u32 u32x4 __attribute__((ext_vector_type(4)));
typedef u32 u32x2 __attribute__((ext_vector_type(2)));
typedef float f32x4u __attribute__((ext_vector_type(4), aligned(4)));

__device__ __forceinline__ u16 f2bf(float f) {
    u32 u = __float_as_uint(f);
    return (u16)((u + 0x7fffu + ((u >> 16) & 1u)) >> 16);   // RNE
}
__device__ __forceinline__ float bf2f(u16 b) {
    return __uint_as_float(((u32)b) << 16);
}
// packed f32x2 -> bf16x2 (RNE), 1 VALU op
__device__ __forceinline__ u32 cvtpk(float lo, float hi) {
    u32 r;
    asm("v_cvt_pk_bf16_f32 %0, %1, %2" : "=v"(r) : "v"(lo), "v"(hi));
    return r;
}
__device__ __forceinline__ float sigmoidf_(float x) {
    return 1.f / (1.f + __expf(-x));
}
// tanh via exp, saturating at +-1; ~4 VALU ops vs libm tanhf's ~20
__device__ __forceinline__ float tanhf_(float x) {
    float e = __expf(2.f * x);
    return 1.f - 2.f / (e + 1.f);
}
__device__ __forceinline__ s16x8 lds_frag(const u16* p) {
    s16x4 lo = *(const s16x4*)p;
    s16x4 hi = *(const s16x4*)(p + 4);
    return __builtin_shufflevector(lo, hi, 0, 1, 2, 3, 4, 5, 6, 7);
}
__device__ __forceinline__ s16x8 gfrag(const u16* W, int n, int ks, int q) {
    // W row-major [64 cols], 16-byte aligned chunks
    return *(const s16x8*)(W + n * 64 + ks * 32 + q * 8);
}
__device__ __forceinline__ float unpk(const u32* p, int r) {
    u32 v = p[r >> 1];
    return bf2f((u16)((r & 1) ? (v >> 16) : (v & 0xffffu)));
}

// ============ fnet via MFMA: per-edge MLP 13->64->64->64, bf16 out ============
// R15: 256 edges/block (two sequential 128-edge halves through the proven
// 2-tile mi-split body). Grid 9766->4883: the staging prologue + barrier is
// paid half as often (block generations 8->4), amortizing the fixed cost the
// R14 occupancy probe showed dominates. hbuf reuse across halves relies on
// the same wave-private in-order DS semantics as between layer transitions.
__global__ __launch_bounds__(256) void k_fnet_mfma(
    const float* __restrict__ ef,
    const float* __restrict__ b1, const float* __restrict__ b2,
    const float* __restrict__ b3,
    const int* __restrict__ eperm,
    const u16* __restrict__ wbf,
    u16* __restrict__ wout)
{
    __shared__ u16 w1l[64 * 16];
    __shared__ u16 w2l[64 * 68];
    __shared__ u16 w3l[64 * 68];
    __shared__ u16 hbuf[4][16 * 68];

    int tid = threadIdx.x;
    const u16* wf1 = wbf + 28672;
    const u16* wf2 = wbf + 29696;
    const u16* wf3 = wbf + 33792;
    // w1l: 1024 u16 = 128 x 16B chunks, rows contiguous (16B aligned both sides)
    if (tid < 128)
        *(u32x4*)(&w1l[tid * 8]) = *(const u32x4*)(wf1 + tid * 8);
    // w2l/w3l: 512 x 16B chunks each; row stride 136B in LDS -> split to 2x b64
    for (int c = tid; c < 512; c += 256) {
        int n = c >> 3, cc = c & 7;
        u32x4 v2 = *(const u32x4*)(wf2 + c * 8);
        u32x4 v3 = *(const u32x4*)(wf3 + c * 8);
        u16* p2 = &w2l[n * 68 + cc * 8];
        u16* p3 = &w3l[n * 68 + cc * 8];
        *(u32x2*)p2       = __builtin_shufflevector(v2, v2, 0, 1);
        *(u32x2*)(p2 + 4) = __builtin_shufflevector(v2, v2, 2, 3);
        *(u32x2*)p3       = __builtin_shufflevector(v3, v3, 0, 1);
        *(u32x2*)(p3 + 4) = __builtin_shufflevector(v3, v3, 2, 3);
    }
    __syncthreads();

    int wave = tid >> 6, lane = tid & 63;
    int q = lane >> 4, t = lane & 15;
    u16* hb = hbuf[wave];

    // biases in permuted slot order: slot (ni,t) holds true feat 4t+ni
    f32x4 b1v = *(const f32x4*)(b1 + 4 * t);
    f32x4 b2v = *(const f32x4*)(b2 + 4 * t);
    f32x4 b3v = *(const f32x4*)(b3 + 4 * t);

    const s16x8 zfrag = {0, 0, 0, 0, 0, 0, 0, 0};

    // ---- W1 fragments (once per block) ----
    s16x8 B1f[4];
#pragma unroll
    for (int ni = 0; ni < 4; ++ni) {
        s16x8 b = zfrag;
        if (q < 2) b = lds_frag(&w1l[(ni * 16 + t) * 16 + q * 8]);
        B1f[ni] = b;
    }

    // ---- two 128-edge halves ----
    for (int half = 0; half < 2; ++half) {
        int ebase = blockIdx.x * 256 + half * 128 + wave * 32;

        // ef fragments for this half's two tiles (early global issue)
        s16x8 a1[2];
#pragma unroll
        for (int mi = 0; mi < 2; ++mi) {
            int e = ebase + mi * 16 + t;
            u32 xp[4] = {0u, 0u, 0u, 0u};
            if (e < NE) {
                const float* ep = ef + (size_t)e * 13;
                if (q == 0) {
                    f32x4u v0 = *(const f32x4u*)(ep);
                    f32x4u v1 = *(const f32x4u*)(ep + 4);
                    xp[0] = cvtpk(v0[0], v0[1]); xp[1] = cvtpk(v0[2], v0[3]);
                    xp[2] = cvtpk(v1[0], v1[1]); xp[3] = cvtpk(v1[2], v1[3]);
                } else if (q == 1) {
                    f32x4u v0 = *(const f32x4u*)(ep + 8);
                    float v12 = ep[12];
                    xp[0] = cvtpk(v0[0], v0[1]); xp[1] = cvtpk(v0[2], v0[3]);
                    xp[2] = cvtpk(v12, 0.f);
                }
            }
            a1[mi] = __builtin_bit_cast(s16x8, *(u32x4*)xp);
        }

        // two sequential 16-edge passes through layers 1-3
#pragma unroll
        for (int mi = 0; mi < 2; ++mi) {
            // layer 1
            f32x4 h1[4];
#pragma unroll
            for (int ni = 0; ni < 4; ++ni) {
                f32x4 acc = {b1v[ni], b1v[ni], b1v[ni], b1v[ni]};
                h1[ni] = __builtin_amdgcn_mfma_f32_16x16x32_bf16(a1[mi], B1f[ni], acc, 0, 0, 0);
            }
            // transition 1: relu + pack + b64 write (cols 4t..4t+3 contiguous)
#pragma unroll
            for (int r = 0; r < 4; ++r) {
                u32 lo = cvtpk(fmaxf(h1[0][r], 0.f), fmaxf(h1[1][r], 0.f));
                u32 hi = cvtpk(fmaxf(h1[2][r], 0.f), fmaxf(h1[3][r], 0.f));
                u32x2 v = {lo, hi};
                *(u32x2*)(&hb[(q * 4 + r) * 68 + 4 * t]) = v;
            }
            // layer 2
            s16x8 a2[2];
#pragma unroll
            for (int ks = 0; ks < 2; ++ks)
                a2[ks] = lds_frag(&hb[t * 68 + ks * 32 + q * 8]);
            f32x4 h2[4];
#pragma unroll
            for (int ni = 0; ni < 4; ++ni) {
                s16x8 w0 = lds_frag(&w2l[(ni * 16 + t) * 68 + q * 8]);
                s16x8 w1_ = lds_frag(&w2l[(ni * 16 + t) * 68 + 32 + q * 8]);
                f32x4 acc = {b2v[ni], b2v[ni], b2v[ni], b2v[ni]};
                acc = __builtin_amdgcn_mfma_f32_16x16x32_bf16(a2[0], w0, acc, 0, 0, 0);
                acc = __builtin_amdgcn_mfma_f32_16x16x32_bf16(a2[1], w1_, acc, 0, 0, 0);
                h2[ni] = acc;
            }
            // transition 2
#pragma unroll
            for (int r = 0; r < 4; ++r) {
                u32 lo = cvtpk(fmaxf(h2[0][r], 0.f), fmaxf(h2[1][r], 0.f));
                u32 hi = cvtpk(fmaxf(h2[2][r], 0.f), fmaxf(h2[3][r], 0.f));
                u32x2 v = {lo, hi};
                *(u32x2*)(&hb[(q * 4 + r) * 68 + 4 * t]) = v;
            }
            // layer 3 + direct CSR-scattered store
            s16x8 a3[2];
#pragma unroll
            for (int ks = 0; ks < 2; ++ks)
                a3[ks] = lds_frag(&hb[t * 68 + ks * 32 + q * 8]);
            f32x4 h3[4];
#pragma unroll
            for (int ni = 0; ni < 4; ++ni) {
                s16x8 w0 = lds_frag(&w3l[(ni * 16 + t) * 68 + q * 8]);
                s16x8 w1_ = lds_frag(&w3l[(ni * 16 + t) * 68 + 32 + q * 8]);
                f32x4 acc = {b3v[ni], b3v[ni], b3v[ni], b3v[ni]};
                acc = __builtin_amdgcn_mfma_f32_16x16x32_bf16(a3[0], w0, acc, 0, 0, 0);
                acc = __builtin_amdgcn_mfma_f32_16x16x32_bf16(a3[1], w1_, acc, 0, 0, 0);
                h3[ni] = acc;
            }
            int baseE = ebase + mi * 16 + q * 4;
            int4 pos = *(const int4*)(eperm + ((baseE + 3 < NE) ? baseE : 0));
#pragma unroll
            for (int r = 0; r < 4; ++r) {
                int e = baseE + r;
                if (e < NE) {
                    int p_ = ((const int*)&pos)[r];
                    u32x2 v = {cvtpk(h3[0][r], h3[1][r]), cvtpk(h3[2][r], h3[3][r])};
                    *(u32x2*)(wout + (size_t)p_ * 64 + 4 * t) = v;
                }
            }
        }
    }
}

// ------- prep: bf16 weights, row-permuted by p(n) within 64-row blocks -------
__global__ void k_prep_w(const float* __restrict__ Wig, const float* __restrict__ Whh,
                         const float* __restrict__ Wih,
                         const float* __restrict__ W1, const float* __restrict__ W2,
                         const float* __restrict__ W3, u16* __restrict__ wb)
{
    int i = blockIdx.x * 256 + threadIdx.x;   // < WB_TOTAL
    if (i >= WB_TOTAL) return;
    float v;
    if (i < 4096) {
        int n = i >> 6, k = i & 63;
        int pn = ((n & 15) << 2) + (n >> 4);
        v = Wig[pn * 64 + k];
    } else if (i < 16384) {
        int j = i - 4096;
        int n = j >> 6, k = j & 63;
        int g = n >> 6, m = n & 63;
        int pm = ((m & 15) << 2) + (m >> 4);
        v = Whh[(g * 64 + pm) * 64 + k];
    } else if (i < 28672) {
        int j = i - 16384;
        int n = j >> 6, k = j & 63;
        int g = n >> 6, m = n & 63;
        int pm = ((m & 15) << 2) + (m >> 4);
        v = Wih[(g * 64 + pm) * 64 + k];
    } else if (i < 29696) {
        int j = i - 28672;
        int n = j >> 4, k = j & 15;
        int pn = ((n & 15) << 2) + (n >> 4);
        v = (k < 13) ? W1[pn * 13 + k] : 0.f;
    } else if (i < 33792) {
        int j = i - 29696;
        int n = j >> 6, k = j & 63;
        int pn = ((n & 15) << 2) + (n >> 4);
        v = W2[pn * 64 + k];
    } else {
        int j = i - 33792;
        int n = j >> 6, k = j & 63;
        int pn = ((n & 15) << 2) + (n >> 4);
        v = W3[pn * 64 + k];
    }
    wb[i] = f2bf(v);
}

// ------- rank pass: ONE atomic pass, 8-way partitioned counters -------
__global__ void k_rank(const int* __restrict__ idx, int* __restrict__ cnt8,
                       int* __restrict__ rank_out)
{
    int e = blockIdx.x * 256 + threadIdx.x;
    int k = blockIdx.x & 7;
    if (e < NE) {
        int d = idx[e];
        int r = atomicAdd(&cnt8[k * NN + d], 1);
        rank_out[e] = r;                       // coalesced
    }
}

// ------- fold 8 partition counts: totals -> counts, cnt8 -> excl prefix -----
__global__ void k_sumcnt(int* __restrict__ cnt8, int* __restrict__ counts)
{
    int d = blockIdx.x * 256 + threadIdx.x;
    if (d >= NN) return;
    int c[8], run = 0;
#pragma unroll
    for (int k = 0; k < 8; ++k) c[k] = cnt8[k * NN + d];
#pragma unroll
    for (int k = 0; k < 8; ++k) { int t = c[k]; cnt8[k * NN + d] = run; run += t; }
    counts[d] = run;
}

// ---------------- two-level exclusive scan over counts ----------------
__global__ void k_scan_partial(const int* __restrict__ counts, int* __restrict__ bsum)
{
    __shared__ int s[256];
    int i = blockIdx.x * 256 + threadIdx.x;
    int v = (i < NN) ? counts[i] : 0;
    s[threadIdx.x] = v; __syncthreads();
    for (int off = 128; off > 0; off >>= 1) {
        if (threadIdx.x < off) s[threadIdx.x] += s[threadIdx.x + off];
        __syncthreads();
    }
    if (threadIdx.x == 0) bsum[blockIdx.x] = s[0];
}

__global__ void k_scan_bsum(const int* __restrict__ bsum, int* __restrict__ bsumex)
{
    __shared__ int s[512];
    int t = threadIdx.x;
    int v0 = (t < 391) ? bsum[t] : 0;
    s[t] = v0; __syncthreads();
    for (int off = 1; off < 512; off <<= 1) {
        int add = (t >= off) ? s[t - off] : 0;
        __syncthreads();
        s[t] += add;
        __syncthreads();
    }
    if (t < 391) bsumex[t] = s[t] - v0;
}

__global__ void k_scan_final(const int* __restrict__ counts, const int* __restrict__ bsumex,
                             int* __restrict__ rowstart, float* __restrict__ invdeg)
{
    __shared__ int s[256];
    int t = threadIdx.x;
    int i = blockIdx.x * 256 + t;
    int c = (i < NN) ? counts[i] : 0;
    s[t] = c; __syncthreads();
    for (int off = 1; off < 256; off <<= 1) {
        int add = (t >= off) ? s[t - off] : 0;
        __syncthreads();
        s[t] += add;
        __syncthreads();
    }
    int ex = s[t] - c + bsumex[blockIdx.x];
    if (i < NN) {
        rowstart[i] = ex;
        invdeg[i] = 1.f / (float)(c > 1 ? c : 1);
    }
    if (i == 0) rowstart[NN] = NE;
}

// ------- finalize: p = rowstart[d] + partition offset + rank; streaming -----
__global__ void k_finalize(const int* __restrict__ idx, const int* __restrict__ cnt8,
                           const int* __restrict__ rowstart,
                           int* __restrict__ eperm, int* __restrict__ srcs)
{
    int e = blockIdx.x * 256 + threadIdx.x;
    if (e < NE) {
        int d = idx[e];
        int s = idx[NE + e];
        int k = (e >> 8) & 7;                  // == blockIdx&7 of k_rank
        int r = eperm[e];                      // temp rank (coalesced)
        int p = rowstart[d] + cnt8[k * NN + d] + r;
        eperm[e] = p;                          // coalesced
        __builtin_nontemporal_store(s, &srcs[p]);  // random 4B, fire-and-forget
    }
}

// ------- copy hx0 into out column 0 + bf16 shadow -------
__global__ void k_init(const float4* __restrict__ hx4, float* __restrict__ outp,
                       u16* __restrict__ hxb16)
{
    int i = blockIdx.x * 256 + threadIdx.x;
    int n = i >> 4, q = i & 15;
    float4 v = hx4[i];
    ((float4*)(outp + (size_t)n * 256))[q] = v;
    u32x2 pk = {cvtpk(v.x, v.y), cvtpk(v.z, v.w)};
    *(u32x2*)(hxb16 + (size_t)n * 64 + q * 4) = pk;
}

// ------- aggregation v3: wave per node, 4 edges/iter, bf16 hx gather -------
__global__ __launch_bounds__(256) void k_agg(
    const u16* __restrict__ hxb16, const u16* __restrict__ w,
    const int* __restrict__ srcs, const int* __restrict__ rowstart,
    const float* __restrict__ invdeg, float* __restrict__ agg, int it)
{
    int lane = threadIdx.x & 63;
    int g = lane >> 4, t = lane & 15;
    int n = blockIdx.x * 4 + (threadIdx.x >> 6);
    n = __builtin_amdgcn_readfirstlane(n);
    int p0 = rowstart[n], p1 = rowstart[n + 1];
    const u16* hxb = hxb16 + 4 * t;
    f32x4 accA = {0.f, 0.f, 0.f, 0.f};
    f32x4 accB = {0.f, 0.f, 0.f, 0.f};
    int p = p0;
    for (; p + 8 <= p1; p += 8) {
        int sA = srcs[p + g];                 // 16-lane broadcast load
        int sB = srcs[p + 4 + g];
        s16x4 hA = *(const s16x4*)(hxb + (size_t)sA * 64);
        s16x4 hB = *(const s16x4*)(hxb + (size_t)sB * 64);
        s16x4 wA = __builtin_nontemporal_load((const s16x4*)(w + (size_t)(p + g) * 64 + 4 * t));
        s16x4 wB = __builtin_nontemporal_load((const s16x4*)(w + (size_t)(p + 4 + g) * 64 + 4 * t));
#pragma unroll
        for (int j = 0; j < 4; ++j) {
            accA[j] = fmaf(bf2f((u16)hA[j]), bf2f((u16)wA[j]), accA[j]);
            accB[j] = fmaf(bf2f((u16)hB[j]), bf2f((u16)wB[j]), accB[j]);
        }
    }
    if (p + 4 <= p1) {
        int sA = srcs[p + g];
        s16x4 hA = *(const s16x4*)(hxb + (size_t)sA * 64);
        s16x4 wA = __builtin_nontemporal_load((const s16x4*)(w + (size_t)(p + g) * 64 + 4 * t));
#pragma unroll
        for (int j = 0; j < 4; ++j)
            accA[j] = fmaf(bf2f((u16)hA[j]), bf2f((u16)wA[j]), accA[j]);
        p += 4;
    }
    int rem = p1 - p;
    if (g < rem) {
        int sB = srcs[p + g];
        s16x4 hB = *(const s16x4*)(hxb + (size_t)sB * 64);
        s16x4 wB = __builtin_nontemporal_load((const s16x4*)(w + (size_t)(p + g) * 64 + 4 * t));
#pragma unroll
        for (int j = 0; j < 4; ++j)
            accB[j] = fmaf(bf2f((u16)hB[j]), bf2f((u16)wB[j]), accB[j]);
    }
#pragma unroll
    for (int j = 0; j < 4; ++j) accA[j] += accB[j];
    // reduce the 4 groups (lane xor 16, 32)
#pragma unroll
    for (int j = 0; j < 4; ++j) {
        accA[j] += __shfl_xor(accA[j], 16, 64);
        accA[j] += __shfl_xor(accA[j], 32, 64);
    }
    if (g == 0) {
        float inv = invdeg[n];
        f32x4 o = {accA[0] * inv, accA[1] * inv, accA[2] * inv, accA[3] * inv};
        *(f32x4*)(agg + (size_t)n * 64 + 4 * t) = o;
    }
}

// ======== fused GRU: gate GEMM + gi/gh MFMA + inorm + gates, all in-kernel ========
// R12 structure (Whh+Wih in LDS, Wig global/L1) + bf16 shadow write of hx'.
__global__ __launch_bounds__(256) void k_gru_fused(
    float* __restrict__ outp, const float* __restrict__ agg,
    const u16* __restrict__ wb,
    const float* __restrict__ big, const float* __restrict__ bih,
    const float* __restrict__ bhh, u16* __restrict__ hxb16, int it)
{
    __shared__ u16 wl[384 * 68];       // Whh rows 0-191, Wih rows 192-383
    __shared__ u16 hbuf[4][16 * 68];
    int tid = threadIdx.x;
    const u16* wigb = wb;

    // ---- stage Whh+Wih (wb[4096..28672)): 3072 x 16B chunks ----
    for (int c = tid; c < 3072; c += 256) {
        int n = c >> 3, cc = c & 7;
        u32x4 v = *(const u32x4*)(wb + 4096 + c * 8);
        u16* pp = &wl[n * 68 + cc * 8];
        *(u32x2*)pp       = __builtin_shufflevector(v, v, 0, 1);
        *(u32x2*)(pp + 4) = __builtin_shufflevector(v, v, 2, 3);
    }

    int wave = tid >> 6, lane = tid & 63;
    int q = lane >> 4, t = lane & 15;
    int nbase = blockIdx.x * 64 + wave * 16;
    u16* hb = hbuf[wave];

    // ---- stage hx -> hb (bf16), float4 reads, packed b64 writes ----
    {
        int c = lane & 15;
        int mrow = lane >> 4;
#pragma unroll
        for (int rep = 0; rep < 4; ++rep) {
            int m = rep * 4 + mrow;
            int node = nbase + m;
            float4 v = make_float4(0.f, 0.f, 0.f, 0.f);
            if (node < NN)
                v = *(const float4*)(outp + (size_t)node * 256 + (size_t)it * 64 + c * 4);
            u32x2 pk = {cvtpk(v.x, v.y), cvtpk(v.z, v.w)};
            *(u32x2*)(&hb[m * 68 + c * 4]) = pk;
        }
    }
    __syncthreads();   // wl visible to all waves (hbuf stays wave-private)

    // ---- hx A-frags + hx rows 4t..4t+3 (C-layout) ----
    s16x8 ahx[2];
    ahx[0] = lds_frag(&hb[t * 68 + q * 8]);
    ahx[1] = lds_frag(&hb[t * 68 + 32 + q * 8]);
    u32 hxpk[4][2];
#pragma unroll
    for (int r = 0; r < 4; ++r)
        *(u32x2*)hxpk[r] = *(const u32x2*)(&hb[(q * 4 + r) * 68 + 4 * t]);

    // ---- gate GEMM: sigmoid(hx @ Wig^T + big) * agg -> inp (to hb) ----
    f32x4 bgv = *(const f32x4*)(big + 4 * t);
    f32x4 gacc[4];
#pragma unroll
    for (int ni = 0; ni < 4; ++ni) {
        s16x8 b0 = gfrag(wigb, ni * 16 + t, 0, q);
        s16x8 b1 = gfrag(wigb, ni * 16 + t, 1, q);
        f32x4 acc = {bgv[ni], bgv[ni], bgv[ni], bgv[ni]};
        acc = __builtin_amdgcn_mfma_f32_16x16x32_bf16(ahx[0], b0, acc, 0, 0, 0);
        acc = __builtin_amdgcn_mfma_f32_16x16x32_bf16(ahx[1], b1, acc, 0, 0, 0);
        gacc[ni] = acc;
    }
#pragma unroll
    for (int r = 0; r < 4; ++r) {
        int node = nbase + q * 4 + r;
        f32x4 av = {0.f, 0.f, 0.f, 0.f};
        if (node < NN) av = *(const f32x4*)(agg + (size_t)node * 64 + 4 * t);
        float i0 = sigmoidf_(gacc[0][r]) * av[0];
        float i1 = sigmoidf_(gacc[1][r]) * av[1];
        float i2 = sigmoidf_(gacc[2][r]) * av[2];
        float i3 = sigmoidf_(gacc[3][r]) * av[3];
        u32x2 pk = {cvtpk(i0, i1), cvtpk(i2, i3)};
        *(u32x2*)(&hb[(q * 4 + r) * 68 + 4 * t]) = pk;
    }

    // ---- gh = hx @ Whh^T  (12 tiles, Whh frags from LDS) ----
    float sgh[4] = {0.f, 0.f, 0.f, 0.f}, qgh[4] = {0.f, 0.f, 0.f, 0.f};
    u32 ghp[12][2];
#pragma unroll
    for (int ni = 0; ni < 12; ++ni) {
        s16x8 b0 = lds_frag(&wl[(ni * 16 + t) * 68 + q * 8]);
        s16x8 b1 = lds_frag(&wl[(ni * 16 + t) * 68 + 32 + q * 8]);
        f32x4 acc = {0.f, 0.f, 0.f, 0.f};
        acc = __builtin_amdgcn_mfma_f32_16x16x32_bf16(ahx[0], b0, acc, 0, 0, 0);
        acc = __builtin_amdgcn_mfma_f32_16x16x32_bf16(ahx[1], b1, acc, 0, 0, 0);
#pragma unroll
        for (int r = 0; r < 4; ++r) { sgh[r] += acc[r]; qgh[r] += acc[r] * acc[r]; }
        ghp[ni][0] = cvtpk(acc[0], acc[1]);
        ghp[ni][1] = cvtpk(acc[2], acc[3]);
    }

    // ---- inp A-frags (after LDS write above; same-wave ordering) ----
    s16x8 ain[2];
    ain[0] = lds_frag(&hb[t * 68 + q * 8]);
    ain[1] = lds_frag(&hb[t * 68 + 32 + q * 8]);

    // ---- gi = inp @ Wih^T  (Wih frags from LDS rows 192..383) ----
    float sgi[4] = {0.f, 0.f, 0.f, 0.f}, qgi[4] = {0.f, 0.f, 0.f, 0.f};
    u32 gip[12][2];
#pragma unroll
    for (int ni = 0; ni < 12; ++ni) {
        s16x8 b0 = lds_frag(&wl[(192 + ni * 16 + t) * 68 + q * 8]);
        s16x8 b1 = lds_frag(&wl[(192 + ni * 16 + t) * 68 + 32 + q * 8]);
        f32x4 acc = {0.f, 0.f, 0.f, 0.f};
        acc = __builtin_amdgcn_mfma_f32_16x16x32_bf16(ain[0], b0, acc, 0, 0, 0);
        acc = __builtin_amdgcn_mfma_f32_16x16x32_bf16(ain[1], b1, acc, 0, 0, 0);
#pragma unroll
        for (int r = 0; r < 4; ++r) { sgi[r] += acc[r]; qgi[r] += acc[r] * acc[r]; }
        gip[ni][0] = cvtpk(acc[0], acc[1]);
        gip[ni][1] = cvtpk(acc[2], acc[3]);
    }

    // ---- reduce stats over t-group ----
#pragma unroll
    for (int m = 1; m < 16; m <<= 1) {
#pragma unroll
        for (int r = 0; r < 4; ++r) {
            sgh[r] += __shfl_xor(sgh[r], m, 64);
            qgh[r] += __shfl_xor(qgh[r], m, 64);
            sgi[r] += __shfl_xor(sgi[r], m, 64);
            qgi[r] += __shfl_xor(qgi[r], m, 64);
        }
    }
    float mi_[4], ri_[4], mh_[4], rh_[4];
#pragma unroll
    for (int r = 0; r < 4; ++r) {
        mi_[r] = sgi[r] * (1.f / 192.f);
        mh_[r] = sgh[r] * (1.f / 192.f);
        ri_[r] = rsqrtf(qgi[r] * (1.f / 192.f) - mi_[r] * mi_[r] + EPSI);
        rh_[r] = rsqrtf(qgh[r] * (1.f / 192.f) - mh_[r] * mh_[r] + EPSI);
    }

    // ---- gates + hx update + float4 stores + bf16 shadow ----
    f32x4 bihr = *(const f32x4*)(bih + 4 * t);
    f32x4 bihi = *(const f32x4*)(bih + 64 + 4 * t);
    f32x4 bihn = *(const f32x4*)(bih + 128 + 4 * t);
    f32x4 bhhr = *(const f32x4*)(bhh + 4 * t);
    f32x4 bhhi = *(const f32x4*)(bhh + 64 + 4 * t);
    f32x4 bhhn = *(const f32x4*)(bhh + 128 + 4 * t);
#pragma unroll
    for (int r = 0; r < 4; ++r) {
        int node = nbase + q * 4 + r;
        f32x4 res;
#pragma unroll
        for (int ni = 0; ni < 4; ++ni) {
            float iv_r = (unpk(gip[ni], r) - mi_[r]) * ri_[r];
            float iv_i = (unpk(gip[ni + 4], r) - mi_[r]) * ri_[r];
            float iv_n = (unpk(gip[ni + 8], r) - mi_[r]) * ri_[r];
            float hv_r = (unpk(ghp[ni], r) - mh_[r]) * rh_[r];
            float hv_i = (unpk(ghp[ni + 4], r) - mh_[r]) * rh_[r];
            float hv_n = (unpk(ghp[ni + 8], r) - mh_[r]) * rh_[r];
            float rg = sigmoidf_(iv_r + bihr[ni] + hv_r + bhhr[ni]);
            float zg = sigmoidf_(iv_i + bihi[ni] + hv_i + bhhi[ni]);
            float ng = tanhf_(iv_n + bihn[ni] + rg * (hv_n + bhhn[ni]));
            float ho = bf2f((u16)((ni & 1) ? (hxpk[r][ni >> 1] >> 16)
                                           : (hxpk[r][ni >> 1] & 0xffffu)));
            res[ni] = ng + zg * (ho - ng);
        }
        if (node < NN) {
            *(f32x4*)(outp + (size_t)node * 256 + (size_t)(it + 1) * 64 + 4 * t) = res;
            u32x2 pk = {cvtpk(res[0], res[1]), cvtpk(res[2], res[3])};
            *(u32x2*)(hxb16 + (size_t)node * 64 + 4 * t) = pk;
        }
    }
}

extern "C" void kernel_launch(void* const* d_in, const int* in_sizes, int n_in,
                              void* d_out, int out_size, void* d_ws, size_t ws_size,
                              hipStream_t stream)
{
    const float* hx  = (const float*)d_in[0];
    const int*   eix = (const int*)d_in[1];
    const float* ef  = (const float*)d_in[2];
    const float* fW1 = (const float*)d_in[3];
    const float* fb1 = (const float*)d_in[4];
    const float* fW2 = (const float*)d_in[5];
    const float* fb2 = (const float*)d_in[6];
    const float* fW3 = (const float*)d_in[7];
    const float* fb3 = (const float*)d_in[8];
    const float* Wih = (const float*)d_in[9];
    const float* Whh = (const float*)d_in[10];
    const float* bih = (const float*)d_in[11];
    const float* bhh = (const float*)d_in[12];
    const float* Wig = (const float*)d_in[13];
    const float* big = (const float*)d_in[14];
    float* outp = (float*)d_out;
    char* ws = (char*)d_ws;

    u16*    w      = (u16*)(ws + WS_W);
    float*  agg    = (float*)(ws + WS_AGG);
    int*    cnt8   = (int*)(ws + WS_AGG);     // aliased: prep-phase only
    u16*    wb     = (u16*)(ws + WS_WB);
    u16*    hxb16  = (u16*)(ws + WS_HXB);
    float*  invdeg = (float*)(ws + WS_INVDEG);
    int*    counts = (int*)(ws + WS_COUNTS);
    int*    rowst  = (int*)(ws + WS_ROWSTART);
    int*    bsum   = (int*)(ws + WS_BSUM);
    int*    bsumex = (int*)(ws + WS_BSUMEX);
    int*    srcs   = (int*)(ws + WS_SRC);
    int*    eperm  = (int*)(ws + WS_EPERM);

    hipMemsetAsync(cnt8, 0, 8 * NN * sizeof(int), stream);
    k_prep_w<<<(WB_TOTAL + 255) / 256, 256, 0, stream>>>(Wig, Whh, Wih, fW1, fW2, fW3, wb);
    k_rank<<<(NE + 255) / 256, 256, 0, stream>>>(eix, cnt8, eperm);
    k_sumcnt<<<391, 256, 0, stream>>>(cnt8, counts);
    k_scan_partial<<<391, 256, 0, stream>>>(counts, bsum);
    k_scan_bsum<<<1, 512, 0, stream>>>(bsum, bsumex);
    k_scan_final<<<391, 256, 0, stream>>>(counts, bsumex, rowst, invdeg);
    k_finalize<<<(NE + 255) / 256, 256, 0, stream>>>(eix, cnt8, rowst, eperm, srcs);
    k_fnet_mfma<<<4883, 256, 0, stream>>>(ef, fb1, fb2, fb3, eperm, wb, w);
    k_init<<<6250, 256, 0, stream>>>((const float4*)hx, outp, hxb16);

    for (int it = 0; it < 3; ++it) {
        k_agg<<<25000, 256, 0, stream>>>(hxb16, w, srcs, rowst, invdeg, agg, it);
        k_gru_fused<<<1563, 256, 0, stream>>>(outp, agg, wb, big, bih, bhh, hxb16, it);
    }
}